// Round 1
// baseline (745.704 us; speedup 1.0000x reference)
//
#include <hip/hip_runtime.h>
#include <float.h>

#define BATCH 2
#define SEQ   2048
#define HEADS 8
#define DHEAD 64
#define DIMM  512
#define NQKV  1536
#define QK_SCALE 0.125f   // 64^-0.5

// ws layout (floats): maskf[4096] | Q | K | V | O   (each B*H*SEQ*DHEAD)
#define QKV_ELEMS ((size_t)BATCH * HEADS * SEQ * DHEAD)

// ---------------- mask prep: sniff dtype, normalize to float 0/1 -------------
__global__ __launch_bounds__(1024) void prep_mask(const void* __restrict__ mraw,
                                                  float* __restrict__ maskf) {
  __shared__ int f_bf16, f_f32, f_gt1, f_oddnz;
  const int t = threadIdx.x;
  if (t == 0) { f_bf16 = 0; f_f32 = 0; f_gt1 = 0; f_oddnz = 0; }
  __syncthreads();
  const unsigned int* w = (const unsigned int*)mraw;
  unsigned int v = w[t];                 // first 4KB: safe for every candidate dtype
  if (v == 0x3f803f80u) f_bf16 = 1;      // two bf16 1.0s
  if (v == 0x3f800000u) f_f32 = 1;       // f32 1.0
  if (v > 1u)           f_gt1 = 1;       // packed bytes
  if ((t & 1) && v != 0u) f_oddnz = 1;   // int64 has zero odd words
  __syncthreads();
  int mode;                               // 0=i32 1=u8 2=i64 3=f32 4=bf16
  if (f_bf16)       mode = 4;
  else if (f_f32)   mode = 3;
  else if (f_gt1)   mode = 1;
  else if (!f_oddnz) mode = 2;
  else              mode = 0;
  for (int i = t; i < BATCH * SEQ; i += 1024) {
    bool keep;
    if (mode == 4)      keep = ((const unsigned short*)mraw)[i] != 0;
    else if (mode == 3) keep = ((const float*)mraw)[i] != 0.f;
    else if (mode == 1) keep = ((const unsigned char*)mraw)[i] != 0;
    else if (mode == 2) keep = w[2 * i] != 0u;
    else                keep = w[i] != 0u;
    maskf[i] = keep ? 1.f : 0.f;
  }
}

// ---------------- qkv GEMM: X(4096x512) @ W(512x1536) -> Q,K,V (b,h,n,d) -----
__global__ __launch_bounds__(256) void gemm_qkv(const float* __restrict__ X,
                                                const float* __restrict__ W,
                                                float* __restrict__ Q,
                                                float* __restrict__ K,
                                                float* __restrict__ V) {
  __shared__ __align__(16) float As[16][64];   // As[kk][m] (transposed)
  __shared__ __align__(16) float Bs[16][64];   // Bs[kk][n]
  const int tid = threadIdx.x;
  const int tx = tid & 15, ty = tid >> 4;
  const int m0 = blockIdx.y * 64, n0 = blockIdx.x * 64;
  float acc[4][4] = {};
  for (int k0 = 0; k0 < DIMM; k0 += 16) {
    { // stage A: 64 rows x 16 cols, one float4 per thread, transposed store
      int r = tid >> 2, c4 = tid & 3;
      float4 a4 = *(const float4*)(X + (size_t)(m0 + r) * DIMM + k0 + c4 * 4);
      As[c4 * 4 + 0][r] = a4.x; As[c4 * 4 + 1][r] = a4.y;
      As[c4 * 4 + 2][r] = a4.z; As[c4 * 4 + 3][r] = a4.w;
      // stage B: 16 rows x 64 cols
      int kk = tid >> 4, n4 = tid & 15;
      *(float4*)(&Bs[kk][n4 * 4]) =
          *(const float4*)(W + (size_t)(k0 + kk) * NQKV + n0 + n4 * 4);
    }
    __syncthreads();
#pragma unroll
    for (int kk = 0; kk < 16; ++kk) {
      float4 a = *(const float4*)(&As[kk][ty * 4]);
      float4 b = *(const float4*)(&Bs[kk][tx * 4]);
      float av[4] = {a.x, a.y, a.z, a.w};
      float bv[4] = {b.x, b.y, b.z, b.w};
#pragma unroll
      for (int i = 0; i < 4; ++i)
#pragma unroll
        for (int j = 0; j < 4; ++j) acc[i][j] += av[i] * bv[j];
    }
    __syncthreads();
  }
  // epilogue scatter: col -> (chunk, head, dd); fold QK scale into Q
  const int cbase = n0 + tx * 4;
  const int chunk = cbase / 512;
  const int within = cbase % 512;
  const int hh = within / 64, dd = within % 64;
  float* dst = (chunk == 0) ? Q : (chunk == 1) ? K : V;
  const float sc = (chunk == 0) ? QK_SCALE : 1.f;
#pragma unroll
  for (int i = 0; i < 4; ++i) {
    int m = m0 + ty * 4 + i;
    int bb = m >> 11, ii = m & (SEQ - 1);
    float4 o;
    o.x = acc[i][0] * sc; o.y = acc[i][1] * sc;
    o.z = acc[i][2] * sc; o.w = acc[i][3] * sc;
    *(float4*)(dst + ((size_t)((bb * HEADS + hh) * SEQ + ii) * DHEAD + dd)) = o;
  }
}

// ---------------- flash attention, 64-query tile per block -------------------
// XOR swizzle: float4-group g of row r stored at group (g ^ (r&15) ^ (r>>4))
__device__ __forceinline__ int swz4(int r, int g) {
  return r * 64 + ((g ^ (r & 15) ^ (r >> 4)) << 2);
}

__global__ __launch_bounds__(256) void attn(const float* __restrict__ Q,
                                            const float* __restrict__ K,
                                            const float* __restrict__ V,
                                            const float* __restrict__ maskf,
                                            float* __restrict__ O) {
  __shared__ __align__(16) float Qs[4096], Ks[4096], Vs[4096], Ps[4096];
  __shared__ float skm[64];
  const int tid = threadIdx.x;
  const int tx = tid & 15, ty = tid >> 4;
  const int qb = blockIdx.x;          // 0..31
  const int bh = blockIdx.y;          // 0..15 = b*8+h
  const int bb = bh >> 3;
  const float* Qb = Q + (size_t)bh * SEQ * DHEAD;
  const float* Kb = K + (size_t)bh * SEQ * DHEAD;
  const float* Vb = V + (size_t)bh * SEQ * DHEAD;

  // stage Q tile (swizzled)
#pragma unroll
  for (int it = 0; it < 4; ++it) {
    int f = tid + it * 256;           // float4 index
    int r = f >> 4, g = f & 15;
    float4 v = *(const float4*)(Qb + (size_t)(qb * 64 + r) * DHEAD + g * 4);
    *(float4*)(&Qs[swz4(r, g)]) = v;
  }

  float o[4][4] = {};
  float mrow[4], lrow[4];
#pragma unroll
  for (int i = 0; i < 4; ++i) { mrow[i] = -FLT_MAX; lrow[i] = 0.f; }

  for (int kt = 0; kt < SEQ / 64; ++kt) {
    __syncthreads();                  // protect Ks/Vs/Ps (and Q store on kt=0)
#pragma unroll
    for (int it = 0; it < 4; ++it) {
      int f = tid + it * 256;
      int r = f >> 4, g = f & 15;
      float4 kv = *(const float4*)(Kb + (size_t)(kt * 64 + r) * DHEAD + g * 4);
      *(float4*)(&Ks[swz4(r, g)]) = kv;
      float4 vv = *(const float4*)(Vb + (size_t)(kt * 64 + r) * DHEAD + g * 4);
      *(float4*)(&Vs[swz4(r, g)]) = vv;
    }
    if (tid < 64) skm[tid] = maskf[bb * SEQ + kt * 64 + tid];
    __syncthreads();

    // S = Q K^T  (K-dim = 64 head dims), rows 4ty+i, cols 4tx+j
    float s[4][4] = {};
#pragma unroll
    for (int g = 0; g < 16; ++g) {
      float4 qv[4], kv[4];
#pragma unroll
      for (int i = 0; i < 4; ++i) qv[i] = *(const float4*)(&Qs[swz4(ty * 4 + i, g)]);
#pragma unroll
      for (int j = 0; j < 4; ++j) kv[j] = *(const float4*)(&Ks[swz4(tx * 4 + j, g)]);
#pragma unroll
      for (int i = 0; i < 4; ++i)
#pragma unroll
        for (int j = 0; j < 4; ++j)
          s[i][j] += qv[i].x * kv[j].x + qv[i].y * kv[j].y +
                     qv[i].z * kv[j].z + qv[i].w * kv[j].w;
    }

    // key mask + online softmax (row stats shared across 16 lanes of same ty)
    float km[4];
#pragma unroll
    for (int j = 0; j < 4; ++j) km[j] = skm[tx * 4 + j];
#pragma unroll
    for (int i = 0; i < 4; ++i) {
#pragma unroll
      for (int j = 0; j < 4; ++j)
        if (km[j] == 0.f) s[i][j] = -FLT_MAX;
      float rm = fmaxf(fmaxf(s[i][0], s[i][1]), fmaxf(s[i][2], s[i][3]));
      rm = fmaxf(rm, __shfl_xor(rm, 1));
      rm = fmaxf(rm, __shfl_xor(rm, 2));
      rm = fmaxf(rm, __shfl_xor(rm, 4));
      rm = fmaxf(rm, __shfl_xor(rm, 8));
      float mnew = fmaxf(mrow[i], rm);
      float resc = __expf(mrow[i] - mnew);
      float rs = 0.f;
#pragma unroll
      for (int j = 0; j < 4; ++j) {
        float p = __expf(s[i][j] - mnew);
        s[i][j] = p;
        rs += p;
      }
      rs += __shfl_xor(rs, 1); rs += __shfl_xor(rs, 2);
      rs += __shfl_xor(rs, 4); rs += __shfl_xor(rs, 8);
      lrow[i] = lrow[i] * resc + rs;
      mrow[i] = mnew;
#pragma unroll
      for (int j = 0; j < 4; ++j) o[i][j] *= resc;
    }

    // write P (swizzled, scalar)
#pragma unroll
    for (int i = 0; i < 4; ++i) {
      int r = ty * 4 + i;
#pragma unroll
      for (int j = 0; j < 4; ++j) {
        int c = tx * 4 + j;
        Ps[swz4(r, c >> 2) + (c & 3)] = s[i][j];
      }
    }
    __syncthreads();

    // O += P @ V  (K-dim = 64 keys)
#pragma unroll
    for (int g = 0; g < 16; ++g) {
      float4 pv[4], vv[4];
#pragma unroll
      for (int i = 0; i < 4; ++i) pv[i] = *(const float4*)(&Ps[swz4(ty * 4 + i, g)]);
#pragma unroll
      for (int u = 0; u < 4; ++u) {
        int kk = g * 4 + u;
        vv[u] = *(const float4*)(&Vs[swz4(kk, tx)]);
      }
#pragma unroll
      for (int i = 0; i < 4; ++i) {
        float pp[4] = {pv[i].x, pv[i].y, pv[i].z, pv[i].w};
#pragma unroll
        for (int u = 0; u < 4; ++u) {
          o[i][0] += pp[u] * vv[u].x;
          o[i][1] += pp[u] * vv[u].y;
          o[i][2] += pp[u] * vv[u].z;
          o[i][3] += pp[u] * vv[u].w;
        }
      }
    }
  }

  // epilogue: normalize rows, store O (b,h,n,d)
#pragma unroll
  for (int i = 0; i < 4; ++i) {
    int r = qb * 64 + ty * 4 + i;
    float inv = 1.f / lrow[i];
    float4 ov;
    ov.x = o[i][0] * inv; ov.y = o[i][1] * inv;
    ov.z = o[i][2] * inv; ov.w = o[i][3] * inv;
    *(float4*)(O + ((size_t)bh * SEQ + r) * DHEAD + tx * 4) = ov;
  }
}

// ---------------- depthwise conv residual: O += conv(V) ----------------------
__global__ __launch_bounds__(256) void conv_res(const float* __restrict__ V,
                                                const float* __restrict__ cw,
                                                float* __restrict__ O) {
  int gid = blockIdx.x * blockDim.x + threadIdx.x;   // over B*H*SEQ*16 float4s
  const int total = BATCH * HEADS * SEQ * (DHEAD / 4);
  if (gid >= total) return;
  int d4 = gid & 15;
  int rest = gid >> 4;                 // bh*SEQ + i
  int i = rest & (SEQ - 1);
  int bh = rest >> 11;
  int hh = bh & 7;
  const float* vb = V + (size_t)bh * SEQ * DHEAD + d4 * 4;
  float4 acc = *(float4*)(O + (size_t)gid * 4);
#pragma unroll
  for (int t = 0; t < 33; ++t) {
    int row = i + t - 16;
    if (row >= 0 && row < SEQ) {
      float w = cw[hh * 33 + t];
      float4 v = *(const float4*)(vb + (size_t)row * DHEAD);
      acc.x += w * v.x; acc.y += w * v.y; acc.z += w * v.z; acc.w += w * v.w;
    }
  }
  *(float4*)(O + (size_t)gid * 4) = acc;
}

// ---------------- out GEMM: O(b,h,n,d)->A(4096x512) @ W(512x512) + bias ------
__global__ __launch_bounds__(256) void gemm_out(const float* __restrict__ O,
                                                const float* __restrict__ W,
                                                const float* __restrict__ bias,
                                                const float* __restrict__ maskf,
                                                float* __restrict__ out) {
  __shared__ __align__(16) float As[16][64];
  __shared__ __align__(16) float Bs[16][64];
  const int tid = threadIdx.x;
  const int tx = tid & 15, ty = tid >> 4;
  const int m0 = blockIdx.y * 64, n0 = blockIdx.x * 64;
  float acc[4][4] = {};
  for (int k0 = 0; k0 < DIMM; k0 += 16) {
    const int hh = k0 >> 6, dd0 = k0 & 63;
    {
      int r = tid >> 2, c4 = tid & 3;
      int m = m0 + r;
      int bb = m >> 11, ii = m & (SEQ - 1);
      float4 a4 = *(const float4*)(
          O + (size_t)((bb * HEADS + hh) * SEQ + ii) * DHEAD + dd0 + c4 * 4);
      As[c4 * 4 + 0][r] = a4.x; As[c4 * 4 + 1][r] = a4.y;
      As[c4 * 4 + 2][r] = a4.z; As[c4 * 4 + 3][r] = a4.w;
      int kk = tid >> 4, n4 = tid & 15;
      *(float4*)(&Bs[kk][n4 * 4]) =
          *(const float4*)(W + (size_t)(k0 + kk) * DIMM + n0 + n4 * 4);
    }
    __syncthreads();
#pragma unroll
    for (int kk = 0; kk < 16; ++kk) {
      float4 a = *(const float4*)(&As[kk][ty * 4]);
      float4 b = *(const float4*)(&Bs[kk][tx * 4]);
      float av[4] = {a.x, a.y, a.z, a.w};
      float bv[4] = {b.x, b.y, b.z, b.w};
#pragma unroll
      for (int i = 0; i < 4; ++i)
#pragma unroll
        for (int j = 0; j < 4; ++j) acc[i][j] += av[i] * bv[j];
    }
    __syncthreads();
  }
#pragma unroll
  for (int i = 0; i < 4; ++i) {
    int m = m0 + ty * 4 + i;
    float mk = maskf[m];              // query-position mask
    int c = n0 + tx * 4;
    float4 ov;
    ov.x = (acc[i][0] + bias[c + 0]) * mk;
    ov.y = (acc[i][1] + bias[c + 1]) * mk;
    ov.z = (acc[i][2] + bias[c + 2]) * mk;
    ov.w = (acc[i][3] + bias[c + 3]) * mk;
    *(float4*)(out + (size_t)m * DIMM + c) = ov;
  }
}

extern "C" void kernel_launch(void* const* d_in, const int* in_sizes, int n_in,
                              void* d_out, int out_size, void* d_ws, size_t ws_size,
                              hipStream_t stream) {
  const float* x     = (const float*)d_in[0];
  const void*  mask  = d_in[1];
  const float* Wqkv  = (const float*)d_in[2];
  const float* Wout  = (const float*)d_in[3];
  const float* bout  = (const float*)d_in[4];
  const float* convw = (const float*)d_in[5];
  float* out = (float*)d_out;

  float* ws    = (float*)d_ws;
  float* maskf = ws;
  float* Q = ws + 4096;
  float* K = Q + QKV_ELEMS;
  float* V = K + QKV_ELEMS;
  float* O = V + QKV_ELEMS;

  prep_mask<<<1, 1024, 0, stream>>>(mask, maskf);
  gemm_qkv<<<dim3(NQKV / 64, (BATCH * SEQ) / 64), 256, 0, stream>>>(x, Wqkv, Q, K, V);
  attn<<<dim3(SEQ / 64, BATCH * HEADS), 256, 0, stream>>>(Q, K, V, maskf, O);
  conv_res<<<(BATCH * HEADS * SEQ * (DHEAD / 4)) / 256, 256, 0, stream>>>(V, convw, O);
  gemm_out<<<dim3(DIMM / 64, (BATCH * SEQ) / 64), 256, 0, stream>>>(O, Wout, bout, maskf, out);
}

// Round 2
// 234.089 us; speedup vs baseline: 3.1856x; 3.1856x over previous
//
#include <hip/hip_runtime.h>
#include <float.h>

#define BATCH 2
#define SEQ   2048
#define HEADS 8
#define DHEAD 64
#define DIMM  512
#define NQKV  1536
#define QK_SCALE 0.125f   // 64^-0.5

#define QKV_ELEMS ((size_t)BATCH * HEADS * SEQ * DHEAD)   // 2097152

typedef __bf16 bf16x8 __attribute__((ext_vector_type(8)));
typedef float  f32x4  __attribute__((ext_vector_type(4)));

__device__ __forceinline__ unsigned short f2bf(float f) {
  unsigned u = __float_as_uint(f);
  unsigned r = (u + 0x7fffu + ((u >> 16) & 1u)) >> 16;   // RNE
  return (unsigned short)r;
}

// ---------------- mask prep: sniff dtype, normalize to float 0/1 -------------
__global__ __launch_bounds__(1024) void prep_mask(const void* __restrict__ mraw,
                                                  float* __restrict__ maskf) {
  __shared__ int f_bf16, f_f32, f_gt1, f_oddnz;
  const int t = threadIdx.x;
  if (t == 0) { f_bf16 = 0; f_f32 = 0; f_gt1 = 0; f_oddnz = 0; }
  __syncthreads();
  const unsigned int* w = (const unsigned int*)mraw;
  unsigned int v = w[t];
  if (v == 0x3f803f80u) f_bf16 = 1;
  if (v == 0x3f800000u) f_f32 = 1;
  if (v > 1u)           f_gt1 = 1;
  if ((t & 1) && v != 0u) f_oddnz = 1;
  __syncthreads();
  int mode;                               // 0=i32 1=u8 2=i64 3=f32 4=bf16
  if (f_bf16)       mode = 4;
  else if (f_f32)   mode = 3;
  else if (f_gt1)   mode = 1;
  else if (!f_oddnz) mode = 2;
  else              mode = 0;
  for (int i = t; i < BATCH * SEQ; i += 1024) {
    bool keep;
    if (mode == 4)      keep = ((const unsigned short*)mraw)[i] != 0;
    else if (mode == 3) keep = ((const float*)mraw)[i] != 0.f;
    else if (mode == 1) keep = ((const unsigned char*)mraw)[i] != 0;
    else if (mode == 2) keep = w[2 * i] != 0u;
    else                keep = w[i] != 0u;
    maskf[i] = keep ? 1.f : 0.f;
  }
}

// ---------------- qkv GEMM: X(4096x512) @ W(512x1536) -----------------------
// outputs: Qbf bf16 (b,h,n,d) pre-scaled; Kbf bf16 (b,h,n,d); V fp32 (b,h,n,d);
//          Vt bf16 (b,h,d,n)
__global__ __launch_bounds__(256) void gemm_qkv(const float* __restrict__ X,
                                                const float* __restrict__ W,
                                                unsigned short* __restrict__ Qbf,
                                                unsigned short* __restrict__ Kbf,
                                                float* __restrict__ V,
                                                unsigned short* __restrict__ Vt) {
  __shared__ __align__(16) float As[16][64];
  __shared__ __align__(16) float Bs[16][64];
  const int tid = threadIdx.x;
  const int tx = tid & 15, ty = tid >> 4;
  const int m0 = blockIdx.y * 64, n0 = blockIdx.x * 64;
  float acc[4][4] = {};
  for (int k0 = 0; k0 < DIMM; k0 += 16) {
    {
      int r = tid >> 2, c4 = tid & 3;
      float4 a4 = *(const float4*)(X + (size_t)(m0 + r) * DIMM + k0 + c4 * 4);
      As[c4 * 4 + 0][r] = a4.x; As[c4 * 4 + 1][r] = a4.y;
      As[c4 * 4 + 2][r] = a4.z; As[c4 * 4 + 3][r] = a4.w;
      int kk = tid >> 4, n4 = tid & 15;
      *(float4*)(&Bs[kk][n4 * 4]) =
          *(const float4*)(W + (size_t)(k0 + kk) * NQKV + n0 + n4 * 4);
    }
    __syncthreads();
#pragma unroll
    for (int kk = 0; kk < 16; ++kk) {
      float4 a = *(const float4*)(&As[kk][ty * 4]);
      float4 b = *(const float4*)(&Bs[kk][tx * 4]);
      float av[4] = {a.x, a.y, a.z, a.w};
      float bv[4] = {b.x, b.y, b.z, b.w};
#pragma unroll
      for (int i = 0; i < 4; ++i)
#pragma unroll
        for (int j = 0; j < 4; ++j) acc[i][j] += av[i] * bv[j];
    }
    __syncthreads();
  }
  const int cbase = n0 + tx * 4;
  const int chunk = cbase >> 9;         // 0=Q 1=K 2=V
  const int within = cbase & 511;
  const int hh = within >> 6, dd = within & 63;
#pragma unroll
  for (int i = 0; i < 4; ++i) {
    int m = m0 + ty * 4 + i;
    int bb = m >> 11, ii = m & (SEQ - 1);
    size_t base = ((size_t)(bb * HEADS + hh) * SEQ + ii) * DHEAD + dd;
    if (chunk == 0) {
      ushort4 q;
      q.x = f2bf(acc[i][0] * QK_SCALE); q.y = f2bf(acc[i][1] * QK_SCALE);
      q.z = f2bf(acc[i][2] * QK_SCALE); q.w = f2bf(acc[i][3] * QK_SCALE);
      *(ushort4*)(Qbf + base) = q;
    } else if (chunk == 1) {
      ushort4 kq;
      kq.x = f2bf(acc[i][0]); kq.y = f2bf(acc[i][1]);
      kq.z = f2bf(acc[i][2]); kq.w = f2bf(acc[i][3]);
      *(ushort4*)(Kbf + base) = kq;
    } else {
      float4 o4; o4.x = acc[i][0]; o4.y = acc[i][1]; o4.z = acc[i][2]; o4.w = acc[i][3];
      *(float4*)(V + base) = o4;
    }
  }
  if (chunk == 2) {
    // transposed bf16 V: Vt[(bb,hh,d),n], pack 4 consecutive n (i-dim)
    int bb = m0 >> 11;
    int iibase = m0 & (SEQ - 1);
#pragma unroll
    for (int j = 0; j < 4; ++j) {
      int d = dd + j;
      ushort4 t;
      t.x = f2bf(acc[0][j]); t.y = f2bf(acc[1][j]);
      t.z = f2bf(acc[2][j]); t.w = f2bf(acc[3][j]);
      *(ushort4*)(Vt + ((size_t)((bb * HEADS + hh) * DHEAD + d) * SEQ) + iibase + ty * 4) = t;
    }
  }
}

// ---------------- flash attention with bf16 MFMA -----------------------------
// Per block: 64 queries, 4 waves (wave w owns query rows w*16..w*16+15).
// KV tile = 64 keys. LDS rows 128B, XOR-swizzled: byte_col ^= (row&7)<<4.
__global__ __launch_bounds__(256) void attn_mfma(const unsigned short* __restrict__ Qbf,
                                                 const unsigned short* __restrict__ Kbf,
                                                 const unsigned short* __restrict__ Vt,
                                                 const float* __restrict__ maskf,
                                                 float* __restrict__ O) {
  __shared__ __align__(16) unsigned char Ks[8192];
  __shared__ __align__(16) unsigned char Vs[8192];
  __shared__ __align__(16) unsigned char Ps[8192];
  __shared__ float skm[64];

  const int tid = threadIdx.x;
  const int lane = tid & 63;
  const int w = tid >> 6;
  const int l15 = lane & 15, g = lane >> 4;

  // XCD-chunked bijective swizzle (512 blocks, 8 XCDs -> 64-block chunks)
  int fid = blockIdx.x;
  int lid = (fid & 7) * 64 + (fid >> 3);
  const int bh = lid >> 5;           // 0..15
  const int qb = lid & 31;           // 0..31
  const int bb = bh >> 3;

  const unsigned short* Qg = Qbf + ((size_t)bh * SEQ + qb * 64) * DHEAD;
  const unsigned short* Kg = Kbf + (size_t)bh * SEQ * DHEAD;
  const unsigned short* Vg = Vt  + (size_t)bh * DHEAD * SEQ;

  // Q fragments (held in registers for the whole kernel)
  bf16x8 qf0, qf1;
  {
    const unsigned char* qrow = (const unsigned char*)(Qg + (size_t)(w * 16 + l15) * DHEAD);
    qf0 = *(const bf16x8*)(qrow + g * 16);
    qf1 = *(const bf16x8*)(qrow + 64 + g * 16);
  }

  f32x4 o[4];
  float mrow[4], lrow[4];
#pragma unroll
  for (int j = 0; j < 4; ++j) { o[j] = (f32x4){0.f, 0.f, 0.f, 0.f}; }
#pragma unroll
  for (int r = 0; r < 4; ++r) { mrow[r] = -3.0e38f; lrow[r] = 0.f; }

  const int sm = tid >> 2;             // staging row 0..63
  const int sc = (tid & 3) * 32;       // staging col byte 0/32/64/96
  const int ssw = (sm & 7) << 4;
  const int rsw = (l15 & 7) << 4;      // read swizzle (rows indexed by l15)

  for (int kt = 0; kt < SEQ / 64; ++kt) {
    __syncthreads();
    {
      const unsigned char* ksrc =
          (const unsigned char*)(Kg + (size_t)kt * 64 * DHEAD) + sm * 128 + sc;
      const unsigned char* vsrc =
          (const unsigned char*)(Vg + (size_t)sm * SEQ + kt * 64) + sc;
      *(int4*)(Ks + sm * 128 + ((sc)      ^ ssw)) = *(const int4*)(ksrc);
      *(int4*)(Ks + sm * 128 + ((sc + 16) ^ ssw)) = *(const int4*)(ksrc + 16);
      *(int4*)(Vs + sm * 128 + ((sc)      ^ ssw)) = *(const int4*)(vsrc);
      *(int4*)(Vs + sm * 128 + ((sc + 16) ^ ssw)) = *(const int4*)(vsrc + 16);
      if (tid < 64) skm[tid] = maskf[bb * SEQ + kt * 64 + tid];
    }
    __syncthreads();

    // S = Q K^T : wave strip 16 q-rows x 64 keys (4 col tiles, Kdim 64 = 2 mfma)
    f32x4 s[4];
#pragma unroll
    for (int j = 0; j < 4; ++j) {
      const unsigned char* krow = Ks + (16 * j + l15) * 128;
      bf16x8 kf0 = *(const bf16x8*)(krow + ((g * 16)      ^ rsw));
      bf16x8 kf1 = *(const bf16x8*)(krow + ((64 + g * 16) ^ rsw));
      f32x4 z = (f32x4){0.f, 0.f, 0.f, 0.f};
      z = __builtin_amdgcn_mfma_f32_16x16x32_bf16(qf0, kf0, z, 0, 0, 0);
      z = __builtin_amdgcn_mfma_f32_16x16x32_bf16(qf1, kf1, z, 0, 0, 0);
      s[j] = z;
    }

    // key mask + online softmax; lane holds rows g*4+r, cols 16j+l15
    float km0 = skm[l15], km1 = skm[16 + l15], km2 = skm[32 + l15], km3 = skm[48 + l15];
#pragma unroll
    for (int r = 0; r < 4; ++r) {
      float v0 = (km0 != 0.f) ? s[0][r] : -1e30f;
      float v1 = (km1 != 0.f) ? s[1][r] : -1e30f;
      float v2 = (km2 != 0.f) ? s[2][r] : -1e30f;
      float v3 = (km3 != 0.f) ? s[3][r] : -1e30f;
      float rm = fmaxf(fmaxf(v0, v1), fmaxf(v2, v3));
      rm = fmaxf(rm, __shfl_xor(rm, 1));
      rm = fmaxf(rm, __shfl_xor(rm, 2));
      rm = fmaxf(rm, __shfl_xor(rm, 4));
      rm = fmaxf(rm, __shfl_xor(rm, 8));
      float mnew = fmaxf(mrow[r], rm);
      float resc = __expf(mrow[r] - mnew);
      float p0 = __expf(v0 - mnew) * km0;
      float p1 = __expf(v1 - mnew) * km1;
      float p2 = __expf(v2 - mnew) * km2;
      float p3 = __expf(v3 - mnew) * km3;
      float rs = (p0 + p1) + (p2 + p3);
      rs += __shfl_xor(rs, 1);
      rs += __shfl_xor(rs, 2);
      rs += __shfl_xor(rs, 4);
      rs += __shfl_xor(rs, 8);
      lrow[r] = lrow[r] * resc + rs;
      mrow[r] = mnew;
      o[0][r] *= resc; o[1][r] *= resc; o[2][r] *= resc; o[3][r] *= resc;

      // write P row pm = w*16 + g*4 + r (bf16, swizzled)
      int pm = w * 16 + g * 4 + r;
      unsigned char* prow = Ps + pm * 128;
      int psw = (pm & 7) << 4;
      *(unsigned short*)(prow + ((2 * (l15)      ) ^ psw)) = f2bf(p0);
      *(unsigned short*)(prow + ((2 * (16 + l15) ) ^ psw)) = f2bf(p1);
      *(unsigned short*)(prow + ((2 * (32 + l15) ) ^ psw)) = f2bf(p2);
      *(unsigned short*)(prow + ((2 * (48 + l15) ) ^ psw)) = f2bf(p3);
    }

    // O += P @ V : A = P rows (wave-private, same-wave LDS RAW -> waitcnt only)
    {
      const unsigned char* parow = Ps + (w * 16 + l15) * 128;
      bf16x8 pa0 = *(const bf16x8*)(parow + ((g * 16)      ^ rsw));
      bf16x8 pa1 = *(const bf16x8*)(parow + ((64 + g * 16) ^ rsw));
#pragma unroll
      for (int j = 0; j < 4; ++j) {
        const unsigned char* vrow = Vs + (16 * j + l15) * 128;
        bf16x8 vf0 = *(const bf16x8*)(vrow + ((g * 16)      ^ rsw));
        bf16x8 vf1 = *(const bf16x8*)(vrow + ((64 + g * 16) ^ rsw));
        o[j] = __builtin_amdgcn_mfma_f32_16x16x32_bf16(pa0, vf0, o[j], 0, 0, 0);
        o[j] = __builtin_amdgcn_mfma_f32_16x16x32_bf16(pa1, vf1, o[j], 0, 0, 0);
      }
    }
  }

  // epilogue: normalize, store O fp32 (b,h,n,d)
#pragma unroll
  for (int r = 0; r < 4; ++r) {
    float inv = 1.f / lrow[r];
    int row = qb * 64 + w * 16 + g * 4 + r;
    float* dst = O + ((size_t)bh * SEQ + row) * DHEAD + l15;
    dst[0]  = o[0][r] * inv;
    dst[16] = o[1][r] * inv;
    dst[32] = o[2][r] * inv;
    dst[48] = o[3][r] * inv;
  }
}

// ---------------- depthwise conv residual: O += conv(V) ----------------------
__global__ __launch_bounds__(256) void conv_res(const float* __restrict__ V,
                                                const float* __restrict__ cw,
                                                float* __restrict__ O) {
  int gid = blockIdx.x * blockDim.x + threadIdx.x;
  const int total = BATCH * HEADS * SEQ * (DHEAD / 4);
  if (gid >= total) return;
  int d4 = gid & 15;
  int rest = gid >> 4;
  int i = rest & (SEQ - 1);
  int bh = rest >> 11;
  int hh = bh & 7;
  const float* vb = V + (size_t)bh * SEQ * DHEAD + d4 * 4;
  float4 acc = *(float4*)(O + (size_t)gid * 4);
#pragma unroll
  for (int t = 0; t < 33; ++t) {
    int row = i + t - 16;
    if (row >= 0 && row < SEQ) {
      float w = cw[hh * 33 + t];
      float4 v = *(const float4*)(vb + (size_t)row * DHEAD);
      acc.x += w * v.x; acc.y += w * v.y; acc.z += w * v.z; acc.w += w * v.w;
    }
  }
  *(float4*)(O + (size_t)gid * 4) = acc;
}

// ---------------- out GEMM: O(b,h,n,d)->A(4096x512) @ W(512x512) + bias ------
__global__ __launch_bounds__(256) void gemm_out(const float* __restrict__ O,
                                                const float* __restrict__ W,
                                                const float* __restrict__ bias,
                                                const float* __restrict__ maskf,
                                                float* __restrict__ out) {
  __shared__ __align__(16) float As[16][64];
  __shared__ __align__(16) float Bs[16][64];
  const int tid = threadIdx.x;
  const int tx = tid & 15, ty = tid >> 4;
  const int m0 = blockIdx.y * 64, n0 = blockIdx.x * 64;
  float acc[4][4] = {};
  for (int k0 = 0; k0 < DIMM; k0 += 16) {
    const int hh = k0 >> 6, dd0 = k0 & 63;
    {
      int r = tid >> 2, c4 = tid & 3;
      int m = m0 + r;
      int bb = m >> 11, ii = m & (SEQ - 1);
      float4 a4 = *(const float4*)(
          O + (size_t)((bb * HEADS + hh) * SEQ + ii) * DHEAD + dd0 + c4 * 4);
      As[c4 * 4 + 0][r] = a4.x; As[c4 * 4 + 1][r] = a4.y;
      As[c4 * 4 + 2][r] = a4.z; As[c4 * 4 + 3][r] = a4.w;
      int kk = tid >> 4, n4 = tid & 15;
      *(float4*)(&Bs[kk][n4 * 4]) =
          *(const float4*)(W + (size_t)(k0 + kk) * DIMM + n0 + n4 * 4);
    }
    __syncthreads();
#pragma unroll
    for (int kk = 0; kk < 16; ++kk) {
      float4 a = *(const float4*)(&As[kk][ty * 4]);
      float4 b = *(const float4*)(&Bs[kk][tx * 4]);
      float av[4] = {a.x, a.y, a.z, a.w};
      float bv[4] = {b.x, b.y, b.z, b.w};
#pragma unroll
      for (int i = 0; i < 4; ++i)
#pragma unroll
        for (int j = 0; j < 4; ++j) acc[i][j] += av[i] * bv[j];
    }
    __syncthreads();
  }
#pragma unroll
  for (int i = 0; i < 4; ++i) {
    int m = m0 + ty * 4 + i;
    float mk = maskf[m];
    int c = n0 + tx * 4;
    float4 ov;
    ov.x = (acc[i][0] + bias[c + 0]) * mk;
    ov.y = (acc[i][1] + bias[c + 1]) * mk;
    ov.z = (acc[i][2] + bias[c + 2]) * mk;
    ov.w = (acc[i][3] + bias[c + 3]) * mk;
    *(float4*)(out + (size_t)m * DIMM + c) = ov;
  }
}

extern "C" void kernel_launch(void* const* d_in, const int* in_sizes, int n_in,
                              void* d_out, int out_size, void* d_ws, size_t ws_size,
                              hipStream_t stream) {
  const float* x     = (const float*)d_in[0];
  const void*  mask  = d_in[1];
  const float* Wqkv  = (const float*)d_in[2];
  const float* Wout  = (const float*)d_in[3];
  const float* bout  = (const float*)d_in[4];
  const float* convw = (const float*)d_in[5];
  float* out = (float*)d_out;

  float* ws    = (float*)d_ws;
  float* maskf = ws;
  float* V = ws + 4096;
  float* O = V + QKV_ELEMS;
  unsigned short* Qbf = (unsigned short*)(O + QKV_ELEMS);
  unsigned short* Kbf = Qbf + QKV_ELEMS;
  unsigned short* Vt  = Kbf + QKV_ELEMS;

  prep_mask<<<1, 1024, 0, stream>>>(mask, maskf);
  gemm_qkv<<<dim3(NQKV / 64, (BATCH * SEQ) / 64), 256, 0, stream>>>(x, Wqkv, Qbf, Kbf, V, Vt);
  attn_mfma<<<512, 256, 0, stream>>>(Qbf, Kbf, Vt, maskf, O);
  conv_res<<<(BATCH * HEADS * SEQ * (DHEAD / 4)) / 256, 256, 0, stream>>>(V, convw, O);
  gemm_out<<<dim3(DIMM / 64, (BATCH * SEQ) / 64), 256, 0, stream>>>(O, Wout, bout, maskf, out);
}

// Round 3
// 155.504 us; speedup vs baseline: 4.7954x; 1.5054x over previous
//
#include <hip/hip_runtime.h>
#include <float.h>

#define BATCH 2
#define SEQ   2048
#define HEADS 8
#define DHEAD 64
#define DIMM  512
#define NQKV  1536
#define QK_SCALE 0.125f   // 64^-0.5

#define QKV_ELEMS ((size_t)BATCH * HEADS * SEQ * DHEAD)   // 2097152

typedef __bf16 bf16x8 __attribute__((ext_vector_type(8)));
typedef float  f32x4  __attribute__((ext_vector_type(4)));

__device__ __forceinline__ unsigned short f2bf(float f) {
  unsigned u = __float_as_uint(f);
  unsigned r = (u + 0x7fffu + ((u >> 16) & 1u)) >> 16;   // RNE
  return (unsigned short)r;
}

// ---------------- mask prep: sniff dtype, normalize to float 0/1 -------------
__global__ __launch_bounds__(1024) void prep_mask(const void* __restrict__ mraw,
                                                  float* __restrict__ maskf) {
  __shared__ int f_bf16, f_f32, f_gt1, f_oddnz;
  const int t = threadIdx.x;
  if (t == 0) { f_bf16 = 0; f_f32 = 0; f_gt1 = 0; f_oddnz = 0; }
  __syncthreads();
  const unsigned int* w = (const unsigned int*)mraw;
  unsigned int v = w[t];
  if (v == 0x3f803f80u) f_bf16 = 1;
  if (v == 0x3f800000u) f_f32 = 1;
  if (v > 1u)           f_gt1 = 1;
  if ((t & 1) && v != 0u) f_oddnz = 1;
  __syncthreads();
  int mode;                               // 0=i32 1=u8 2=i64 3=f32 4=bf16
  if (f_bf16)       mode = 4;
  else if (f_f32)   mode = 3;
  else if (f_gt1)   mode = 1;
  else if (!f_oddnz) mode = 2;
  else              mode = 0;
  for (int i = t; i < BATCH * SEQ; i += 1024) {
    bool keep;
    if (mode == 4)      keep = ((const unsigned short*)mraw)[i] != 0;
    else if (mode == 3) keep = ((const float*)mraw)[i] != 0.f;
    else if (mode == 1) keep = ((const unsigned char*)mraw)[i] != 0;
    else if (mode == 2) keep = w[2 * i] != 0u;
    else                keep = w[i] != 0u;
    maskf[i] = keep ? 1.f : 0.f;
  }
}

// ---------------- weight transpose+convert: W fp32 [K][N] -> Wt bf16 [N][K] --
__global__ __launch_bounds__(256) void transpose_w(const float* __restrict__ W,
                                                   unsigned short* __restrict__ Wt,
                                                   int K, int N) {
  __shared__ float T[64][65];
  const int t = threadIdx.x;
  const int n0 = blockIdx.x * 64, k0 = blockIdx.y * 64;
  {
    int r0 = t >> 4, c4 = t & 15;
#pragma unroll
    for (int rr = 0; rr < 4; ++rr) {
      int r = r0 + rr * 16;
      float4 v = *(const float4*)(W + (size_t)(k0 + r) * N + n0 + c4 * 4);
      T[r][c4 * 4 + 0] = v.x; T[r][c4 * 4 + 1] = v.y;
      T[r][c4 * 4 + 2] = v.z; T[r][c4 * 4 + 3] = v.w;
    }
  }
  __syncthreads();
  {
    int n = t >> 2, kc = t & 3;
    union { unsigned short u[16]; int4 v[2]; } p;
#pragma unroll
    for (int i = 0; i < 16; ++i) p.u[i] = f2bf(T[kc * 16 + i][n]);
    int4* dst = (int4*)(Wt + (size_t)(n0 + n) * K + k0 + kc * 16);
    dst[0] = p.v[0]; dst[1] = p.v[1];
  }
}

// ---------------- qkv GEMM (MFMA): Xbf-onfly @ Wt^T -> Q,K bf16; V f32; Vt bf16
__global__ __launch_bounds__(256) void gemm_qkv_mfma(
    const float* __restrict__ X, const unsigned short* __restrict__ Wt,
    unsigned short* __restrict__ Qbf, unsigned short* __restrict__ Kbf,
    float* __restrict__ V, unsigned short* __restrict__ Vt) {
  __shared__ __align__(16) unsigned char Al[128 * 128];
  __shared__ __align__(16) unsigned char Bl[128 * 128];
  const int tid = threadIdx.x;
  const int lane = tid & 63;
  const int w = tid >> 6;
  const int l15 = lane & 15, g = lane >> 4;
  const int wr = w >> 1, wc = w & 1;
  int bid = blockIdx.x;                   // 384 blocks, 384%8==0 -> bijective
  int lid = (bid & 7) * 48 + (bid >> 3);
  int by = lid / 12, bx = lid - by * 12;
  const int m0 = by * 128, n0 = bx * 128;

  f32x4 acc[4][4] = {};
  const int srow = tid >> 3;              // 0..31
  const int scg  = tid & 7;
  const int rsw = (l15 & 7) << 4;

  for (int k0 = 0; k0 < DIMM; k0 += 64) {
    __syncthreads();
#pragma unroll
    for (int it = 0; it < 4; ++it) {
      int row = srow + it * 32;
      int sw = (row & 7) << 4;
      const float* asrc = X + (size_t)(m0 + row) * DIMM + k0 + scg * 8;
      float4 a0 = *(const float4*)asrc;
      float4 a1 = *(const float4*)(asrc + 4);
      union { unsigned short u[8]; int4 v; } pk;
      pk.u[0] = f2bf(a0.x); pk.u[1] = f2bf(a0.y);
      pk.u[2] = f2bf(a0.z); pk.u[3] = f2bf(a0.w);
      pk.u[4] = f2bf(a1.x); pk.u[5] = f2bf(a1.y);
      pk.u[6] = f2bf(a1.z); pk.u[7] = f2bf(a1.w);
      *(int4*)(Al + row * 128 + ((scg * 16) ^ sw)) = pk.v;
      *(int4*)(Bl + row * 128 + ((scg * 16) ^ sw)) =
          *(const int4*)(Wt + (size_t)(n0 + row) * DIMM + k0 + scg * 8);
    }
    __syncthreads();
#pragma unroll
    for (int ks = 0; ks < 2; ++ks) {
      bf16x8 af[4], bfr[4];
#pragma unroll
      for (int mi = 0; mi < 4; ++mi)
        af[mi] = *(const bf16x8*)(Al + (wr * 64 + mi * 16 + l15) * 128 +
                                  ((ks * 64 + g * 16) ^ rsw));
#pragma unroll
      for (int nj = 0; nj < 4; ++nj)
        bfr[nj] = *(const bf16x8*)(Bl + (wc * 64 + nj * 16 + l15) * 128 +
                                   ((ks * 64 + g * 16) ^ rsw));
#pragma unroll
      for (int mi = 0; mi < 4; ++mi)
#pragma unroll
        for (int nj = 0; nj < 4; ++nj)
          acc[mi][nj] = __builtin_amdgcn_mfma_f32_16x16x32_bf16(
              af[mi], bfr[nj], acc[mi][nj], 0, 0, 0);
    }
  }
  const int chunk = n0 >> 9;              // 0=Q 1=K 2=V
#pragma unroll
  for (int nj = 0; nj < 4; ++nj) {
    int col = (n0 & 511) + wc * 64 + nj * 16 + l15;   // 0..511 within chunk
    int hh = col >> 6, dd = col & 63;
#pragma unroll
    for (int mi = 0; mi < 4; ++mi) {
#pragma unroll
      for (int r = 0; r < 4; ++r) {
        int m = m0 + wr * 64 + mi * 16 + g * 4 + r;
        int bb = m >> 11, ii = m & (SEQ - 1);
        size_t base = ((size_t)(bb * HEADS + hh) * SEQ + ii) * DHEAD + dd;
        float v = acc[mi][nj][r];
        if (chunk == 0)      Qbf[base] = f2bf(v * QK_SCALE);
        else if (chunk == 1) Kbf[base] = f2bf(v);
        else {
          V[base] = v;
          Vt[((size_t)(bb * HEADS + hh) * DHEAD + dd) * SEQ + ii] = f2bf(v);
        }
      }
    }
  }
}

// ---------------- flash attention with bf16 MFMA (unchanged, verified) -------
__global__ __launch_bounds__(256) void attn_mfma(const unsigned short* __restrict__ Qbf,
                                                 const unsigned short* __restrict__ Kbf,
                                                 const unsigned short* __restrict__ Vt,
                                                 const float* __restrict__ maskf,
                                                 float* __restrict__ O) {
  __shared__ __align__(16) unsigned char Ks[8192];
  __shared__ __align__(16) unsigned char Vs[8192];
  __shared__ __align__(16) unsigned char Ps[8192];
  __shared__ float skm[64];

  const int tid = threadIdx.x;
  const int lane = tid & 63;
  const int w = tid >> 6;
  const int l15 = lane & 15, g = lane >> 4;

  int fid = blockIdx.x;
  int lid = (fid & 7) * 64 + (fid >> 3);
  const int bh = lid >> 5;
  const int qb = lid & 31;
  const int bb = bh >> 3;

  const unsigned short* Qg = Qbf + ((size_t)bh * SEQ + qb * 64) * DHEAD;
  const unsigned short* Kg = Kbf + (size_t)bh * SEQ * DHEAD;
  const unsigned short* Vg = Vt  + (size_t)bh * DHEAD * SEQ;

  bf16x8 qf0, qf1;
  {
    const unsigned char* qrow = (const unsigned char*)(Qg + (size_t)(w * 16 + l15) * DHEAD);
    qf0 = *(const bf16x8*)(qrow + g * 16);
    qf1 = *(const bf16x8*)(qrow + 64 + g * 16);
  }

  f32x4 o[4];
  float mrow[4], lrow[4];
#pragma unroll
  for (int j = 0; j < 4; ++j) { o[j] = (f32x4){0.f, 0.f, 0.f, 0.f}; }
#pragma unroll
  for (int r = 0; r < 4; ++r) { mrow[r] = -3.0e38f; lrow[r] = 0.f; }

  const int sm = tid >> 2;
  const int sc = (tid & 3) * 32;
  const int ssw = (sm & 7) << 4;
  const int rsw = (l15 & 7) << 4;

  for (int kt = 0; kt < SEQ / 64; ++kt) {
    __syncthreads();
    {
      const unsigned char* ksrc =
          (const unsigned char*)(Kg + (size_t)kt * 64 * DHEAD) + sm * 128 + sc;
      const unsigned char* vsrc =
          (const unsigned char*)(Vg + (size_t)sm * SEQ + kt * 64) + sc;
      *(int4*)(Ks + sm * 128 + ((sc)      ^ ssw)) = *(const int4*)(ksrc);
      *(int4*)(Ks + sm * 128 + ((sc + 16) ^ ssw)) = *(const int4*)(ksrc + 16);
      *(int4*)(Vs + sm * 128 + ((sc)      ^ ssw)) = *(const int4*)(vsrc);
      *(int4*)(Vs + sm * 128 + ((sc + 16) ^ ssw)) = *(const int4*)(vsrc + 16);
      if (tid < 64) skm[tid] = maskf[bb * SEQ + kt * 64 + tid];
    }
    __syncthreads();

    f32x4 s[4];
#pragma unroll
    for (int j = 0; j < 4; ++j) {
      const unsigned char* krow = Ks + (16 * j + l15) * 128;
      bf16x8 kf0 = *(const bf16x8*)(krow + ((g * 16)      ^ rsw));
      bf16x8 kf1 = *(const bf16x8*)(krow + ((64 + g * 16) ^ rsw));
      f32x4 z = (f32x4){0.f, 0.f, 0.f, 0.f};
      z = __builtin_amdgcn_mfma_f32_16x16x32_bf16(qf0, kf0, z, 0, 0, 0);
      z = __builtin_amdgcn_mfma_f32_16x16x32_bf16(qf1, kf1, z, 0, 0, 0);
      s[j] = z;
    }

    float km0 = skm[l15], km1 = skm[16 + l15], km2 = skm[32 + l15], km3 = skm[48 + l15];
#pragma unroll
    for (int r = 0; r < 4; ++r) {
      float v0 = (km0 != 0.f) ? s[0][r] : -1e30f;
      float v1 = (km1 != 0.f) ? s[1][r] : -1e30f;
      float v2 = (km2 != 0.f) ? s[2][r] : -1e30f;
      float v3 = (km3 != 0.f) ? s[3][r] : -1e30f;
      float rm = fmaxf(fmaxf(v0, v1), fmaxf(v2, v3));
      rm = fmaxf(rm, __shfl_xor(rm, 1));
      rm = fmaxf(rm, __shfl_xor(rm, 2));
      rm = fmaxf(rm, __shfl_xor(rm, 4));
      rm = fmaxf(rm, __shfl_xor(rm, 8));
      float mnew = fmaxf(mrow[r], rm);
      float resc = __expf(mrow[r] - mnew);
      float p0 = __expf(v0 - mnew) * km0;
      float p1 = __expf(v1 - mnew) * km1;
      float p2 = __expf(v2 - mnew) * km2;
      float p3 = __expf(v3 - mnew) * km3;
      float rs = (p0 + p1) + (p2 + p3);
      rs += __shfl_xor(rs, 1);
      rs += __shfl_xor(rs, 2);
      rs += __shfl_xor(rs, 4);
      rs += __shfl_xor(rs, 8);
      lrow[r] = lrow[r] * resc + rs;
      mrow[r] = mnew;
      o[0][r] *= resc; o[1][r] *= resc; o[2][r] *= resc; o[3][r] *= resc;

      int pm = w * 16 + g * 4 + r;
      unsigned char* prow = Ps + pm * 128;
      int psw = (pm & 7) << 4;
      *(unsigned short*)(prow + ((2 * (l15)      ) ^ psw)) = f2bf(p0);
      *(unsigned short*)(prow + ((2 * (16 + l15) ) ^ psw)) = f2bf(p1);
      *(unsigned short*)(prow + ((2 * (32 + l15) ) ^ psw)) = f2bf(p2);
      *(unsigned short*)(prow + ((2 * (48 + l15) ) ^ psw)) = f2bf(p3);
    }

    {
      const unsigned char* parow = Ps + (w * 16 + l15) * 128;
      bf16x8 pa0 = *(const bf16x8*)(parow + ((g * 16)      ^ rsw));
      bf16x8 pa1 = *(const bf16x8*)(parow + ((64 + g * 16) ^ rsw));
#pragma unroll
      for (int j = 0; j < 4; ++j) {
        const unsigned char* vrow = Vs + (16 * j + l15) * 128;
        bf16x8 vf0 = *(const bf16x8*)(vrow + ((g * 16)      ^ rsw));
        bf16x8 vf1 = *(const bf16x8*)(vrow + ((64 + g * 16) ^ rsw));
        o[j] = __builtin_amdgcn_mfma_f32_16x16x32_bf16(pa0, vf0, o[j], 0, 0, 0);
        o[j] = __builtin_amdgcn_mfma_f32_16x16x32_bf16(pa1, vf1, o[j], 0, 0, 0);
      }
    }
  }

#pragma unroll
  for (int r = 0; r < 4; ++r) {
    float inv = 1.f / lrow[r];
    int row = qb * 64 + w * 16 + g * 4 + r;
    float* dst = O + ((size_t)bh * SEQ + row) * DHEAD + l15;
    dst[0]  = o[0][r] * inv;
    dst[16] = o[1][r] * inv;
    dst[32] = o[2][r] * inv;
    dst[48] = o[3][r] * inv;
  }
}

// ---------------- depthwise conv residual: O += conv(V) ----------------------
__global__ __launch_bounds__(256) void conv_res(const float* __restrict__ V,
                                                const float* __restrict__ cw,
                                                float* __restrict__ O) {
  int gid = blockIdx.x * blockDim.x + threadIdx.x;
  const int total = BATCH * HEADS * SEQ * (DHEAD / 4);
  if (gid >= total) return;
  int d4 = gid & 15;
  int rest = gid >> 4;
  int i = rest & (SEQ - 1);
  int bh = rest >> 11;
  int hh = bh & 7;
  const float* vb = V + (size_t)bh * SEQ * DHEAD + d4 * 4;
  float4 acc = *(float4*)(O + (size_t)gid * 4);
#pragma unroll
  for (int t = 0; t < 33; ++t) {
    int row = i + t - 16;
    if (row >= 0 && row < SEQ) {
      float w = cw[hh * 33 + t];
      float4 v = *(const float4*)(vb + (size_t)row * DHEAD);
      acc.x += w * v.x; acc.y += w * v.y; acc.z += w * v.z; acc.w += w * v.w;
    }
  }
  *(float4*)(O + (size_t)gid * 4) = acc;
}

// ---------------- out GEMM (MFMA): gather-A from O fp32, 128x64 tile ---------
__global__ __launch_bounds__(256) void gemm_out_mfma(
    const float* __restrict__ O, const unsigned short* __restrict__ Wt,
    const float* __restrict__ bias, const float* __restrict__ maskf,
    float* __restrict__ out) {
  __shared__ __align__(16) unsigned char Al[128 * 128];
  __shared__ __align__(16) unsigned char Bl[64 * 128];
  const int tid = threadIdx.x;
  const int lane = tid & 63;
  const int w = tid >> 6;
  const int l15 = lane & 15, g = lane >> 4;
  const int wr = w >> 1, wc = w & 1;
  int bid = blockIdx.x;                    // 256 blocks
  int lid = (bid & 7) * 32 + (bid >> 3);
  int by = lid >> 3, bx = lid & 7;
  const int m0 = by * 128, n0 = bx * 64;

  f32x4 acc[4][2] = {};
  const int srow = tid >> 3, scg = tid & 7;
  const int rsw = (l15 & 7) << 4;

  for (int k0 = 0; k0 < DIMM; k0 += 64) {
    const int hh = k0 >> 6;                // K-step == one head
    __syncthreads();
#pragma unroll
    for (int it = 0; it < 4; ++it) {
      int row = srow + it * 32;
      int sw = (row & 7) << 4;
      int m = m0 + row;
      int bb = m >> 11, ii = m & (SEQ - 1);
      const float* asrc = O + ((size_t)(bb * HEADS + hh) * SEQ + ii) * DHEAD + scg * 8;
      float4 a0 = *(const float4*)asrc;
      float4 a1 = *(const float4*)(asrc + 4);
      union { unsigned short u[8]; int4 v; } pk;
      pk.u[0] = f2bf(a0.x); pk.u[1] = f2bf(a0.y);
      pk.u[2] = f2bf(a0.z); pk.u[3] = f2bf(a0.w);
      pk.u[4] = f2bf(a1.x); pk.u[5] = f2bf(a1.y);
      pk.u[6] = f2bf(a1.z); pk.u[7] = f2bf(a1.w);
      *(int4*)(Al + row * 128 + ((scg * 16) ^ sw)) = pk.v;
      if (it < 2) {
        *(int4*)(Bl + row * 128 + ((scg * 16) ^ sw)) =
            *(const int4*)(Wt + (size_t)(n0 + row) * DIMM + k0 + scg * 8);
      }
    }
    __syncthreads();
#pragma unroll
    for (int ks = 0; ks < 2; ++ks) {
      bf16x8 af[4], bfr[2];
#pragma unroll
      for (int mi = 0; mi < 4; ++mi)
        af[mi] = *(const bf16x8*)(Al + (wr * 64 + mi * 16 + l15) * 128 +
                                  ((ks * 64 + g * 16) ^ rsw));
#pragma unroll
      for (int nj = 0; nj < 2; ++nj)
        bfr[nj] = *(const bf16x8*)(Bl + (wc * 32 + nj * 16 + l15) * 128 +
                                   ((ks * 64 + g * 16) ^ rsw));
#pragma unroll
      for (int mi = 0; mi < 4; ++mi)
#pragma unroll
        for (int nj = 0; nj < 2; ++nj)
          acc[mi][nj] = __builtin_amdgcn_mfma_f32_16x16x32_bf16(
              af[mi], bfr[nj], acc[mi][nj], 0, 0, 0);
    }
  }
#pragma unroll
  for (int nj = 0; nj < 2; ++nj) {
    int col = n0 + wc * 32 + nj * 16 + l15;
    float bcol = bias[col];
#pragma unroll
    for (int mi = 0; mi < 4; ++mi) {
#pragma unroll
      for (int r = 0; r < 4; ++r) {
        int m = m0 + wr * 64 + mi * 16 + g * 4 + r;
        out[(size_t)m * DIMM + col] = (acc[mi][nj][r] + bcol) * maskf[m];
      }
    }
  }
}

extern "C" void kernel_launch(void* const* d_in, const int* in_sizes, int n_in,
                              void* d_out, int out_size, void* d_ws, size_t ws_size,
                              hipStream_t stream) {
  const float* x     = (const float*)d_in[0];
  const void*  mask  = d_in[1];
  const float* Wqkv  = (const float*)d_in[2];
  const float* Wout  = (const float*)d_in[3];
  const float* bout  = (const float*)d_in[4];
  const float* convw = (const float*)d_in[5];
  float* out = (float*)d_out;

  float* ws    = (float*)d_ws;
  float* maskf = ws;
  float* V = ws + 4096;
  float* O = V + QKV_ELEMS;
  unsigned short* Qbf = (unsigned short*)(O + QKV_ELEMS);
  unsigned short* Kbf = Qbf + QKV_ELEMS;
  unsigned short* Vt  = Kbf + QKV_ELEMS;
  unsigned short* Wtq = Vt + QKV_ELEMS;                 // 1536*512
  unsigned short* Wto = Wtq + (size_t)NQKV * DIMM;      // 512*512

  prep_mask<<<1, 1024, 0, stream>>>(mask, maskf);
  transpose_w<<<dim3(NQKV / 64, DIMM / 64), 256, 0, stream>>>(Wqkv, Wtq, DIMM, NQKV);
  transpose_w<<<dim3(DIMM / 64, DIMM / 64), 256, 0, stream>>>(Wout, Wto, DIMM, DIMM);
  gemm_qkv_mfma<<<384, 256, 0, stream>>>(x, Wtq, Qbf, Kbf, V, Vt);
  attn_mfma<<<512, 256, 0, stream>>>(Qbf, Kbf, Vt, maskf, O);
  conv_res<<<(BATCH * HEADS * SEQ * (DHEAD / 4)) / 256, 256, 0, stream>>>(V, convw, O);
  gemm_out_mfma<<<256, 256, 0, stream>>>(O, Wto, bout, maskf, out);
}

// Round 4
// 119.065 us; speedup vs baseline: 6.2630x; 1.3060x over previous
//
#include <hip/hip_runtime.h>
#include <float.h>

#define BATCH 2
#define SEQ   2048
#define HEADS 8
#define DHEAD 64
#define DIMM  512
#define NQKV  1536
#define QK_SCALE 0.125f   // 64^-0.5

#define QKV_ELEMS ((size_t)BATCH * HEADS * SEQ * DHEAD)   // 2097152

typedef __bf16 bf16x8 __attribute__((ext_vector_type(8)));
typedef float  f32x4  __attribute__((ext_vector_type(4)));

__device__ __forceinline__ unsigned short bfbits(float f) {
  __bf16 h = (__bf16)f;
  return *(unsigned short*)&h;
}
__device__ __forceinline__ float bf2f(unsigned short u) {
  return __uint_as_float((unsigned)u << 16);
}

// ---------------- mask prep: sniff dtype, normalize to float 0/1 -------------
__global__ __launch_bounds__(1024) void prep_mask(const void* __restrict__ mraw,
                                                  float* __restrict__ maskf) {
  __shared__ int f_bf16, f_f32, f_gt1, f_oddnz;
  const int t = threadIdx.x;
  if (t == 0) { f_bf16 = 0; f_f32 = 0; f_gt1 = 0; f_oddnz = 0; }
  __syncthreads();
  const unsigned int* w = (const unsigned int*)mraw;
  unsigned int v = w[t];
  if (v == 0x3f803f80u) f_bf16 = 1;
  if (v == 0x3f800000u) f_f32 = 1;
  if (v > 1u)           f_gt1 = 1;
  if ((t & 1) && v != 0u) f_oddnz = 1;
  __syncthreads();
  int mode;                               // 0=i32 1=u8 2=i64 3=f32 4=bf16
  if (f_bf16)       mode = 4;
  else if (f_f32)   mode = 3;
  else if (f_gt1)   mode = 1;
  else if (!f_oddnz) mode = 2;
  else              mode = 0;
  for (int i = t; i < BATCH * SEQ; i += 1024) {
    bool keep;
    if (mode == 4)      keep = ((const unsigned short*)mraw)[i] != 0;
    else if (mode == 3) keep = ((const float*)mraw)[i] != 0.f;
    else if (mode == 1) keep = ((const unsigned char*)mraw)[i] != 0;
    else if (mode == 2) keep = w[2 * i] != 0u;
    else                keep = w[i] != 0u;
    maskf[i] = keep ? 1.f : 0.f;
  }
}

// ---------------- weight transpose+convert: W fp32 [K][N] -> Wt bf16 [N][K] --
__global__ __launch_bounds__(256) void transpose_w(const float* __restrict__ W,
                                                   unsigned short* __restrict__ Wt,
                                                   int K, int N) {
  __shared__ float T[64][65];
  const int t = threadIdx.x;
  const int n0 = blockIdx.x * 64, k0 = blockIdx.y * 64;
  {
    int r0 = t >> 4, c4 = t & 15;
#pragma unroll
    for (int rr = 0; rr < 4; ++rr) {
      int r = r0 + rr * 16;
      float4 v = *(const float4*)(W + (size_t)(k0 + r) * N + n0 + c4 * 4);
      T[r][c4 * 4 + 0] = v.x; T[r][c4 * 4 + 1] = v.y;
      T[r][c4 * 4 + 2] = v.z; T[r][c4 * 4 + 3] = v.w;
    }
  }
  __syncthreads();
  {
    int n = t >> 2, kc = t & 3;
    union { unsigned short u[16]; int4 v[2]; } p;
#pragma unroll
    for (int i = 0; i < 16; ++i) p.u[i] = bfbits(T[kc * 16 + i][n]);
    int4* dst = (int4*)(Wt + (size_t)(n0 + n) * K + k0 + kc * 16);
    dst[0] = p.v[0]; dst[1] = p.v[1];
  }
}

// ---------------- qkv GEMM (MFMA): 128x64 tiles, 768 blocks ------------------
// outputs: Qbf bf16 (b,h,n,d) pre-scaled; Kbf bf16 (b,h,n,d); Vt bf16 (b,h,d,n)
__global__ __launch_bounds__(256) void gemm_qkv_mfma(
    const float* __restrict__ X, const unsigned short* __restrict__ Wt,
    unsigned short* __restrict__ Qbf, unsigned short* __restrict__ Kbf,
    unsigned short* __restrict__ Vt) {
  __shared__ __align__(16) unsigned char Al[128 * 128];
  __shared__ __align__(16) unsigned char Bl[64 * 128];
  const int tid = threadIdx.x;
  const int lane = tid & 63;
  const int w = tid >> 6;
  const int l15 = lane & 15, g = lane >> 4;
  const int wr = w >> 1, wc = w & 1;
  int bid = blockIdx.x;                    // 768 blocks, 768%8==0 -> bijective
  int lid = (bid & 7) * 96 + (bid >> 3);
  int by = lid / 24, bx = lid - by * 24;   // by 0..31, bx 0..23
  const int m0 = by * 128;

  f32x4 acc[4][2] = {};
  const int srow = tid >> 3, scg = tid & 7;
  const int rsw = (l15 & 7) << 4;

  for (int k0 = 0; k0 < DIMM; k0 += 64) {
    __syncthreads();
#pragma unroll
    for (int it = 0; it < 4; ++it) {
      int row = srow + it * 32;
      int sw = (row & 7) << 4;
      const float* asrc = X + (size_t)(m0 + row) * DIMM + k0 + scg * 8;
      float4 a0 = *(const float4*)asrc;
      float4 a1 = *(const float4*)(asrc + 4);
      union { unsigned short u[8]; int4 v; } pk;
      pk.u[0] = bfbits(a0.x); pk.u[1] = bfbits(a0.y);
      pk.u[2] = bfbits(a0.z); pk.u[3] = bfbits(a0.w);
      pk.u[4] = bfbits(a1.x); pk.u[5] = bfbits(a1.y);
      pk.u[6] = bfbits(a1.z); pk.u[7] = bfbits(a1.w);
      *(int4*)(Al + row * 128 + ((scg * 16) ^ sw)) = pk.v;
      if (it < 2) {
        *(int4*)(Bl + row * 128 + ((scg * 16) ^ sw)) =
            *(const int4*)(Wt + (size_t)(bx * 64 + row) * DIMM + k0 + scg * 8);
      }
    }
    __syncthreads();
#pragma unroll
    for (int ks = 0; ks < 2; ++ks) {
      bf16x8 af[4], bfr[2];
#pragma unroll
      for (int mi = 0; mi < 4; ++mi)
        af[mi] = *(const bf16x8*)(Al + (wr * 64 + mi * 16 + l15) * 128 +
                                  ((ks * 64 + g * 16) ^ rsw));
#pragma unroll
      for (int nj = 0; nj < 2; ++nj)
        bfr[nj] = *(const bf16x8*)(Bl + (wc * 32 + nj * 16 + l15) * 128 +
                                   ((ks * 64 + g * 16) ^ rsw));
#pragma unroll
      for (int mi = 0; mi < 4; ++mi)
#pragma unroll
        for (int nj = 0; nj < 2; ++nj)
          acc[mi][nj] = __builtin_amdgcn_mfma_f32_16x16x32_bf16(
              af[mi], bfr[nj], acc[mi][nj], 0, 0, 0);
    }
  }
  const int chunk = bx >> 3;               // 0=Q 1=K 2=V
  const int bb = m0 >> 11;
#pragma unroll
  for (int nj = 0; nj < 2; ++nj) {
    int col = (bx & 7) * 64 + wc * 32 + nj * 16 + l15;    // 0..511
    int hh = col >> 6, dd = col & 63;
#pragma unroll
    for (int mi = 0; mi < 4; ++mi) {
      int ii0 = (m0 & (SEQ - 1)) + wr * 64 + mi * 16 + g * 4;
      if (chunk == 2) {
        union { unsigned short u[4]; ushort4 v; } pk;
#pragma unroll
        for (int r = 0; r < 4; ++r) pk.u[r] = bfbits(acc[mi][nj][r]);
        *(ushort4*)(Vt + ((size_t)(bb * HEADS + hh) * DHEAD + dd) * SEQ + ii0) = pk.v;
      } else {
        unsigned short* dst = (chunk == 0) ? Qbf : Kbf;
        float sc = (chunk == 0) ? QK_SCALE : 1.f;
#pragma unroll
        for (int r = 0; r < 4; ++r)
          dst[((size_t)(bb * HEADS + hh) * SEQ + ii0 + r) * DHEAD + dd] =
              bfbits(acc[mi][nj][r] * sc);
      }
    }
  }
}

// ---------------- flash attention, split-KV x2 -------------------------------
// 1024 blocks: (bh, qb, half). Each handles 16 of 32 KV tiles; writes
// normalized partial O (bf16) + LSE (fp32).
__global__ __launch_bounds__(256) void attn_split(const unsigned short* __restrict__ Qbf,
                                                  const unsigned short* __restrict__ Kbf,
                                                  const unsigned short* __restrict__ Vt,
                                                  const float* __restrict__ maskf,
                                                  unsigned short* __restrict__ Po,
                                                  float* __restrict__ LSE) {
  __shared__ __align__(16) unsigned char Ks[8192];
  __shared__ __align__(16) unsigned char Vs[8192];
  __shared__ __align__(16) unsigned char Ps[8192];
  __shared__ float skm[64];

  const int tid = threadIdx.x;
  const int lane = tid & 63;
  const int w = tid >> 6;
  const int l15 = lane & 15, g = lane >> 4;

  int fid = blockIdx.x;
  int lid = (fid & 7) * 128 + (fid >> 3);  // bijective over 1024
  const int bh = lid >> 6;                 // 0..15
  const int rem = lid & 63;
  const int qb = rem >> 1;                 // 0..31
  const int half = rem & 1;
  const int bb = bh >> 3;

  const unsigned short* Qg = Qbf + ((size_t)bh * SEQ + qb * 64) * DHEAD;
  const unsigned short* Kg = Kbf + (size_t)bh * SEQ * DHEAD;
  const unsigned short* Vg = Vt  + (size_t)bh * DHEAD * SEQ;

  bf16x8 qf0, qf1;
  {
    const unsigned char* qrow = (const unsigned char*)(Qg + (size_t)(w * 16 + l15) * DHEAD);
    qf0 = *(const bf16x8*)(qrow + g * 16);
    qf1 = *(const bf16x8*)(qrow + 64 + g * 16);
  }

  f32x4 o[4];
  float mrow[4], lrow[4];
#pragma unroll
  for (int j = 0; j < 4; ++j) { o[j] = (f32x4){0.f, 0.f, 0.f, 0.f}; }
#pragma unroll
  for (int r = 0; r < 4; ++r) { mrow[r] = -3.0e38f; lrow[r] = 0.f; }

  const int sm = tid >> 2;
  const int sc = (tid & 3) * 32;
  const int ssw = (sm & 7) << 4;
  const int rsw = (l15 & 7) << 4;

  const int kt0 = half * 16;
  for (int kt = kt0; kt < kt0 + 16; ++kt) {
    __syncthreads();
    {
      const unsigned char* ksrc =
          (const unsigned char*)(Kg + (size_t)kt * 64 * DHEAD) + sm * 128 + sc;
      const unsigned char* vsrc =
          (const unsigned char*)(Vg + (size_t)sm * SEQ + kt * 64) + sc;
      *(int4*)(Ks + sm * 128 + ((sc)      ^ ssw)) = *(const int4*)(ksrc);
      *(int4*)(Ks + sm * 128 + ((sc + 16) ^ ssw)) = *(const int4*)(ksrc + 16);
      *(int4*)(Vs + sm * 128 + ((sc)      ^ ssw)) = *(const int4*)(vsrc);
      *(int4*)(Vs + sm * 128 + ((sc + 16) ^ ssw)) = *(const int4*)(vsrc + 16);
      if (tid < 64) skm[tid] = maskf[bb * SEQ + kt * 64 + tid];
    }
    __syncthreads();

    f32x4 s[4];
#pragma unroll
    for (int j = 0; j < 4; ++j) {
      const unsigned char* krow = Ks + (16 * j + l15) * 128;
      bf16x8 kf0 = *(const bf16x8*)(krow + ((g * 16)      ^ rsw));
      bf16x8 kf1 = *(const bf16x8*)(krow + ((64 + g * 16) ^ rsw));
      f32x4 z = (f32x4){0.f, 0.f, 0.f, 0.f};
      z = __builtin_amdgcn_mfma_f32_16x16x32_bf16(qf0, kf0, z, 0, 0, 0);
      z = __builtin_amdgcn_mfma_f32_16x16x32_bf16(qf1, kf1, z, 0, 0, 0);
      s[j] = z;
    }

    float km0 = skm[l15], km1 = skm[16 + l15], km2 = skm[32 + l15], km3 = skm[48 + l15];
#pragma unroll
    for (int r = 0; r < 4; ++r) {
      float v0 = (km0 != 0.f) ? s[0][r] : -1e30f;
      float v1 = (km1 != 0.f) ? s[1][r] : -1e30f;
      float v2 = (km2 != 0.f) ? s[2][r] : -1e30f;
      float v3 = (km3 != 0.f) ? s[3][r] : -1e30f;
      float rm = fmaxf(fmaxf(v0, v1), fmaxf(v2, v3));
      rm = fmaxf(rm, __shfl_xor(rm, 1));
      rm = fmaxf(rm, __shfl_xor(rm, 2));
      rm = fmaxf(rm, __shfl_xor(rm, 4));
      rm = fmaxf(rm, __shfl_xor(rm, 8));
      float mnew = fmaxf(mrow[r], rm);
      float resc = __expf(mrow[r] - mnew);
      float p0 = __expf(v0 - mnew) * km0;
      float p1 = __expf(v1 - mnew) * km1;
      float p2 = __expf(v2 - mnew) * km2;
      float p3 = __expf(v3 - mnew) * km3;
      float rs = (p0 + p1) + (p2 + p3);
      rs += __shfl_xor(rs, 1);
      rs += __shfl_xor(rs, 2);
      rs += __shfl_xor(rs, 4);
      rs += __shfl_xor(rs, 8);
      lrow[r] = lrow[r] * resc + rs;
      mrow[r] = mnew;
      o[0][r] *= resc; o[1][r] *= resc; o[2][r] *= resc; o[3][r] *= resc;

      int pm = w * 16 + g * 4 + r;
      unsigned char* prow = Ps + pm * 128;
      int psw = (pm & 7) << 4;
      *(__bf16*)(prow + ((2 * (l15)      ) ^ psw)) = (__bf16)p0;
      *(__bf16*)(prow + ((2 * (16 + l15) ) ^ psw)) = (__bf16)p1;
      *(__bf16*)(prow + ((2 * (32 + l15) ) ^ psw)) = (__bf16)p2;
      *(__bf16*)(prow + ((2 * (48 + l15) ) ^ psw)) = (__bf16)p3;
    }

    {
      const unsigned char* parow = Ps + (w * 16 + l15) * 128;
      bf16x8 pa0 = *(const bf16x8*)(parow + ((g * 16)      ^ rsw));
      bf16x8 pa1 = *(const bf16x8*)(parow + ((64 + g * 16) ^ rsw));
#pragma unroll
      for (int j = 0; j < 4; ++j) {
        const unsigned char* vrow = Vs + (16 * j + l15) * 128;
        bf16x8 vf0 = *(const bf16x8*)(vrow + ((g * 16)      ^ rsw));
        bf16x8 vf1 = *(const bf16x8*)(vrow + ((64 + g * 16) ^ rsw));
        o[j] = __builtin_amdgcn_mfma_f32_16x16x32_bf16(pa0, vf0, o[j], 0, 0, 0);
        o[j] = __builtin_amdgcn_mfma_f32_16x16x32_bf16(pa1, vf1, o[j], 0, 0, 0);
      }
    }
  }

  // epilogue: normalized partial O (bf16) + LSE
#pragma unroll
  for (int r = 0; r < 4; ++r) {
    float l = lrow[r];
    float inv = (l > 0.f) ? 1.f / l : 0.f;
    int row = qb * 64 + w * 16 + g * 4 + r;
    size_t base = half * QKV_ELEMS + ((size_t)bh * SEQ + row) * DHEAD + l15;
    Po[base]      = bfbits(o[0][r] * inv);
    Po[base + 16] = bfbits(o[1][r] * inv);
    Po[base + 32] = bfbits(o[2][r] * inv);
    Po[base + 48] = bfbits(o[3][r] * inv);
    if (l15 == 0)
      LSE[half * (BATCH * HEADS * SEQ) + bh * SEQ + row] =
          (l > 0.f) ? mrow[r] + __logf(l) : -3.0e38f;
  }
}

// ---------------- combine halves + depthwise conv residual -> Obf bf16 -------
__global__ __launch_bounds__(256) void combine_conv(
    const unsigned short* __restrict__ Po, const float* __restrict__ LSE,
    const unsigned short* __restrict__ Vt, const float* __restrict__ cw,
    unsigned short* __restrict__ Obf) {
  __shared__ float T[96][68];
  __shared__ float cwl[33];
  const int tid = threadIdx.x;
  const int bid = blockIdx.x;              // 512 = 16 bh x 32 n-chunks
  const int bh = bid >> 5;
  const int n0 = (bid & 31) * 64;
  const int hh = bh & 7;
  if (tid < 33) cwl[tid] = cw[hh * 33 + tid];
  // stage Vt[d][n0-16 .. n0+80) -> T[n_local][d], f32
  for (int idx = tid; idx < 64 * 24; idx += 256) {
    int d = idx / 24, c4 = idx - (idx / 24) * 24;
    int nbase = n0 - 16 + c4 * 4;
    const unsigned short* src = Vt + ((size_t)bh * DHEAD + d) * SEQ;
#pragma unroll
    for (int q = 0; q < 4; ++q) {
      int n = nbase + q;
      T[c4 * 4 + q][d] = (n >= 0 && n < SEQ) ? bf2f(src[n]) : 0.f;
    }
  }
  __syncthreads();
#pragma unroll
  for (int p = 0; p < 4; ++p) {
    int n = (tid >> 4) + p * 16;           // 0..63
    int d4 = tid & 15;
    int row = bh * SEQ + n0 + n;
    float ls0 = LSE[row], ls1 = LSE[BATCH * HEADS * SEQ + row];
    float m = fmaxf(ls0, ls1);
    float w0 = __expf(ls0 - m), w1 = __expf(ls1 - m);
    float inv = 1.f / (w0 + w1);
    w0 *= inv; w1 *= inv;
    const unsigned short* p0 = Po + (size_t)row * DHEAD + d4 * 4;
    const unsigned short* p1 = p0 + QKV_ELEMS;
    ushort4 a = *(const ushort4*)p0, b = *(const ushort4*)p1;
    float o0 = w0 * bf2f(a.x) + w1 * bf2f(b.x);
    float o1 = w0 * bf2f(a.y) + w1 * bf2f(b.y);
    float o2 = w0 * bf2f(a.z) + w1 * bf2f(b.z);
    float o3 = w0 * bf2f(a.w) + w1 * bf2f(b.w);
#pragma unroll
    for (int t = 0; t < 33; ++t) {
      float wv = cwl[t];
      float4 tv = *(const float4*)&T[n + t][d4 * 4];
      o0 += wv * tv.x; o1 += wv * tv.y; o2 += wv * tv.z; o3 += wv * tv.w;
    }
    union { unsigned short u[4]; ushort4 v; } pk;
    pk.u[0] = bfbits(o0); pk.u[1] = bfbits(o1);
    pk.u[2] = bfbits(o2); pk.u[3] = bfbits(o3);
    *(ushort4*)(Obf + (size_t)row * DHEAD + d4 * 4) = pk.v;
  }
}

// ---------------- out GEMM (MFMA): Obf bf16 gather-A, 64x64 tiles ------------
__global__ __launch_bounds__(256) void gemm_out_mfma(
    const unsigned short* __restrict__ Obf, const unsigned short* __restrict__ Wt,
    const float* __restrict__ bias, const float* __restrict__ maskf,
    float* __restrict__ out) {
  __shared__ __align__(16) unsigned char Al[64 * 128];
  __shared__ __align__(16) unsigned char Bl[64 * 128];
  const int tid = threadIdx.x;
  const int lane = tid & 63;
  const int w = tid >> 6;
  const int l15 = lane & 15, g = lane >> 4;
  const int wr = w >> 1, wc = w & 1;
  int bid = blockIdx.x;                    // 512 blocks
  int lid = (bid & 7) * 64 + (bid >> 3);
  int by = lid >> 3, bx = lid & 7;         // by 0..63, bx 0..7
  const int m0 = by * 64, n0 = bx * 64;
  const int bb = m0 >> 11;
  const int ii0 = m0 & (SEQ - 1);

  f32x4 acc[2][2] = {};
  const int srow = tid >> 3, scg = tid & 7;
  const int rsw = (l15 & 7) << 4;

  for (int k0 = 0; k0 < DIMM; k0 += 64) {
    const int hh = k0 >> 6;
    __syncthreads();
#pragma unroll
    for (int it = 0; it < 2; ++it) {
      int row = srow + it * 32;
      int sw = (row & 7) << 4;
      *(int4*)(Al + row * 128 + ((scg * 16) ^ sw)) =
          *(const int4*)(Obf + ((size_t)(bb * HEADS + hh) * SEQ + ii0 + row) * DHEAD + scg * 8);
      *(int4*)(Bl + row * 128 + ((scg * 16) ^ sw)) =
          *(const int4*)(Wt + (size_t)(n0 + row) * DIMM + k0 + scg * 8);
    }
    __syncthreads();
#pragma unroll
    for (int ks = 0; ks < 2; ++ks) {
      bf16x8 af[2], bfr[2];
#pragma unroll
      for (int mi = 0; mi < 2; ++mi)
        af[mi] = *(const bf16x8*)(Al + (wr * 32 + mi * 16 + l15) * 128 +
                                  ((ks * 64 + g * 16) ^ rsw));
#pragma unroll
      for (int nj = 0; nj < 2; ++nj)
        bfr[nj] = *(const bf16x8*)(Bl + (wc * 32 + nj * 16 + l15) * 128 +
                                   ((ks * 64 + g * 16) ^ rsw));
#pragma unroll
      for (int mi = 0; mi < 2; ++mi)
#pragma unroll
        for (int nj = 0; nj < 2; ++nj)
          acc[mi][nj] = __builtin_amdgcn_mfma_f32_16x16x32_bf16(
              af[mi], bfr[nj], acc[mi][nj], 0, 0, 0);
    }
  }
#pragma unroll
  for (int nj = 0; nj < 2; ++nj) {
    int col = n0 + wc * 32 + nj * 16 + l15;
    float bcol = bias[col];
#pragma unroll
    for (int mi = 0; mi < 2; ++mi) {
#pragma unroll
      for (int r = 0; r < 4; ++r) {
        int m = m0 + wr * 32 + mi * 16 + g * 4 + r;
        out[(size_t)m * DIMM + col] = (acc[mi][nj][r] + bcol) * maskf[m];
      }
    }
  }
}

extern "C" void kernel_launch(void* const* d_in, const int* in_sizes, int n_in,
                              void* d_out, int out_size, void* d_ws, size_t ws_size,
                              hipStream_t stream) {
  const float* x     = (const float*)d_in[0];
  const void*  mask  = d_in[1];
  const float* Wqkv  = (const float*)d_in[2];
  const float* Wout  = (const float*)d_in[3];
  const float* bout  = (const float*)d_in[4];
  const float* convw = (const float*)d_in[5];
  float* out = (float*)d_out;

  float* maskf = (float*)d_ws;
  unsigned short* Qbf = (unsigned short*)(maskf + 4096);
  unsigned short* Kbf = Qbf + QKV_ELEMS;
  unsigned short* Vt  = Kbf + QKV_ELEMS;
  unsigned short* Po  = Vt + QKV_ELEMS;                  // 2 halves
  float* LSE          = (float*)(Po + 2 * QKV_ELEMS);    // 2 * 32768
  unsigned short* Obf = (unsigned short*)(LSE + 2 * BATCH * HEADS * SEQ);
  unsigned short* Wtq = Obf + QKV_ELEMS;                 // 1536*512
  unsigned short* Wto = Wtq + (size_t)NQKV * DIMM;       // 512*512

  prep_mask<<<1, 1024, 0, stream>>>(mask, maskf);
  transpose_w<<<dim3(NQKV / 64, DIMM / 64), 256, 0, stream>>>(Wqkv, Wtq, DIMM, NQKV);
  transpose_w<<<dim3(DIMM / 64, DIMM / 64), 256, 0, stream>>>(Wout, Wto, DIMM, DIMM);
  gemm_qkv_mfma<<<768, 256, 0, stream>>>(x, Wtq, Qbf, Kbf, Vt);
  attn_split<<<1024, 256, 0, stream>>>(Qbf, Kbf, Vt, maskf, Po, LSE);
  combine_conv<<<512, 256, 0, stream>>>(Po, LSE, Vt, convw, Obf);
  gemm_out_mfma<<<512, 256, 0, stream>>>(Obf, Wto, bout, maskf, out);
}

// Round 5
// 109.342 us; speedup vs baseline: 6.8200x; 1.0889x over previous
//
#include <hip/hip_runtime.h>
#include <float.h>

#define BATCH 2
#define SEQ   2048
#define HEADS 8
#define DHEAD 64
#define DIMM  512
#define NQKV  1536
#define QK_SCALE 0.125f   // 64^-0.5

#define QKV_ELEMS ((size_t)BATCH * HEADS * SEQ * DHEAD)   // 2097152

typedef __bf16 bf16x8 __attribute__((ext_vector_type(8)));
typedef float  f32x4  __attribute__((ext_vector_type(4)));

__device__ __forceinline__ unsigned short bfbits(float f) {
  __bf16 h = (__bf16)f;
  return *(unsigned short*)&h;
}
__device__ __forceinline__ float bf2f(unsigned short u) {
  return __uint_as_float((unsigned)u << 16);
}

// ---------------- mask prep: sniff dtype, normalize to float 0/1 -------------
__global__ __launch_bounds__(1024) void prep_mask(const void* __restrict__ mraw,
                                                  float* __restrict__ maskf,
                                                  unsigned* __restrict__ kmaxn) {
  __shared__ int f_bf16, f_f32, f_gt1, f_oddnz;
  const int t = threadIdx.x;
  if (t < 16) kmaxn[t] = 0u;              // init for knorm's atomicMax
  if (t == 0) { f_bf16 = 0; f_f32 = 0; f_gt1 = 0; f_oddnz = 0; }
  __syncthreads();
  const unsigned int* w = (const unsigned int*)mraw;
  unsigned int v = w[t];
  if (v == 0x3f803f80u) f_bf16 = 1;
  if (v == 0x3f800000u) f_f32 = 1;
  if (v > 1u)           f_gt1 = 1;
  if ((t & 1) && v != 0u) f_oddnz = 1;
  __syncthreads();
  int mode;                               // 0=i32 1=u8 2=i64 3=f32 4=bf16
  if (f_bf16)       mode = 4;
  else if (f_f32)   mode = 3;
  else if (f_gt1)   mode = 1;
  else if (!f_oddnz) mode = 2;
  else              mode = 0;
  for (int i = t; i < BATCH * SEQ; i += 1024) {
    bool keep;
    if (mode == 4)      keep = ((const unsigned short*)mraw)[i] != 0;
    else if (mode == 3) keep = ((const float*)mraw)[i] != 0.f;
    else if (mode == 1) keep = ((const unsigned char*)mraw)[i] != 0;
    else if (mode == 2) keep = w[2 * i] != 0u;
    else                keep = w[i] != 0u;
    maskf[i] = keep ? 1.f : 0.f;
  }
}

// ---------------- weight transpose+convert: W fp32 [K][N] -> Wt bf16 [N][K] --
__global__ __launch_bounds__(256) void transpose_w(const float* __restrict__ W,
                                                   unsigned short* __restrict__ Wt,
                                                   int K, int N) {
  __shared__ float T[64][65];
  const int t = threadIdx.x;
  const int n0 = blockIdx.x * 64, k0 = blockIdx.y * 64;
  {
    int r0 = t >> 4, c4 = t & 15;
#pragma unroll
    for (int rr = 0; rr < 4; ++rr) {
      int r = r0 + rr * 16;
      float4 v = *(const float4*)(W + (size_t)(k0 + r) * N + n0 + c4 * 4);
      T[r][c4 * 4 + 0] = v.x; T[r][c4 * 4 + 1] = v.y;
      T[r][c4 * 4 + 2] = v.z; T[r][c4 * 4 + 3] = v.w;
    }
  }
  __syncthreads();
  {
    int n = t >> 2, kc = t & 3;
    union { unsigned short u[16]; int4 v[2]; } p;
#pragma unroll
    for (int i = 0; i < 16; ++i) p.u[i] = bfbits(T[kc * 16 + i][n]);
    int4* dst = (int4*)(Wt + (size_t)(n0 + n) * K + k0 + kc * 16);
    dst[0] = p.v[0]; dst[1] = p.v[1];
  }
}

// ---------------- qkv GEMM (MFMA): 128x64 tiles, 768 blocks ------------------
__global__ __launch_bounds__(256) void gemm_qkv_mfma(
    const float* __restrict__ X, const unsigned short* __restrict__ Wt,
    unsigned short* __restrict__ Qbf, unsigned short* __restrict__ Kbf,
    unsigned short* __restrict__ Vt) {
  __shared__ __align__(16) unsigned char Al[128 * 128];
  __shared__ __align__(16) unsigned char Bl[64 * 128];
  const int tid = threadIdx.x;
  const int lane = tid & 63;
  const int w = tid >> 6;
  const int l15 = lane & 15, g = lane >> 4;
  const int wr = w >> 1, wc = w & 1;
  int bid = blockIdx.x;                    // 768 blocks, 768%8==0 -> bijective
  int lid = (bid & 7) * 96 + (bid >> 3);
  int by = lid / 24, bx = lid - by * 24;   // by 0..31, bx 0..23
  const int m0 = by * 128;

  f32x4 acc[4][2] = {};
  const int srow = tid >> 3, scg = tid & 7;
  const int rsw = (l15 & 7) << 4;

  for (int k0 = 0; k0 < DIMM; k0 += 64) {
    __syncthreads();
#pragma unroll
    for (int it = 0; it < 4; ++it) {
      int row = srow + it * 32;
      int sw = (row & 7) << 4;
      const float* asrc = X + (size_t)(m0 + row) * DIMM + k0 + scg * 8;
      float4 a0 = *(const float4*)asrc;
      float4 a1 = *(const float4*)(asrc + 4);
      union { unsigned short u[8]; int4 v; } pk;
      pk.u[0] = bfbits(a0.x); pk.u[1] = bfbits(a0.y);
      pk.u[2] = bfbits(a0.z); pk.u[3] = bfbits(a0.w);
      pk.u[4] = bfbits(a1.x); pk.u[5] = bfbits(a1.y);
      pk.u[6] = bfbits(a1.z); pk.u[7] = bfbits(a1.w);
      *(int4*)(Al + row * 128 + ((scg * 16) ^ sw)) = pk.v;
      if (it < 2) {
        *(int4*)(Bl + row * 128 + ((scg * 16) ^ sw)) =
            *(const int4*)(Wt + (size_t)(bx * 64 + row) * DIMM + k0 + scg * 8);
      }
    }
    __syncthreads();
#pragma unroll
    for (int ks = 0; ks < 2; ++ks) {
      bf16x8 af[4], bfr[2];
#pragma unroll
      for (int mi = 0; mi < 4; ++mi)
        af[mi] = *(const bf16x8*)(Al + (wr * 64 + mi * 16 + l15) * 128 +
                                  ((ks * 64 + g * 16) ^ rsw));
#pragma unroll
      for (int nj = 0; nj < 2; ++nj)
        bfr[nj] = *(const bf16x8*)(Bl + (wc * 32 + nj * 16 + l15) * 128 +
                                   ((ks * 64 + g * 16) ^ rsw));
#pragma unroll
      for (int mi = 0; mi < 4; ++mi)
#pragma unroll
        for (int nj = 0; nj < 2; ++nj)
          acc[mi][nj] = __builtin_amdgcn_mfma_f32_16x16x32_bf16(
              af[mi], bfr[nj], acc[mi][nj], 0, 0, 0);
    }
  }
  const int chunk = bx >> 3;               // 0=Q 1=K 2=V
  const int bb = m0 >> 11;
#pragma unroll
  for (int nj = 0; nj < 2; ++nj) {
    int col = (bx & 7) * 64 + wc * 32 + nj * 16 + l15;    // 0..511
    int hh = col >> 6, dd = col & 63;
#pragma unroll
    for (int mi = 0; mi < 4; ++mi) {
      int ii0 = (m0 & (SEQ - 1)) + wr * 64 + mi * 16 + g * 4;
      if (chunk == 2) {
        union { unsigned short u[4]; ushort4 v; } pk;
#pragma unroll
        for (int r = 0; r < 4; ++r) pk.u[r] = bfbits(acc[mi][nj][r]);
        *(ushort4*)(Vt + ((size_t)(bb * HEADS + hh) * DHEAD + dd) * SEQ + ii0) = pk.v;
      } else {
        unsigned short* dst = (chunk == 0) ? Qbf : Kbf;
        float sc = (chunk == 0) ? QK_SCALE : 1.f;
#pragma unroll
        for (int r = 0; r < 4; ++r)
          dst[((size_t)(bb * HEADS + hh) * SEQ + ii0 + r) * DHEAD + dd] =
              bfbits(acc[mi][nj][r] * sc);
      }
    }
  }
}

// ---------------- per-(b,h) max key-norm^2 (for softmax shift bound) ---------
__global__ __launch_bounds__(256) void knorm(const unsigned short* __restrict__ Kbf,
                                             unsigned* __restrict__ kmaxn) {
  int row = blockIdx.x * 256 + threadIdx.x;       // 32768 rows
  const bf16x8* kr = (const bf16x8*)(Kbf + (size_t)row * DHEAD);
  float n2 = 0.f;
#pragma unroll
  for (int c = 0; c < 8; ++c) {
    bf16x8 v = kr[c];
#pragma unroll
    for (int i = 0; i < 8; ++i) { float f = (float)v[i]; n2 += f * f; }
  }
#pragma unroll
  for (int d = 1; d < 64; d <<= 1) n2 = fmaxf(n2, __shfl_xor(n2, d));
  if ((threadIdx.x & 63) == 0)
    atomicMax(kmaxn + (row >> 11), __float_as_uint(n2));
}

// ---------------- flash attention, split-KV x2, bounded-shift softmax --------
// p = exp(s - B) with B = ||q||*max||k|| >= max(s); no per-tile reductions.
__global__ __launch_bounds__(256) void attn_split(const unsigned short* __restrict__ Qbf,
                                                  const unsigned short* __restrict__ Kbf,
                                                  const unsigned short* __restrict__ Vt,
                                                  const float* __restrict__ maskf,
                                                  const unsigned* __restrict__ kmaxn,
                                                  unsigned short* __restrict__ Po,
                                                  float* __restrict__ LSE) {
  __shared__ __align__(16) unsigned char Ks[8192];
  __shared__ __align__(16) unsigned char Vs[8192];
  __shared__ __align__(16) unsigned char Ps[8192];
  __shared__ float skm[64];
  __shared__ float qns[64];

  const int tid = threadIdx.x;
  const int lane = tid & 63;
  const int w = tid >> 6;
  const int l15 = lane & 15, g = lane >> 4;

  int fid = blockIdx.x;
  int lid = (fid & 7) * 128 + (fid >> 3);  // bijective over 1024
  const int bh = lid >> 6;                 // 0..15
  const int rem = lid & 63;
  const int qb = rem >> 1;                 // 0..31
  const int half = rem & 1;
  const int bb = bh >> 3;

  const unsigned short* Qg = Qbf + ((size_t)bh * SEQ + qb * 64) * DHEAD;
  const unsigned short* Kg = Kbf + (size_t)bh * SEQ * DHEAD;
  const unsigned short* Vg = Vt  + (size_t)bh * DHEAD * SEQ;

  bf16x8 qf0, qf1;
  {
    const unsigned char* qrow = (const unsigned char*)(Qg + (size_t)(w * 16 + l15) * DHEAD);
    qf0 = *(const bf16x8*)(qrow + g * 16);
    qf1 = *(const bf16x8*)(qrow + 64 + g * 16);
  }
  // ||q||^2 for row l15: in-lane partial + reduce across the 4 g-lanes
  {
    float qn2 = 0.f;
#pragma unroll
    for (int i = 0; i < 8; ++i) {
      float a = (float)qf0[i]; qn2 += a * a;
      float b = (float)qf1[i]; qn2 += b * b;
    }
    qn2 += __shfl_xor(qn2, 16);
    qn2 += __shfl_xor(qn2, 32);
    if (g == 0) qns[w * 16 + l15] = qn2;
  }
  __syncthreads();
  const float kmax2 = __uint_as_float(kmaxn[bh]);
  float B[4];
#pragma unroll
  for (int r = 0; r < 4; ++r) B[r] = sqrtf(qns[w * 16 + g * 4 + r] * kmax2);

  f32x4 o[4];
  float lsum[4] = {0.f, 0.f, 0.f, 0.f};
#pragma unroll
  for (int j = 0; j < 4; ++j) { o[j] = (f32x4){0.f, 0.f, 0.f, 0.f}; }

  const int sm = tid >> 2;
  const int sc = (tid & 3) * 32;
  const int ssw = (sm & 7) << 4;
  const int rsw = (l15 & 7) << 4;

  const int kt0 = half * 16;
  for (int kt = kt0; kt < kt0 + 16; ++kt) {
    __syncthreads();
    {
      const unsigned char* ksrc =
          (const unsigned char*)(Kg + (size_t)kt * 64 * DHEAD) + sm * 128 + sc;
      const unsigned char* vsrc =
          (const unsigned char*)(Vg + (size_t)sm * SEQ + kt * 64) + sc;
      *(int4*)(Ks + sm * 128 + ((sc)      ^ ssw)) = *(const int4*)(ksrc);
      *(int4*)(Ks + sm * 128 + ((sc + 16) ^ ssw)) = *(const int4*)(ksrc + 16);
      *(int4*)(Vs + sm * 128 + ((sc)      ^ ssw)) = *(const int4*)(vsrc);
      *(int4*)(Vs + sm * 128 + ((sc + 16) ^ ssw)) = *(const int4*)(vsrc + 16);
      if (tid < 64) skm[tid] = maskf[bb * SEQ + kt * 64 + tid];
    }
    __syncthreads();

    // S = Q K^T
    f32x4 s[4];
#pragma unroll
    for (int j = 0; j < 4; ++j) {
      const unsigned char* krow = Ks + (16 * j + l15) * 128;
      bf16x8 kf0 = *(const bf16x8*)(krow + ((g * 16)      ^ rsw));
      bf16x8 kf1 = *(const bf16x8*)(krow + ((64 + g * 16) ^ rsw));
      f32x4 z = (f32x4){0.f, 0.f, 0.f, 0.f};
      z = __builtin_amdgcn_mfma_f32_16x16x32_bf16(qf0, kf0, z, 0, 0, 0);
      z = __builtin_amdgcn_mfma_f32_16x16x32_bf16(qf1, kf1, z, 0, 0, 0);
      s[j] = z;
    }

    // p = exp(s - B) * km ; accumulate per-lane partial row sums; store P bf16
    float km0 = skm[l15], km1 = skm[16 + l15], km2 = skm[32 + l15], km3 = skm[48 + l15];
#pragma unroll
    for (int r = 0; r < 4; ++r) {
      float p0 = __expf(s[0][r] - B[r]) * km0;
      float p1 = __expf(s[1][r] - B[r]) * km1;
      float p2 = __expf(s[2][r] - B[r]) * km2;
      float p3 = __expf(s[3][r] - B[r]) * km3;
      lsum[r] += (p0 + p1) + (p2 + p3);
      int pm = w * 16 + g * 4 + r;
      unsigned char* prow = Ps + pm * 128;
      int psw = (pm & 7) << 4;
      *(__bf16*)(prow + ((2 * (l15)      ) ^ psw)) = (__bf16)p0;
      *(__bf16*)(prow + ((2 * (16 + l15) ) ^ psw)) = (__bf16)p1;
      *(__bf16*)(prow + ((2 * (32 + l15) ) ^ psw)) = (__bf16)p2;
      *(__bf16*)(prow + ((2 * (48 + l15) ) ^ psw)) = (__bf16)p3;
    }

    // O += P @ V
    {
      const unsigned char* parow = Ps + (w * 16 + l15) * 128;
      bf16x8 pa0 = *(const bf16x8*)(parow + ((g * 16)      ^ rsw));
      bf16x8 pa1 = *(const bf16x8*)(parow + ((64 + g * 16) ^ rsw));
#pragma unroll
      for (int j = 0; j < 4; ++j) {
        const unsigned char* vrow = Vs + (16 * j + l15) * 128;
        bf16x8 vf0 = *(const bf16x8*)(vrow + ((g * 16)      ^ rsw));
        bf16x8 vf1 = *(const bf16x8*)(vrow + ((64 + g * 16) ^ rsw));
        o[j] = __builtin_amdgcn_mfma_f32_16x16x32_bf16(pa0, vf0, o[j], 0, 0, 0);
        o[j] = __builtin_amdgcn_mfma_f32_16x16x32_bf16(pa1, vf1, o[j], 0, 0, 0);
      }
    }
  }

  // epilogue: one-time row-sum reduction, write normalized partial O + LSE
#pragma unroll
  for (int r = 0; r < 4; ++r) {
    float l = lsum[r];
    l += __shfl_xor(l, 1);
    l += __shfl_xor(l, 2);
    l += __shfl_xor(l, 4);
    l += __shfl_xor(l, 8);
    float inv = (l > 0.f) ? 1.f / l : 0.f;
    int row = qb * 64 + w * 16 + g * 4 + r;
    size_t base = half * QKV_ELEMS + ((size_t)bh * SEQ + row) * DHEAD + l15;
    Po[base]      = bfbits(o[0][r] * inv);
    Po[base + 16] = bfbits(o[1][r] * inv);
    Po[base + 32] = bfbits(o[2][r] * inv);
    Po[base + 48] = bfbits(o[3][r] * inv);
    if (l15 == 0)
      LSE[half * (BATCH * HEADS * SEQ) + bh * SEQ + row] =
          (l > 0.f) ? B[r] + __logf(l) : -3.0e38f;
  }
}

// ---------------- combine halves + depthwise conv residual -> Obf bf16 -------
__global__ __launch_bounds__(256) void combine_conv(
    const unsigned short* __restrict__ Po, const float* __restrict__ LSE,
    const unsigned short* __restrict__ Vt, const float* __restrict__ cw,
    unsigned short* __restrict__ Obf) {
  __shared__ float T[96][68];
  __shared__ float cwl[33];
  const int tid = threadIdx.x;
  const int bid = blockIdx.x;              // 512 = 16 bh x 32 n-chunks
  const int bh = bid >> 5;
  const int n0 = (bid & 31) * 64;
  const int hh = bh & 7;
  if (tid < 33) cwl[tid] = cw[hh * 33 + tid];
  for (int idx = tid; idx < 64 * 24; idx += 256) {
    int d = idx / 24, c4 = idx - (idx / 24) * 24;
    int nbase = n0 - 16 + c4 * 4;
    const unsigned short* src = Vt + ((size_t)bh * DHEAD + d) * SEQ;
#pragma unroll
    for (int q = 0; q < 4; ++q) {
      int n = nbase + q;
      T[c4 * 4 + q][d] = (n >= 0 && n < SEQ) ? bf2f(src[n]) : 0.f;
    }
  }
  __syncthreads();
#pragma unroll
  for (int p = 0; p < 4; ++p) {
    int n = (tid >> 4) + p * 16;           // 0..63
    int d4 = tid & 15;
    int row = bh * SEQ + n0 + n;
    float ls0 = LSE[row], ls1 = LSE[BATCH * HEADS * SEQ + row];
    float m = fmaxf(ls0, ls1);
    float w0 = __expf(ls0 - m), w1 = __expf(ls1 - m);
    float inv = 1.f / (w0 + w1);
    w0 *= inv; w1 *= inv;
    const unsigned short* p0 = Po + (size_t)row * DHEAD + d4 * 4;
    const unsigned short* p1 = p0 + QKV_ELEMS;
    ushort4 a = *(const ushort4*)p0, b = *(const ushort4*)p1;
    float o0 = w0 * bf2f(a.x) + w1 * bf2f(b.x);
    float o1 = w0 * bf2f(a.y) + w1 * bf2f(b.y);
    float o2 = w0 * bf2f(a.z) + w1 * bf2f(b.z);
    float o3 = w0 * bf2f(a.w) + w1 * bf2f(b.w);
#pragma unroll
    for (int t = 0; t < 33; ++t) {
      float wv = cwl[t];
      float4 tv = *(const float4*)&T[n + t][d4 * 4];
      o0 += wv * tv.x; o1 += wv * tv.y; o2 += wv * tv.z; o3 += wv * tv.w;
    }
    union { unsigned short u[4]; ushort4 v; } pk;
    pk.u[0] = bfbits(o0); pk.u[1] = bfbits(o1);
    pk.u[2] = bfbits(o2); pk.u[3] = bfbits(o3);
    *(ushort4*)(Obf + (size_t)row * DHEAD + d4 * 4) = pk.v;
  }
}

// ---------------- out GEMM (MFMA): Obf bf16 gather-A, 64x64 tiles ------------
__global__ __launch_bounds__(256) void gemm_out_mfma(
    const unsigned short* __restrict__ Obf, const unsigned short* __restrict__ Wt,
    const float* __restrict__ bias, const float* __restrict__ maskf,
    float* __restrict__ out) {
  __shared__ __align__(16) unsigned char Al[64 * 128];
  __shared__ __align__(16) unsigned char Bl[64 * 128];
  const int tid = threadIdx.x;
  const int lane = tid & 63;
  const int w = tid >> 6;
  const int l15 = lane & 15, g = lane >> 4;
  const int wr = w >> 1, wc = w & 1;
  int bid = blockIdx.x;                    // 512 blocks
  int lid = (bid & 7) * 64 + (bid >> 3);
  int by = lid >> 3, bx = lid & 7;         // by 0..63, bx 0..7
  const int m0 = by * 64, n0 = bx * 64;
  const int bb = m0 >> 11;
  const int ii0 = m0 & (SEQ - 1);

  f32x4 acc[2][2] = {};
  const int srow = tid >> 3, scg = tid & 7;
  const int rsw = (l15 & 7) << 4;

  for (int k0 = 0; k0 < DIMM; k0 += 64) {
    const int hh = k0 >> 6;
    __syncthreads();
#pragma unroll
    for (int it = 0; it < 2; ++it) {
      int row = srow + it * 32;
      int sw = (row & 7) << 4;
      *(int4*)(Al + row * 128 + ((scg * 16) ^ sw)) =
          *(const int4*)(Obf + ((size_t)(bb * HEADS + hh) * SEQ + ii0 + row) * DHEAD + scg * 8);
      *(int4*)(Bl + row * 128 + ((scg * 16) ^ sw)) =
          *(const int4*)(Wt + (size_t)(n0 + row) * DIMM + k0 + scg * 8);
    }
    __syncthreads();
#pragma unroll
    for (int ks = 0; ks < 2; ++ks) {
      bf16x8 af[2], bfr[2];
#pragma unroll
      for (int mi = 0; mi < 2; ++mi)
        af[mi] = *(const bf16x8*)(Al + (wr * 32 + mi * 16 + l15) * 128 +
                                  ((ks * 64 + g * 16) ^ rsw));
#pragma unroll
      for (int nj = 0; nj < 2; ++nj)
        bfr[nj] = *(const bf16x8*)(Bl + (wc * 32 + nj * 16 + l15) * 128 +
                                   ((ks * 64 + g * 16) ^ rsw));
#pragma unroll
      for (int mi = 0; mi < 2; ++mi)
#pragma unroll
        for (int nj = 0; nj < 2; ++nj)
          acc[mi][nj] = __builtin_amdgcn_mfma_f32_16x16x32_bf16(
              af[mi], bfr[nj], acc[mi][nj], 0, 0, 0);
    }
  }
#pragma unroll
  for (int nj = 0; nj < 2; ++nj) {
    int col = n0 + wc * 32 + nj * 16 + l15;
    float bcol = bias[col];
#pragma unroll
    for (int mi = 0; mi < 2; ++mi) {
#pragma unroll
      for (int r = 0; r < 4; ++r) {
        int m = m0 + wr * 32 + mi * 16 + g * 4 + r;
        out[(size_t)m * DIMM + col] = (acc[mi][nj][r] + bcol) * maskf[m];
      }
    }
  }
}

extern "C" void kernel_launch(void* const* d_in, const int* in_sizes, int n_in,
                              void* d_out, int out_size, void* d_ws, size_t ws_size,
                              hipStream_t stream) {
  const float* x     = (const float*)d_in[0];
  const void*  mask  = d_in[1];
  const float* Wqkv  = (const float*)d_in[2];
  const float* Wout  = (const float*)d_in[3];
  const float* bout  = (const float*)d_in[4];
  const float* convw = (const float*)d_in[5];
  float* out = (float*)d_out;

  float* maskf = (float*)d_ws;
  unsigned* kmaxn = (unsigned*)(maskf + 4096);           // 16 used, pad 64
  unsigned short* Qbf = (unsigned short*)(kmaxn + 64);
  unsigned short* Kbf = Qbf + QKV_ELEMS;
  unsigned short* Vt  = Kbf + QKV_ELEMS;
  unsigned short* Po  = Vt + QKV_ELEMS;                  // 2 halves
  float* LSE          = (float*)(Po + 2 * QKV_ELEMS);    // 2 * 32768
  unsigned short* Obf = (unsigned short*)(LSE + 2 * BATCH * HEADS * SEQ);
  unsigned short* Wtq = Obf + QKV_ELEMS;                 // 1536*512
  unsigned short* Wto = Wtq + (size_t)NQKV * DIMM;       // 512*512

  prep_mask<<<1, 1024, 0, stream>>>(mask, maskf, kmaxn);
  transpose_w<<<dim3(NQKV / 64, DIMM / 64), 256, 0, stream>>>(Wqkv, Wtq, DIMM, NQKV);
  transpose_w<<<dim3(DIMM / 64, DIMM / 64), 256, 0, stream>>>(Wout, Wto, DIMM, DIMM);
  gemm_qkv_mfma<<<768, 256, 0, stream>>>(x, Wtq, Qbf, Kbf, Vt);
  knorm<<<(BATCH * HEADS * SEQ) / 256, 256, 0, stream>>>(Kbf, kmaxn);
  attn_split<<<1024, 256, 0, stream>>>(Qbf, Kbf, Vt, maskf, kmaxn, Po, LSE);
  combine_conv<<<512, 256, 0, stream>>>(Po, LSE, Vt, convw, Obf);
  gemm_out_mfma<<<512, 256, 0, stream>>>(Obf, Wto, bout, maskf, out);
}

// Round 6
// 101.979 us; speedup vs baseline: 7.3123x; 1.0722x over previous
//
#include <hip/hip_runtime.h>
#include <float.h>

#define BATCH 2
#define SEQ   2048
#define HEADS 8
#define DHEAD 64
#define DIMM  512
#define NQKV  1536
#define QK_SCALE 0.125f            // 64^-0.5
#define QSCALE_L2 (0.125f * 1.44269504f)   // fold log2(e) into Q for exp2 softmax

#define QKV_ELEMS ((size_t)BATCH * HEADS * SEQ * DHEAD)   // 2097152

typedef __bf16 bf16x8 __attribute__((ext_vector_type(8)));
typedef short  s16x4  __attribute__((ext_vector_type(4)));
typedef float  f32x4  __attribute__((ext_vector_type(4)));

#if __has_builtin(__builtin_amdgcn_exp2f)
#define EXP2F __builtin_amdgcn_exp2f
#else
#define EXP2F exp2f
#endif

__device__ __forceinline__ unsigned short bfbits(float f) {
  __bf16 h = (__bf16)f;
  return *(unsigned short*)&h;
}
__device__ __forceinline__ float bf2f(unsigned short u) {
  return __uint_as_float((unsigned)u << 16);
}
__device__ __forceinline__ unsigned cvtpk(float a, float b) {
  unsigned r;
  asm("v_cvt_pk_bf16_f32 %0, %1, %2" : "=v"(r) : "v"(a), "v"(b));
  return r;
}
// D = A(16x16) * B(16x16) + C with k=16; A: row=l&15,k=4*(l>>4)+i; B: col=l&15,
// same k; D: col=l&15, row=4*(l>>4)+r.
__device__ __forceinline__ f32x4 mfma16(s16x4 a, s16x4 b, f32x4 c) {
#if __has_builtin(__builtin_amdgcn_mfma_f32_16x16x16bf16_1k)
  return __builtin_amdgcn_mfma_f32_16x16x16bf16_1k(a, b, c, 0, 0, 0);
#else
  f32x4 d;
  asm("v_mfma_f32_16x16x16_bf16 %0, %1, %2, %3" : "=v"(d) : "v"(a), "v"(b), "v"(c));
  return d;
#endif
}

// ---------------- mask prep: sniff dtype, normalize to float 0/1 -------------
__global__ __launch_bounds__(1024) void prep_mask(const void* __restrict__ mraw,
                                                  float* __restrict__ maskf,
                                                  unsigned* __restrict__ kmaxn) {
  __shared__ int f_bf16, f_f32, f_gt1, f_oddnz;
  const int t = threadIdx.x;
  if (t < 16) kmaxn[t] = 0u;              // init for knorm's atomicMax
  if (t == 0) { f_bf16 = 0; f_f32 = 0; f_gt1 = 0; f_oddnz = 0; }
  __syncthreads();
  const unsigned int* w = (const unsigned int*)mraw;
  unsigned int v = w[t];
  if (v == 0x3f803f80u) f_bf16 = 1;
  if (v == 0x3f800000u) f_f32 = 1;
  if (v > 1u)           f_gt1 = 1;
  if ((t & 1) && v != 0u) f_oddnz = 1;
  __syncthreads();
  int mode;                               // 0=i32 1=u8 2=i64 3=f32 4=bf16
  if (f_bf16)       mode = 4;
  else if (f_f32)   mode = 3;
  else if (f_gt1)   mode = 1;
  else if (!f_oddnz) mode = 2;
  else              mode = 0;
  for (int i = t; i < BATCH * SEQ; i += 1024) {
    bool keep;
    if (mode == 4)      keep = ((const unsigned short*)mraw)[i] != 0;
    else if (mode == 3) keep = ((const float*)mraw)[i] != 0.f;
    else if (mode == 1) keep = ((const unsigned char*)mraw)[i] != 0;
    else if (mode == 2) keep = w[2 * i] != 0u;
    else                keep = w[i] != 0u;
    maskf[i] = keep ? 1.f : 0.f;
  }
}

// ---------------- X fp32 -> bf16 (once; halves qkv staging work) -------------
__global__ __launch_bounds__(256) void x_to_bf16(const float* __restrict__ X,
                                                 unsigned short* __restrict__ Xbf) {
  size_t i = ((size_t)blockIdx.x * 256 + threadIdx.x) * 8;
  float4 a0 = *(const float4*)(X + i);
  float4 a1 = *(const float4*)(X + i + 4);
  union { unsigned short u[8]; int4 v; } pk;
  pk.u[0] = bfbits(a0.x); pk.u[1] = bfbits(a0.y);
  pk.u[2] = bfbits(a0.z); pk.u[3] = bfbits(a0.w);
  pk.u[4] = bfbits(a1.x); pk.u[5] = bfbits(a1.y);
  pk.u[6] = bfbits(a1.z); pk.u[7] = bfbits(a1.w);
  *(int4*)(Xbf + i) = pk.v;
}

// ---------------- weight transpose+convert: W fp32 [K][N] -> Wt bf16 [N][K] --
__global__ __launch_bounds__(256) void transpose_w(const float* __restrict__ W,
                                                   unsigned short* __restrict__ Wt,
                                                   int K, int N) {
  __shared__ float T[64][65];
  const int t = threadIdx.x;
  const int n0 = blockIdx.x * 64, k0 = blockIdx.y * 64;
  {
    int r0 = t >> 4, c4 = t & 15;
#pragma unroll
    for (int rr = 0; rr < 4; ++rr) {
      int r = r0 + rr * 16;
      float4 v = *(const float4*)(W + (size_t)(k0 + r) * N + n0 + c4 * 4);
      T[r][c4 * 4 + 0] = v.x; T[r][c4 * 4 + 1] = v.y;
      T[r][c4 * 4 + 2] = v.z; T[r][c4 * 4 + 3] = v.w;
    }
  }
  __syncthreads();
  {
    int n = t >> 2, kc = t & 3;
    union { unsigned short u[16]; int4 v[2]; } p;
#pragma unroll
    for (int i = 0; i < 16; ++i) p.u[i] = bfbits(T[kc * 16 + i][n]);
    int4* dst = (int4*)(Wt + (size_t)(n0 + n) * K + k0 + kc * 16);
    dst[0] = p.v[0]; dst[1] = p.v[1];
  }
}

// ---------------- qkv GEMM (MFMA): 128x64 tiles, 768 blocks ------------------
__global__ __launch_bounds__(256) void gemm_qkv_mfma(
    const unsigned short* __restrict__ Xbf, const unsigned short* __restrict__ Wt,
    unsigned short* __restrict__ Qbf, unsigned short* __restrict__ Kbf,
    unsigned short* __restrict__ Vt) {
  __shared__ __align__(16) unsigned char Al[128 * 128];
  __shared__ __align__(16) unsigned char Bl[64 * 128];
  const int tid = threadIdx.x;
  const int lane = tid & 63;
  const int w = tid >> 6;
  const int l15 = lane & 15, g = lane >> 4;
  const int wr = w >> 1, wc = w & 1;
  int bid = blockIdx.x;                    // 768 blocks, 768%8==0 -> bijective
  int lid = (bid & 7) * 96 + (bid >> 3);
  int by = lid / 24, bx = lid - by * 24;   // by 0..31, bx 0..23
  const int m0 = by * 128;

  f32x4 acc[4][2] = {};
  const int srow = tid >> 3, scg = tid & 7;
  const int rsw = (l15 & 7) << 4;

  for (int k0 = 0; k0 < DIMM; k0 += 64) {
    __syncthreads();
#pragma unroll
    for (int it = 0; it < 4; ++it) {
      int row = srow + it * 32;
      int sw = (row & 7) << 4;
      *(int4*)(Al + row * 128 + ((scg * 16) ^ sw)) =
          *(const int4*)(Xbf + (size_t)(m0 + row) * DIMM + k0 + scg * 8);
      if (it < 2) {
        *(int4*)(Bl + row * 128 + ((scg * 16) ^ sw)) =
            *(const int4*)(Wt + (size_t)(bx * 64 + row) * DIMM + k0 + scg * 8);
      }
    }
    __syncthreads();
#pragma unroll
    for (int ks = 0; ks < 2; ++ks) {
      bf16x8 af[4], bfr[2];
#pragma unroll
      for (int mi = 0; mi < 4; ++mi)
        af[mi] = *(const bf16x8*)(Al + (wr * 64 + mi * 16 + l15) * 128 +
                                  ((ks * 64 + g * 16) ^ rsw));
#pragma unroll
      for (int nj = 0; nj < 2; ++nj)
        bfr[nj] = *(const bf16x8*)(Bl + (wc * 32 + nj * 16 + l15) * 128 +
                                   ((ks * 64 + g * 16) ^ rsw));
#pragma unroll
      for (int mi = 0; mi < 4; ++mi)
#pragma unroll
        for (int nj = 0; nj < 2; ++nj)
          acc[mi][nj] = __builtin_amdgcn_mfma_f32_16x16x32_bf16(
              af[mi], bfr[nj], acc[mi][nj], 0, 0, 0);
    }
  }
  const int chunk = bx >> 3;               // 0=Q 1=K 2=V
  const int bb = m0 >> 11;
#pragma unroll
  for (int nj = 0; nj < 2; ++nj) {
    int col = (bx & 7) * 64 + wc * 32 + nj * 16 + l15;    // 0..511
    int hh = col >> 6, dd = col & 63;
#pragma unroll
    for (int mi = 0; mi < 4; ++mi) {
      int ii0 = (m0 & (SEQ - 1)) + wr * 64 + mi * 16 + g * 4;
      if (chunk == 2) {
        union { unsigned short u[4]; ushort4 v; } pk;
#pragma unroll
        for (int r = 0; r < 4; ++r) pk.u[r] = bfbits(acc[mi][nj][r]);
        *(ushort4*)(Vt + ((size_t)(bb * HEADS + hh) * DHEAD + dd) * SEQ + ii0) = pk.v;
      } else {
        unsigned short* dst = (chunk == 0) ? Qbf : Kbf;
        float sc = (chunk == 0) ? QSCALE_L2 : 1.f;
#pragma unroll
        for (int r = 0; r < 4; ++r)
          dst[((size_t)(bb * HEADS + hh) * SEQ + ii0 + r) * DHEAD + dd] =
              bfbits(acc[mi][nj][r] * sc);
      }
    }
  }
}

// ---------------- per-(b,h) max key-norm^2 (for softmax shift bound) ---------
__global__ __launch_bounds__(256) void knorm(const unsigned short* __restrict__ Kbf,
                                             unsigned* __restrict__ kmaxn) {
  int row = blockIdx.x * 256 + threadIdx.x;       // 32768 rows
  const bf16x8* kr = (const bf16x8*)(Kbf + (size_t)row * DHEAD);
  float n2 = 0.f;
#pragma unroll
  for (int c = 0; c < 8; ++c) {
    bf16x8 v = kr[c];
#pragma unroll
    for (int i = 0; i < 8; ++i) { float f = (float)v[i]; n2 += f * f; }
  }
#pragma unroll
  for (int d = 1; d < 64; d <<= 1) n2 = fmaxf(n2, __shfl_xor(n2, d));
  if ((threadIdx.x & 63) == 0)
    atomicMax(kmaxn + (row >> 11), __float_as_uint(n2));
}

// ---------------- flash attention: swapped QK^T, in-register P, x16 PV -------
// S^T = mfma(K,Q): lane (l15,g) holds P[q=l15][key=16j+4g+r] -> exp2 ->
// cvt_pk to bf16x4 = A-frag of mfma_16x16x16 for PV. No P LDS round-trip.
__global__ __launch_bounds__(256) void attn_split(const unsigned short* __restrict__ Qbf,
                                                  const unsigned short* __restrict__ Kbf,
                                                  const unsigned short* __restrict__ Vt,
                                                  const float* __restrict__ maskf,
                                                  const unsigned* __restrict__ kmaxn,
                                                  unsigned short* __restrict__ Po,
                                                  float* __restrict__ LSE) {
  __shared__ __align__(16) unsigned char Ks[8192];
  __shared__ __align__(16) unsigned char Vs[8192];
  __shared__ __align__(16) float skm[64];

  const int tid = threadIdx.x;
  const int lane = tid & 63;
  const int w = tid >> 6;
  const int l15 = lane & 15, g = lane >> 4;

  int fid = blockIdx.x;
  int lid = (fid & 7) * 128 + (fid >> 3);  // bijective over 1024
  const int bh = lid >> 6;                 // 0..15
  const int rem = lid & 63;
  const int qb = rem >> 1;                 // 0..31
  const int half = rem & 1;
  const int bb = bh >> 3;

  const unsigned short* Qg = Qbf + ((size_t)bh * SEQ + qb * 64) * DHEAD;
  const unsigned short* Kg = Kbf + (size_t)bh * SEQ * DHEAD;
  const unsigned short* Vg = Vt  + (size_t)bh * DHEAD * SEQ;

  bf16x8 qf0, qf1;
  {
    const unsigned char* qrow = (const unsigned char*)(Qg + (size_t)(w * 16 + l15) * DHEAD);
    qf0 = *(const bf16x8*)(qrow + g * 16);
    qf1 = *(const bf16x8*)(qrow + 64 + g * 16);
  }
  // ||q||^2 for q=l15 fully in-register (lane holds 16 of 64 dims)
  float Bx, Bnat;
  {
    float qn2 = 0.f;
#pragma unroll
    for (int i = 0; i < 8; ++i) {
      float a = (float)qf0[i]; qn2 += a * a;
      float b = (float)qf1[i]; qn2 += b * b;
    }
    qn2 += __shfl_xor(qn2, 16);
    qn2 += __shfl_xor(qn2, 32);
    const float kmax2 = __uint_as_float(kmaxn[bh]);
    Bx = sqrtf(qn2 * kmax2);               // bound in log2 units (Q pre-scaled)
    Bnat = Bx * 0.69314718f;
  }

  f32x4 o[4] = {};
  float lsum = 0.f;

  const int sm = tid >> 2;
  const int sc = (tid & 3) * 32;
  const int ssw = (sm & 7) << 4;
  const int rsw = (l15 & 7) << 4;

  const int kt0 = half * 16;
  // T14 async-stage: prefetch tile kt0 into regs
  int4 rk0, rk1, rv0, rv1;
  float rmv = 0.f;
  {
    const unsigned char* ksrc =
        (const unsigned char*)(Kg + (size_t)kt0 * 64 * DHEAD) + sm * 128 + sc;
    const unsigned char* vsrc =
        (const unsigned char*)(Vg + (size_t)sm * SEQ + kt0 * 64) + sc;
    rk0 = *(const int4*)(ksrc); rk1 = *(const int4*)(ksrc + 16);
    rv0 = *(const int4*)(vsrc); rv1 = *(const int4*)(vsrc + 16);
    if (tid < 64) rmv = maskf[bb * SEQ + kt0 * 64 + tid];
  }

  for (int kt = kt0; kt < kt0 + 16; ++kt) {
    __syncthreads();                       // previous tile's LDS reads done
    *(int4*)(Ks + sm * 128 + ((sc)      ^ ssw)) = rk0;
    *(int4*)(Ks + sm * 128 + ((sc + 16) ^ ssw)) = rk1;
    *(int4*)(Vs + sm * 128 + ((sc)      ^ ssw)) = rv0;
    *(int4*)(Vs + sm * 128 + ((sc + 16) ^ ssw)) = rv1;
    if (tid < 64) skm[tid] = rmv;
    if (kt + 1 < kt0 + 16) {               // issue next tile's loads now;
      const unsigned char* ksrc =          // they complete under this compute
          (const unsigned char*)(Kg + (size_t)(kt + 1) * 64 * DHEAD) + sm * 128 + sc;
      const unsigned char* vsrc =
          (const unsigned char*)(Vg + (size_t)sm * SEQ + (kt + 1) * 64) + sc;
      rk0 = *(const int4*)(ksrc); rk1 = *(const int4*)(ksrc + 16);
      rv0 = *(const int4*)(vsrc); rv1 = *(const int4*)(vsrc + 16);
      if (tid < 64) rmv = maskf[bb * SEQ + (kt + 1) * 64 + tid];
    }
    __syncthreads();

    // S^T = K · Q^T : lane (l15,g) gets S[key=16j+4g+r][q=l15]
    f32x4 s[4];
#pragma unroll
    for (int j = 0; j < 4; ++j) {
      const unsigned char* krow = Ks + (16 * j + l15) * 128;
      bf16x8 kf0 = *(const bf16x8*)(krow + ((g * 16)      ^ rsw));
      bf16x8 kf1 = *(const bf16x8*)(krow + ((64 + g * 16) ^ rsw));
      f32x4 z = (f32x4){0.f, 0.f, 0.f, 0.f};
      z = __builtin_amdgcn_mfma_f32_16x16x32_bf16(kf0, qf0, z, 0, 0, 0);
      z = __builtin_amdgcn_mfma_f32_16x16x32_bf16(kf1, qf1, z, 0, 0, 0);
      s[j] = z;
    }

    // p = exp2(s - Bx) * km ; pack to bf16x4 A-fragments in-register
    s16x4 pa[4];
#pragma unroll
    for (int j = 0; j < 4; ++j) {
      float4 km4 = *(const float4*)&skm[16 * j + 4 * g];
      float p0 = EXP2F(s[j][0] - Bx) * km4.x;
      float p1 = EXP2F(s[j][1] - Bx) * km4.y;
      float p2 = EXP2F(s[j][2] - Bx) * km4.z;
      float p3 = EXP2F(s[j][3] - Bx) * km4.w;
      lsum += (p0 + p1) + (p2 + p3);
      union { uint2 u; s16x4 v; } pk;
      pk.u.x = cvtpk(p0, p1);
      pk.u.y = cvtpk(p2, p3);
      pa[j] = pk.v;
    }

    // O += P @ V via 16x16x16: B-frag = 4 consecutive keys of V^T row d
#pragma unroll
    for (int dj = 0; dj < 4; ++dj) {
      const unsigned char* vrow = Vs + (16 * dj + l15) * 128;
#pragma unroll
      for (int j = 0; j < 4; ++j) {
        s16x4 vb = *(const s16x4*)(vrow + ((32 * j + 8 * g) ^ rsw));
        o[dj] = mfma16(pa[j], vb, o[dj]);
      }
    }
  }

  // epilogue: row sums across g-lanes, redistribute, write partial O + LSE
  lsum += __shfl_xor(lsum, 16);
  lsum += __shfl_xor(lsum, 32);
#pragma unroll
  for (int r = 0; r < 4; ++r) {
    float lr = __shfl(lsum, 4 * g + r);    // sum for q-row 4g+r
    float inv = (lr > 0.f) ? 1.f / lr : 0.f;
    int row = qb * 64 + w * 16 + 4 * g + r;
    size_t base = half * QKV_ELEMS + ((size_t)bh * SEQ + row) * DHEAD + l15;
    Po[base]      = bfbits(o[0][r] * inv);
    Po[base + 16] = bfbits(o[1][r] * inv);
    Po[base + 32] = bfbits(o[2][r] * inv);
    Po[base + 48] = bfbits(o[3][r] * inv);
  }
  if (g == 0) {
    int row = qb * 64 + w * 16 + l15;
    LSE[half * (BATCH * HEADS * SEQ) + bh * SEQ + row] =
        (lsum > 0.f) ? Bnat + __logf(lsum) : -3.0e38f;
  }
}

// ---------------- combine halves + depthwise conv residual -> Obf bf16 -------
__global__ __launch_bounds__(256) void combine_conv(
    const unsigned short* __restrict__ Po, const float* __restrict__ LSE,
    const unsigned short* __restrict__ Vt, const float* __restrict__ cw,
    unsigned short* __restrict__ Obf) {
  __shared__ float T[96][68];
  __shared__ float cwl[33];
  const int tid = threadIdx.x;
  const int bid = blockIdx.x;              // 512 = 16 bh x 32 n-chunks
  const int bh = bid >> 5;
  const int n0 = (bid & 31) * 64;
  const int hh = bh & 7;
  if (tid < 33) cwl[tid] = cw[hh * 33 + tid];
  for (int idx = tid; idx < 64 * 24; idx += 256) {
    int d = idx / 24, c4 = idx - (idx / 24) * 24;
    int nbase = n0 - 16 + c4 * 4;
    const unsigned short* src = Vt + ((size_t)bh * DHEAD + d) * SEQ;
#pragma unroll
    for (int q = 0; q < 4; ++q) {
      int n = nbase + q;
      T[c4 * 4 + q][d] = (n >= 0 && n < SEQ) ? bf2f(src[n]) : 0.f;
    }
  }
  __syncthreads();
#pragma unroll
  for (int p = 0; p < 4; ++p) {
    int n = (tid >> 4) + p * 16;           // 0..63
    int d4 = tid & 15;
    int row = bh * SEQ + n0 + n;
    float ls0 = LSE[row], ls1 = LSE[BATCH * HEADS * SEQ + row];
    float m = fmaxf(ls0, ls1);
    float w0 = __expf(ls0 - m), w1 = __expf(ls1 - m);
    float inv = 1.f / (w0 + w1);
    w0 *= inv; w1 *= inv;
    const unsigned short* p0 = Po + (size_t)row * DHEAD + d4 * 4;
    const unsigned short* p1 = p0 + QKV_ELEMS;
    ushort4 a = *(const ushort4*)p0, b = *(const ushort4*)p1;
    float o0 = w0 * bf2f(a.x) + w1 * bf2f(b.x);
    float o1 = w0 * bf2f(a.y) + w1 * bf2f(b.y);
    float o2 = w0 * bf2f(a.z) + w1 * bf2f(b.z);
    float o3 = w0 * bf2f(a.w) + w1 * bf2f(b.w);
#pragma unroll
    for (int t = 0; t < 33; ++t) {
      float wv = cwl[t];
      float4 tv = *(const float4*)&T[n + t][d4 * 4];
      o0 += wv * tv.x; o1 += wv * tv.y; o2 += wv * tv.z; o3 += wv * tv.w;
    }
    union { unsigned short u[4]; ushort4 v; } pk;
    pk.u[0] = bfbits(o0); pk.u[1] = bfbits(o1);
    pk.u[2] = bfbits(o2); pk.u[3] = bfbits(o3);
    *(ushort4*)(Obf + (size_t)row * DHEAD + d4 * 4) = pk.v;
  }
}

// ---------------- out GEMM (MFMA): Obf bf16 gather-A, 64x64 tiles ------------
__global__ __launch_bounds__(256) void gemm_out_mfma(
    const unsigned short* __restrict__ Obf, const unsigned short* __restrict__ Wt,
    const float* __restrict__ bias, const float* __restrict__ maskf,
    float* __restrict__ out) {
  __shared__ __align__(16) unsigned char Al[64 * 128];
  __shared__ __align__(16) unsigned char Bl[64 * 128];
  const int tid = threadIdx.x;
  const int lane = tid & 63;
  const int w = tid >> 6;
  const int l15 = lane & 15, g = lane >> 4;
  const int wr = w >> 1, wc = w & 1;
  int bid = blockIdx.x;                    // 512 blocks
  int lid = (bid & 7) * 64 + (bid >> 3);
  int by = lid >> 3, bx = lid & 7;         // by 0..63, bx 0..7
  const int m0 = by * 64, n0 = bx * 64;
  const int bb = m0 >> 11;
  const int ii0 = m0 & (SEQ - 1);

  f32x4 acc[2][2] = {};
  const int srow = tid >> 3, scg = tid & 7;
  const int rsw = (l15 & 7) << 4;

  for (int k0 = 0; k0 < DIMM; k0 += 64) {
    const int hh = k0 >> 6;
    __syncthreads();
#pragma unroll
    for (int it = 0; it < 2; ++it) {
      int row = srow + it * 32;
      int sw = (row & 7) << 4;
      *(int4*)(Al + row * 128 + ((scg * 16) ^ sw)) =
          *(const int4*)(Obf + ((size_t)(bb * HEADS + hh) * SEQ + ii0 + row) * DHEAD + scg * 8);
      *(int4*)(Bl + row * 128 + ((scg * 16) ^ sw)) =
          *(const int4*)(Wt + (size_t)(n0 + row) * DIMM + k0 + scg * 8);
    }
    __syncthreads();
#pragma unroll
    for (int ks = 0; ks < 2; ++ks) {
      bf16x8 af[2], bfr[2];
#pragma unroll
      for (int mi = 0; mi < 2; ++mi)
        af[mi] = *(const bf16x8*)(Al + (wr * 32 + mi * 16 + l15) * 128 +
                                  ((ks * 64 + g * 16) ^ rsw));
#pragma unroll
      for (int nj = 0; nj < 2; ++nj)
        bfr[nj] = *(const bf16x8*)(Bl + (wc * 32 + nj * 16 + l15) * 128 +
                                   ((ks * 64 + g * 16) ^ rsw));
#pragma unroll
      for (int mi = 0; mi < 2; ++mi)
#pragma unroll
        for (int nj = 0; nj < 2; ++nj)
          acc[mi][nj] = __builtin_amdgcn_mfma_f32_16x16x32_bf16(
              af[mi], bfr[nj], acc[mi][nj], 0, 0, 0);
    }
  }
#pragma unroll
  for (int nj = 0; nj < 2; ++nj) {
    int col = n0 + wc * 32 + nj * 16 + l15;
    float bcol = bias[col];
#pragma unroll
    for (int mi = 0; mi < 2; ++mi) {
#pragma unroll
      for (int r = 0; r < 4; ++r) {
        int m = m0 + wr * 32 + mi * 16 + g * 4 + r;
        out[(size_t)m * DIMM + col] = (acc[mi][nj][r] + bcol) * maskf[m];
      }
    }
  }
}

extern "C" void kernel_launch(void* const* d_in, const int* in_sizes, int n_in,
                              void* d_out, int out_size, void* d_ws, size_t ws_size,
                              hipStream_t stream) {
  const float* x     = (const float*)d_in[0];
  const void*  mask  = d_in[1];
  const float* Wqkv  = (const float*)d_in[2];
  const float* Wout  = (const float*)d_in[3];
  const float* bout  = (const float*)d_in[4];
  const float* convw = (const float*)d_in[5];
  float* out = (float*)d_out;

  float* maskf = (float*)d_ws;
  unsigned* kmaxn = (unsigned*)(maskf + 4096);           // 16 used, pad 64
  unsigned short* Qbf = (unsigned short*)(kmaxn + 64);
  unsigned short* Kbf = Qbf + QKV_ELEMS;
  unsigned short* Vt  = Kbf + QKV_ELEMS;
  unsigned short* Po  = Vt + QKV_ELEMS;                  // 2 halves
  float* LSE          = (float*)(Po + 2 * QKV_ELEMS);    // 2 * 32768
  unsigned short* Obf = (unsigned short*)(LSE + 2 * BATCH * HEADS * SEQ);
  unsigned short* Wtq = Obf + QKV_ELEMS;                 // 1536*512
  unsigned short* Wto = Wtq + (size_t)NQKV * DIMM;       // 512*512
  unsigned short* Xbf = Wto + (size_t)DIMM * DIMM;       // 4096*512

  prep_mask<<<1, 1024, 0, stream>>>(mask, maskf, kmaxn);
  x_to_bf16<<<1024, 256, 0, stream>>>(x, Xbf);
  transpose_w<<<dim3(NQKV / 64, DIMM / 64), 256, 0, stream>>>(Wqkv, Wtq, DIMM, NQKV);
  transpose_w<<<dim3(DIMM / 64, DIMM / 64), 256, 0, stream>>>(Wout, Wto, DIMM, DIMM);
  gemm_qkv_mfma<<<768, 256, 0, stream>>>(Xbf, Wtq, Qbf, Kbf, Vt);
  knorm<<<(BATCH * HEADS * SEQ) / 256, 256, 0, stream>>>(Kbf, kmaxn);
  attn_split<<<1024, 256, 0, stream>>>(Qbf, Kbf, Vt, maskf, kmaxn, Po, LSE);
  combine_conv<<<512, 256, 0, stream>>>(Po, LSE, Vt, convw, Obf);
  gemm_out_mfma<<<512, 256, 0, stream>>>(Obf, Wto, bout, maskf, out);
}

// Round 7
// 100.433 us; speedup vs baseline: 7.4249x; 1.0154x over previous
//
#include <hip/hip_runtime.h>
#include <float.h>

#define BATCH 2
#define SEQ   2048
#define HEADS 8
#define DHEAD 64
#define DIMM  512
#define NQKV  1536
#define QSCALE_L2 (0.125f * 1.44269504f)   // fold log2(e)*scale into Q (exp2 softmax)

#define QKV_ELEMS ((size_t)BATCH * HEADS * SEQ * DHEAD)   // 2097152

typedef __bf16 bf16x8 __attribute__((ext_vector_type(8)));
typedef short  s16x4  __attribute__((ext_vector_type(4)));
typedef float  f32x4  __attribute__((ext_vector_type(4)));

#if __has_builtin(__builtin_amdgcn_exp2f)
#define EXP2F __builtin_amdgcn_exp2f
#else
#define EXP2F exp2f
#endif

__device__ __forceinline__ unsigned short bfbits(float f) {
  __bf16 h = (__bf16)f;
  return *(unsigned short*)&h;
}
__device__ __forceinline__ float bf2f(unsigned short u) {
  return __uint_as_float((unsigned)u << 16);
}
__device__ __forceinline__ unsigned cvtpk(float a, float b) {
  unsigned r;
  asm("v_cvt_pk_bf16_f32 %0, %1, %2" : "=v"(r) : "v"(a), "v"(b));
  return r;
}
__device__ __forceinline__ f32x4 mfma16(s16x4 a, s16x4 b, f32x4 c) {
#if __has_builtin(__builtin_amdgcn_mfma_f32_16x16x16bf16_1k)
  return __builtin_amdgcn_mfma_f32_16x16x16bf16_1k(a, b, c, 0, 0, 0);
#else
  f32x4 d;
  asm("v_mfma_f32_16x16x16_bf16 %0, %1, %2, %3" : "=v"(d) : "v"(a), "v"(b), "v"(c));
  return d;
#endif
}

// ---------------- fused prep: X->bf16 | W transposes | mask sniff ------------
__device__ __forceinline__ void transpose_tile_dev(
    const float* __restrict__ W, unsigned short* __restrict__ Wt,
    int K, int N, int n0, int k0, int t, float T[64][65]) {
  {
    int r0 = t >> 4, c4 = t & 15;
#pragma unroll
    for (int rr = 0; rr < 4; ++rr) {
      int r = r0 + rr * 16;
      float4 v = *(const float4*)(W + (size_t)(k0 + r) * N + n0 + c4 * 4);
      T[r][c4 * 4 + 0] = v.x; T[r][c4 * 4 + 1] = v.y;
      T[r][c4 * 4 + 2] = v.z; T[r][c4 * 4 + 3] = v.w;
    }
  }
  __syncthreads();
  {
    int n = t >> 2, kc = t & 3;
    union { unsigned short u[16]; int4 v[2]; } p;
#pragma unroll
    for (int i = 0; i < 16; ++i) p.u[i] = bfbits(T[kc * 16 + i][n]);
    int4* dst = (int4*)(Wt + (size_t)(n0 + n) * K + k0 + kc * 16);
    dst[0] = p.v[0]; dst[1] = p.v[1];
  }
}

__global__ __launch_bounds__(256) void prep_all(
    const float* __restrict__ X, const void* __restrict__ mraw,
    const float* __restrict__ Wqkv, const float* __restrict__ Wout,
    unsigned short* __restrict__ Xbf, float* __restrict__ maskf,
    unsigned short* __restrict__ Wtq, unsigned short* __restrict__ Wto,
    unsigned* __restrict__ kmaxn) {
  __shared__ float T[64][65];
  __shared__ int f_bf16, f_f32, f_gt1, f_oddnz;
  const int b = blockIdx.x;
  const int t = threadIdx.x;
  if (b < 1024) {                      // X fp32 -> bf16 (2M elems)
    size_t i = ((size_t)b * 256 + t) * 8;
    float4 a0 = *(const float4*)(X + i);
    float4 a1 = *(const float4*)(X + i + 4);
    union { unsigned short u[8]; int4 v; } pk;
    pk.u[0] = bfbits(a0.x); pk.u[1] = bfbits(a0.y);
    pk.u[2] = bfbits(a0.z); pk.u[3] = bfbits(a0.w);
    pk.u[4] = bfbits(a1.x); pk.u[5] = bfbits(a1.y);
    pk.u[6] = bfbits(a1.z); pk.u[7] = bfbits(a1.w);
    *(int4*)(Xbf + i) = pk.v;
  } else if (b < 1216) {               // Wqkv transpose: 24 n-tiles x 8 k-tiles
    int bb2 = b - 1024;
    transpose_tile_dev(Wqkv, Wtq, DIMM, NQKV, (bb2 % 24) * 64, (bb2 / 24) * 64, t, T);
  } else if (b < 1280) {               // Wout transpose: 8 x 8
    int bb2 = b - 1216;
    transpose_tile_dev(Wout, Wto, DIMM, DIMM, (bb2 & 7) * 64, (bb2 >> 3) * 64, t, T);
  } else {                             // mask sniff + normalize + kmaxn init
    if (t < 16) kmaxn[t] = 0u;
    if (t == 0) { f_bf16 = 0; f_f32 = 0; f_gt1 = 0; f_oddnz = 0; }
    __syncthreads();
    const unsigned int* w = (const unsigned int*)mraw;
    unsigned int v = w[t];             // first 1KB: safe for every candidate dtype
    if (v == 0x3f803f80u) f_bf16 = 1;
    if (v == 0x3f800000u) f_f32 = 1;
    if (v > 1u)           f_gt1 = 1;
    if ((t & 1) && v != 0u) f_oddnz = 1;
    __syncthreads();
    int mode;                          // 0=i32 1=u8 2=i64 3=f32 4=bf16
    if (f_bf16)       mode = 4;
    else if (f_f32)   mode = 3;
    else if (f_gt1)   mode = 1;
    else if (!f_oddnz) mode = 2;
    else              mode = 0;
    for (int i = t; i < BATCH * SEQ; i += 256) {
      bool keep;
      if (mode == 4)      keep = ((const unsigned short*)mraw)[i] != 0;
      else if (mode == 3) keep = ((const float*)mraw)[i] != 0.f;
      else if (mode == 1) keep = ((const unsigned char*)mraw)[i] != 0;
      else if (mode == 2) keep = w[2 * i] != 0u;
      else                keep = w[i] != 0u;
      maskf[i] = keep ? 1.f : 0.f;
    }
  }
}

// ---------------- qkv GEMM (MFMA) + fused per-(b,h) max|k| -------------------
__global__ __launch_bounds__(256) void gemm_qkv_mfma(
    const unsigned short* __restrict__ Xbf, const unsigned short* __restrict__ Wt,
    unsigned short* __restrict__ Qbf, unsigned short* __restrict__ Kbf,
    unsigned short* __restrict__ Vt, unsigned* __restrict__ kmaxn) {
  __shared__ __align__(16) unsigned char Al[128 * 128];
  __shared__ __align__(16) unsigned char Bl[64 * 128];
  const int tid = threadIdx.x;
  const int lane = tid & 63;
  const int w = tid >> 6;
  const int l15 = lane & 15, g = lane >> 4;
  const int wr = w >> 1, wc = w & 1;
  int bid = blockIdx.x;                    // 768 blocks, bijective XCD swizzle
  int lid = (bid & 7) * 96 + (bid >> 3);
  int by = lid / 24, bx = lid - by * 24;   // by 0..31, bx 0..23
  const int m0 = by * 128;

  f32x4 acc[4][2] = {};
  const int srow = tid >> 3, scg = tid & 7;
  const int rsw = (l15 & 7) << 4;

  for (int k0 = 0; k0 < DIMM; k0 += 64) {
    __syncthreads();
#pragma unroll
    for (int it = 0; it < 4; ++it) {
      int row = srow + it * 32;
      int sw = (row & 7) << 4;
      *(int4*)(Al + row * 128 + ((scg * 16) ^ sw)) =
          *(const int4*)(Xbf + (size_t)(m0 + row) * DIMM + k0 + scg * 8);
      if (it < 2) {
        *(int4*)(Bl + row * 128 + ((scg * 16) ^ sw)) =
            *(const int4*)(Wt + (size_t)(bx * 64 + row) * DIMM + k0 + scg * 8);
      }
    }
    __syncthreads();
#pragma unroll
    for (int ks = 0; ks < 2; ++ks) {
      bf16x8 af[4], bfr[2];
#pragma unroll
      for (int mi = 0; mi < 4; ++mi)
        af[mi] = *(const bf16x8*)(Al + (wr * 64 + mi * 16 + l15) * 128 +
                                  ((ks * 64 + g * 16) ^ rsw));
#pragma unroll
      for (int nj = 0; nj < 2; ++nj)
        bfr[nj] = *(const bf16x8*)(Bl + (wc * 32 + nj * 16 + l15) * 128 +
                                   ((ks * 64 + g * 16) ^ rsw));
#pragma unroll
      for (int mi = 0; mi < 4; ++mi)
#pragma unroll
        for (int nj = 0; nj < 2; ++nj)
          acc[mi][nj] = __builtin_amdgcn_mfma_f32_16x16x32_bf16(
              af[mi], bfr[nj], acc[mi][nj], 0, 0, 0);
    }
  }
  const int chunk = bx >> 3;               // 0=Q 1=K 2=V
  const int bb = m0 >> 11;
#pragma unroll
  for (int nj = 0; nj < 2; ++nj) {
    int col = (bx & 7) * 64 + wc * 32 + nj * 16 + l15;    // 0..511
    int hh = col >> 6, dd = col & 63;
#pragma unroll
    for (int mi = 0; mi < 4; ++mi) {
      int ii0 = (m0 & (SEQ - 1)) + wr * 64 + mi * 16 + g * 4;
      if (chunk == 2) {
        union { unsigned short u[4]; ushort4 v; } pk;
#pragma unroll
        for (int r = 0; r < 4; ++r) pk.u[r] = bfbits(acc[mi][nj][r]);
        *(ushort4*)(Vt + ((size_t)(bb * HEADS + hh) * DHEAD + dd) * SEQ + ii0) = pk.v;
      } else {
        unsigned short* dst = (chunk == 0) ? Qbf : Kbf;
        float sc = (chunk == 0) ? QSCALE_L2 : 1.f;
#pragma unroll
        for (int r = 0; r < 4; ++r)
          dst[((size_t)(bb * HEADS + hh) * SEQ + ii0 + r) * DHEAD + dd] =
              bfbits(acc[mi][nj][r] * sc);
      }
    }
  }
  if (chunk == 1) {                        // fused key-bound: max|k| per (b,h)
    float kab = 0.f;
#pragma unroll
    for (int nj = 0; nj < 2; ++nj)
#pragma unroll
      for (int mi = 0; mi < 4; ++mi)
#pragma unroll
        for (int r = 0; r < 4; ++r) kab = fmaxf(kab, fabsf(acc[mi][nj][r]));
#pragma unroll
    for (int d = 1; d < 64; d <<= 1) kab = fmaxf(kab, __shfl_xor(kab, d));
    if (lane == 0)                         // block covers exactly one head
      atomicMax(kmaxn + (bb * HEADS + (bx & 7)), __float_as_uint(kab * 1.005f));
  }
}

// ---------------- flash attention: dbuf LDS, 1 barrier/tile, in-reg P --------
// S^T = mfma(K,Q): lane (l15,g) holds P[q=l15][key=16j+4g+r]; exp2 with fixed
// bound B = ||q||*8*max|k| (uniform shift, cancels in normalization).
__global__ __launch_bounds__(256) void attn_split(const unsigned short* __restrict__ Qbf,
                                                  const unsigned short* __restrict__ Kbf,
                                                  const unsigned short* __restrict__ Vt,
                                                  const float* __restrict__ maskf,
                                                  const unsigned* __restrict__ kmaxn,
                                                  unsigned short* __restrict__ Po,
                                                  float* __restrict__ LSE) {
  __shared__ __align__(16) unsigned char Ks[16384];   // 2 x 8KB
  __shared__ __align__(16) unsigned char Vs[16384];

  const int tid = threadIdx.x;
  const int lane = tid & 63;
  const int w = tid >> 6;
  const int l15 = lane & 15, g = lane >> 4;

  int fid = blockIdx.x;
  int lid = (fid & 7) * 128 + (fid >> 3);  // bijective over 1024
  const int bh = lid >> 6;                 // 0..15
  const int rem = lid & 63;
  const int qb = rem >> 1;                 // 0..31
  const int half = rem & 1;
  const int bb = bh >> 3;

  const unsigned short* Qg = Qbf + ((size_t)bh * SEQ + qb * 64) * DHEAD;
  const unsigned short* Kg = Kbf + (size_t)bh * SEQ * DHEAD;
  const unsigned short* Vg = Vt  + (size_t)bh * DHEAD * SEQ;
  const float* mrow = maskf + bb * SEQ;

  bf16x8 qf0, qf1;
  {
    const unsigned char* qrow = (const unsigned char*)(Qg + (size_t)(w * 16 + l15) * DHEAD);
    qf0 = *(const bf16x8*)(qrow + g * 16);
    qf1 = *(const bf16x8*)(qrow + 64 + g * 16);
  }
  float Bx, Bnat;
  {
    float qn2 = 0.f;
#pragma unroll
    for (int i = 0; i < 8; ++i) {
      float a = (float)qf0[i]; qn2 += a * a;
      float b = (float)qf1[i]; qn2 += b * b;
    }
    qn2 += __shfl_xor(qn2, 16);
    qn2 += __shfl_xor(qn2, 32);
    const float kabs = __uint_as_float(kmaxn[bh]);
    Bx = sqrtf(qn2) * 8.f * kabs;          // log2-units (Q pre-scaled)
    Bnat = Bx * 0.69314718f;
  }

  f32x4 o[4] = {};
  float lsum = 0.f;

  const int sm = tid >> 2;
  const int sc = (tid & 3) * 32;
  const int ssw = (sm & 7) << 4;
  const int rsw = (l15 & 7) << 4;
  const int kt0 = half * 16;

  int4 rk0, rk1, rv0, rv1;
  {
    const unsigned char* ksrc =
        (const unsigned char*)(Kg + (size_t)kt0 * 64 * DHEAD) + sm * 128 + sc;
    const unsigned char* vsrc =
        (const unsigned char*)(Vg + (size_t)sm * SEQ + kt0 * 64) + sc;
    rk0 = *(const int4*)(ksrc); rk1 = *(const int4*)(ksrc + 16);
    rv0 = *(const int4*)(vsrc); rv1 = *(const int4*)(vsrc + 16);
  }
  *(int4*)(Ks + sm * 128 + ((sc)      ^ ssw)) = rk0;
  *(int4*)(Ks + sm * 128 + ((sc + 16) ^ ssw)) = rk1;
  *(int4*)(Vs + sm * 128 + ((sc)      ^ ssw)) = rv0;
  *(int4*)(Vs + sm * 128 + ((sc + 16) ^ ssw)) = rv1;
  __syncthreads();

  for (int t = 0; t < 16; ++t) {
    const int kt = kt0 + t;
    const int co = (t & 1) << 13;          // current buffer byte offset
    const int no = co ^ 8192;              // next buffer
    // mask for current tile (uniform across l15 -> L1 broadcast)
    float4 km[4];
#pragma unroll
    for (int j = 0; j < 4; ++j) km[j] = *(const float4*)(mrow + kt * 64 + 16 * j + 4 * g);
    // T14: issue next tile's global loads; complete under this tile's compute
    if (t < 15) {
      const unsigned char* ksrc =
          (const unsigned char*)(Kg + (size_t)(kt + 1) * 64 * DHEAD) + sm * 128 + sc;
      const unsigned char* vsrc =
          (const unsigned char*)(Vg + (size_t)sm * SEQ + (kt + 1) * 64) + sc;
      rk0 = *(const int4*)(ksrc); rk1 = *(const int4*)(ksrc + 16);
      rv0 = *(const int4*)(vsrc); rv1 = *(const int4*)(vsrc + 16);
    }

    // S^T = K · Q^T
    f32x4 s[4];
#pragma unroll
    for (int j = 0; j < 4; ++j) {
      const unsigned char* krow = Ks + co + (16 * j + l15) * 128;
      bf16x8 kf0 = *(const bf16x8*)(krow + ((g * 16)      ^ rsw));
      bf16x8 kf1 = *(const bf16x8*)(krow + ((64 + g * 16) ^ rsw));
      f32x4 z = (f32x4){0.f, 0.f, 0.f, 0.f};
      z = __builtin_amdgcn_mfma_f32_16x16x32_bf16(kf0, qf0, z, 0, 0, 0);
      z = __builtin_amdgcn_mfma_f32_16x16x32_bf16(kf1, qf1, z, 0, 0, 0);
      s[j] = z;
    }

    // p = exp2(s - Bx) * km ; pack to bf16x4 A-fragments in-register
    s16x4 pa[4];
#pragma unroll
    for (int j = 0; j < 4; ++j) {
      float p0 = EXP2F(s[j][0] - Bx) * km[j].x;
      float p1 = EXP2F(s[j][1] - Bx) * km[j].y;
      float p2 = EXP2F(s[j][2] - Bx) * km[j].z;
      float p3 = EXP2F(s[j][3] - Bx) * km[j].w;
      lsum += (p0 + p1) + (p2 + p3);
      union { uint2 u; s16x4 v; } pk;
      pk.u.x = cvtpk(p0, p1);
      pk.u.y = cvtpk(p2, p3);
      pa[j] = pk.v;
    }

    // O += P @ V via 16x16x16
#pragma unroll
    for (int dj = 0; dj < 4; ++dj) {
      const unsigned char* vrow = Vs + co + (16 * dj + l15) * 128;
#pragma unroll
      for (int j = 0; j < 4; ++j) {
        s16x4 vb = *(const s16x4*)(vrow + ((32 * j + 8 * g) ^ rsw));
        o[dj] = mfma16(pa[j], vb, o[dj]);
      }
    }

    if (t < 15) {                          // stage next tile into other buffer
      *(int4*)(Ks + no + sm * 128 + ((sc)      ^ ssw)) = rk0;
      *(int4*)(Ks + no + sm * 128 + ((sc + 16) ^ ssw)) = rk1;
      *(int4*)(Vs + no + sm * 128 + ((sc)      ^ ssw)) = rv0;
      *(int4*)(Vs + no + sm * 128 + ((sc + 16) ^ ssw)) = rv1;
      __syncthreads();                     // single barrier per tile
    }
  }

  // epilogue: row sums across g-lanes, redistribute, write partial O + LSE
  lsum += __shfl_xor(lsum, 16);
  lsum += __shfl_xor(lsum, 32);
#pragma unroll
  for (int r = 0; r < 4; ++r) {
    float lr = __shfl(lsum, 4 * g + r);    // sum for q-row 4g+r
    float inv = (lr > 0.f) ? 1.f / lr : 0.f;
    int row = qb * 64 + w * 16 + 4 * g + r;
    size_t base = half * QKV_ELEMS + ((size_t)bh * SEQ + row) * DHEAD + l15;
    Po[base]      = bfbits(o[0][r] * inv);
    Po[base + 16] = bfbits(o[1][r] * inv);
    Po[base + 32] = bfbits(o[2][r] * inv);
    Po[base + 48] = bfbits(o[3][r] * inv);
  }
  if (g == 0) {
    int row = qb * 64 + w * 16 + l15;
    LSE[half * (BATCH * HEADS * SEQ) + bh * SEQ + row] =
        (lsum > 0.f) ? Bnat + __logf(lsum) : -3.0e38f;
  }
}

// ---------------- combine halves + depthwise conv residual -> Obf bf16 -------
__global__ __launch_bounds__(256) void combine_conv(
    const unsigned short* __restrict__ Po, const float* __restrict__ LSE,
    const unsigned short* __restrict__ Vt, const float* __restrict__ cw,
    unsigned short* __restrict__ Obf) {
  __shared__ float T[96][68];
  __shared__ float cwl[33];
  const int tid = threadIdx.x;
  const int bid = blockIdx.x;              // 512 = 16 bh x 32 n-chunks
  const int bh = bid >> 5;
  const int n0 = (bid & 31) * 64;
  const int hh = bh & 7;
  if (tid < 33) cwl[tid] = cw[hh * 33 + tid];
  for (int idx = tid; idx < 64 * 24; idx += 256) {
    int d = idx / 24, c4 = idx - (idx / 24) * 24;
    int nbase = n0 - 16 + c4 * 4;
    const unsigned short* src = Vt + ((size_t)bh * DHEAD + d) * SEQ;
#pragma unroll
    for (int q = 0; q < 4; ++q) {
      int n = nbase + q;
      T[c4 * 4 + q][d] = (n >= 0 && n < SEQ) ? bf2f(src[n]) : 0.f;
    }
  }
  __syncthreads();
#pragma unroll
  for (int p = 0; p < 4; ++p) {
    int n = (tid >> 4) + p * 16;           // 0..63
    int d4 = tid & 15;
    int row = bh * SEQ + n0 + n;
    float ls0 = LSE[row], ls1 = LSE[BATCH * HEADS * SEQ + row];
    float m = fmaxf(ls0, ls1);
    float w0 = __expf(ls0 - m), w1 = __expf(ls1 - m);
    float inv = 1.f / (w0 + w1);
    w0 *= inv; w1 *= inv;
    const unsigned short* p0 = Po + (size_t)row * DHEAD + d4 * 4;
    const unsigned short* p1 = p0 + QKV_ELEMS;
    ushort4 a = *(const ushort4*)p0, b = *(const ushort4*)p1;
    float o0 = w0 * bf2f(a.x) + w1 * bf2f(b.x);
    float o1 = w0 * bf2f(a.y) + w1 * bf2f(b.y);
    float o2 = w0 * bf2f(a.z) + w1 * bf2f(b.z);
    float o3 = w0 * bf2f(a.w) + w1 * bf2f(b.w);
#pragma unroll
    for (int t = 0; t < 33; ++t) {
      float wv = cwl[t];
      float4 tv = *(const float4*)&T[n + t][d4 * 4];
      o0 += wv * tv.x; o1 += wv * tv.y; o2 += wv * tv.z; o3 += wv * tv.w;
    }
    union { unsigned short u[4]; ushort4 v; } pk;
    pk.u[0] = bfbits(o0); pk.u[1] = bfbits(o1);
    pk.u[2] = bfbits(o2); pk.u[3] = bfbits(o3);
    *(ushort4*)(Obf + (size_t)row * DHEAD + d4 * 4) = pk.v;
  }
}

// ---------------- out GEMM (MFMA): Obf bf16 gather-A, 64x64 tiles ------------
__global__ __launch_bounds__(256) void gemm_out_mfma(
    const unsigned short* __restrict__ Obf, const unsigned short* __restrict__ Wt,
    const float* __restrict__ bias, const float* __restrict__ maskf,
    float* __restrict__ out) {
  __shared__ __align__(16) unsigned char Al[64 * 128];
  __shared__ __align__(16) unsigned char Bl[64 * 128];
  const int tid = threadIdx.x;
  const int lane = tid & 63;
  const int w = tid >> 6;
  const int l15 = lane & 15, g = lane >> 4;
  const int wr = w >> 1, wc = w & 1;
  int bid = blockIdx.x;                    // 512 blocks
  int lid = (bid & 7) * 64 + (bid >> 3);
  int by = lid >> 3, bx = lid & 7;         // by 0..63, bx 0..7
  const int m0 = by * 64, n0 = bx * 64;
  const int bb = m0 >> 11;
  const int ii0 = m0 & (SEQ - 1);

  f32x4 acc[2][2] = {};
  const int srow = tid >> 3, scg = tid & 7;
  const int rsw = (l15 & 7) << 4;

  for (int k0 = 0; k0 < DIMM; k0 += 64) {
    const int hh = k0 >> 6;
    __syncthreads();
#pragma unroll
    for (int it = 0; it < 2; ++it) {
      int row = srow + it * 32;
      int sw = (row & 7) << 4;
      *(int4*)(Al + row * 128 + ((scg * 16) ^ sw)) =
          *(const int4*)(Obf + ((size_t)(bb * HEADS + hh) * SEQ + ii0 + row) * DHEAD + scg * 8);
      *(int4*)(Bl + row * 128 + ((scg * 16) ^ sw)) =
          *(const int4*)(Wt + (size_t)(n0 + row) * DIMM + k0 + scg * 8);
    }
    __syncthreads();
#pragma unroll
    for (int ks = 0; ks < 2; ++ks) {
      bf16x8 af[2], bfr[2];
#pragma unroll
      for (int mi = 0; mi < 2; ++mi)
        af[mi] = *(const bf16x8*)(Al + (wr * 32 + mi * 16 + l15) * 128 +
                                  ((ks * 64 + g * 16) ^ rsw));
#pragma unroll
      for (int nj = 0; nj < 2; ++nj)
        bfr[nj] = *(const bf16x8*)(Bl + (wc * 32 + nj * 16 + l15) * 128 +
                                   ((ks * 64 + g * 16) ^ rsw));
#pragma unroll
      for (int mi = 0; mi < 2; ++mi)
#pragma unroll
        for (int nj = 0; nj < 2; ++nj)
          acc[mi][nj] = __builtin_amdgcn_mfma_f32_16x16x32_bf16(
              af[mi], bfr[nj], acc[mi][nj], 0, 0, 0);
    }
  }
#pragma unroll
  for (int nj = 0; nj < 2; ++nj) {
    int col = n0 + wc * 32 + nj * 16 + l15;
    float bcol = bias[col];
#pragma unroll
    for (int mi = 0; mi < 2; ++mi) {
#pragma unroll
      for (int r = 0; r < 4; ++r) {
        int m = m0 + wr * 32 + mi * 16 + g * 4 + r;
        out[(size_t)m * DIMM + col] = (acc[mi][nj][r] + bcol) * maskf[m];
      }
    }
  }
}

extern "C" void kernel_launch(void* const* d_in, const int* in_sizes, int n_in,
                              void* d_out, int out_size, void* d_ws, size_t ws_size,
                              hipStream_t stream) {
  const float* x     = (const float*)d_in[0];
  const void*  mask  = d_in[1];
  const float* Wqkv  = (const float*)d_in[2];
  const float* Wout  = (const float*)d_in[3];
  const float* bout  = (const float*)d_in[4];
  const float* convw = (const float*)d_in[5];
  float* out = (float*)d_out;

  float* maskf = (float*)d_ws;
  unsigned* kmaxn = (unsigned*)(maskf + 4096);           // 16 used, pad 64
  unsigned short* Qbf = (unsigned short*)(kmaxn + 64);
  unsigned short* Kbf = Qbf + QKV_ELEMS;
  unsigned short* Vt  = Kbf + QKV_ELEMS;
  unsigned short* Po  = Vt + QKV_ELEMS;                  // 2 halves
  float* LSE          = (float*)(Po + 2 * QKV_ELEMS);    // 2 * 32768
  unsigned short* Obf = (unsigned short*)(LSE + 2 * BATCH * HEADS * SEQ);
  unsigned short* Wtq = Obf + QKV_ELEMS;                 // 1536*512
  unsigned short* Wto = Wtq + (size_t)NQKV * DIMM;       // 512*512
  unsigned short* Xbf = Wto + (size_t)DIMM * DIMM;       // 4096*512

  prep_all<<<1281, 256, 0, stream>>>(x, mask, Wqkv, Wout, Xbf, maskf, Wtq, Wto, kmaxn);
  gemm_qkv_mfma<<<768, 256, 0, stream>>>(Xbf, Wtq, Qbf, Kbf, Vt, kmaxn);
  attn_split<<<1024, 256, 0, stream>>>(Qbf, Kbf, Vt, maskf, kmaxn, Po, LSE);
  combine_conv<<<512, 256, 0, stream>>>(Po, LSE, Vt, convw, Obf);
  gemm_out_mfma<<<512, 256, 0, stream>>>(Obf, Wto, bout, maskf, out);
}

// Round 8
// 99.549 us; speedup vs baseline: 7.4908x; 1.0089x over previous
//
#include <hip/hip_runtime.h>
#include <float.h>

#define BATCH 2
#define SEQ   2048
#define HEADS 8
#define DHEAD 64
#define DIMM  512
#define NQKV  1536
#define QSCALE_L2 (0.125f * 1.44269504f)   // fold log2(e)*scale into Q (exp2 softmax)

#define QKV_ELEMS ((size_t)BATCH * HEADS * SEQ * DHEAD)   // 2097152
#define BHS (BATCH * HEADS * SEQ)                          // 32768
#define NSPLIT 4

typedef __bf16 bf16x8 __attribute__((ext_vector_type(8)));
typedef short  s16x4  __attribute__((ext_vector_type(4)));
typedef float  f32x4  __attribute__((ext_vector_type(4)));

#if __has_builtin(__builtin_amdgcn_exp2f)
#define EXP2F __builtin_amdgcn_exp2f
#else
#define EXP2F exp2f
#endif

__device__ __forceinline__ unsigned short bfbits(float f) {
  __bf16 h = (__bf16)f;
  return *(unsigned short*)&h;
}
__device__ __forceinline__ float bf2f(unsigned short u) {
  return __uint_as_float((unsigned)u << 16);
}
__device__ __forceinline__ unsigned cvtpk(float a, float b) {
  unsigned r;
  asm("v_cvt_pk_bf16_f32 %0, %1, %2" : "=v"(r) : "v"(a), "v"(b));
  return r;
}
__device__ __forceinline__ f32x4 mfma16(s16x4 a, s16x4 b, f32x4 c) {
#if __has_builtin(__builtin_amdgcn_mfma_f32_16x16x16bf16_1k)
  return __builtin_amdgcn_mfma_f32_16x16x16bf16_1k(a, b, c, 0, 0, 0);
#else
  f32x4 d;
  asm("v_mfma_f32_16x16x16_bf16 %0, %1, %2, %3" : "=v"(d) : "v"(a), "v"(b), "v"(c));
  return d;
#endif
}

// ---------------- fused prep: X->bf16 | W transposes | mask sniff ------------
__device__ __forceinline__ void transpose_tile_dev(
    const float* __restrict__ W, unsigned short* __restrict__ Wt,
    int K, int N, int n0, int k0, int t, float T[64][65]) {
  {
    int r0 = t >> 4, c4 = t & 15;
#pragma unroll
    for (int rr = 0; rr < 4; ++rr) {
      int r = r0 + rr * 16;
      float4 v = *(const float4*)(W + (size_t)(k0 + r) * N + n0 + c4 * 4);
      T[r][c4 * 4 + 0] = v.x; T[r][c4 * 4 + 1] = v.y;
      T[r][c4 * 4 + 2] = v.z; T[r][c4 * 4 + 3] = v.w;
    }
  }
  __syncthreads();
  {
    int n = t >> 2, kc = t & 3;
    union { unsigned short u[16]; int4 v[2]; } p;
#pragma unroll
    for (int i = 0; i < 16; ++i) p.u[i] = bfbits(T[kc * 16 + i][n]);
    int4* dst = (int4*)(Wt + (size_t)(n0 + n) * K + k0 + kc * 16);
    dst[0] = p.v[0]; dst[1] = p.v[1];
  }
}

__global__ __launch_bounds__(256) void prep_all(
    const float* __restrict__ X, const void* __restrict__ mraw,
    const float* __restrict__ Wqkv, const float* __restrict__ Wout,
    unsigned short* __restrict__ Xbf, float* __restrict__ maskf,
    unsigned short* __restrict__ Wtq, unsigned short* __restrict__ Wto,
    unsigned* __restrict__ kmaxn) {
  __shared__ float T[64][65];
  __shared__ int f_bf16, f_f32, f_gt1, f_oddnz;
  const int b = blockIdx.x;
  const int t = threadIdx.x;
  if (b < 1024) {                      // X fp32 -> bf16 (2M elems)
    size_t i = ((size_t)b * 256 + t) * 8;
    float4 a0 = *(const float4*)(X + i);
    float4 a1 = *(const float4*)(X + i + 4);
    union { unsigned short u[8]; int4 v; } pk;
    pk.u[0] = bfbits(a0.x); pk.u[1] = bfbits(a0.y);
    pk.u[2] = bfbits(a0.z); pk.u[3] = bfbits(a0.w);
    pk.u[4] = bfbits(a1.x); pk.u[5] = bfbits(a1.y);
    pk.u[6] = bfbits(a1.z); pk.u[7] = bfbits(a1.w);
    *(int4*)(Xbf + i) = pk.v;
  } else if (b < 1216) {               // Wqkv transpose: 24 n-tiles x 8 k-tiles
    int bb2 = b - 1024;
    transpose_tile_dev(Wqkv, Wtq, DIMM, NQKV, (bb2 % 24) * 64, (bb2 / 24) * 64, t, T);
  } else if (b < 1280) {               // Wout transpose: 8 x 8
    int bb2 = b - 1216;
    transpose_tile_dev(Wout, Wto, DIMM, DIMM, (bb2 & 7) * 64, (bb2 >> 3) * 64, t, T);
  } else {                             // mask sniff + normalize + kmaxn init
    if (t < 16) kmaxn[t] = 0u;
    if (t == 0) { f_bf16 = 0; f_f32 = 0; f_gt1 = 0; f_oddnz = 0; }
    __syncthreads();
    const unsigned int* w = (const unsigned int*)mraw;
    unsigned int v = w[t];             // first 1KB: safe for every candidate dtype
    if (v == 0x3f803f80u) f_bf16 = 1;
    if (v == 0x3f800000u) f_f32 = 1;
    if (v > 1u)           f_gt1 = 1;
    if ((t & 1) && v != 0u) f_oddnz = 1;
    __syncthreads();
    int mode;                          // 0=i32 1=u8 2=i64 3=f32 4=bf16
    if (f_bf16)       mode = 4;
    else if (f_f32)   mode = 3;
    else if (f_gt1)   mode = 1;
    else if (!f_oddnz) mode = 2;
    else              mode = 0;
    for (int i = t; i < BATCH * SEQ; i += 256) {
      bool keep;
      if (mode == 4)      keep = ((const unsigned short*)mraw)[i] != 0;
      else if (mode == 3) keep = ((const float*)mraw)[i] != 0.f;
      else if (mode == 1) keep = ((const unsigned char*)mraw)[i] != 0;
      else if (mode == 2) keep = w[2 * i] != 0u;
      else                keep = w[i] != 0u;
      maskf[i] = keep ? 1.f : 0.f;
    }
  }
}

// ---------------- qkv GEMM (MFMA) + fused per-(b,h) max|k| -------------------
__global__ __launch_bounds__(256) void gemm_qkv_mfma(
    const unsigned short* __restrict__ Xbf, const unsigned short* __restrict__ Wt,
    unsigned short* __restrict__ Qbf, unsigned short* __restrict__ Kbf,
    unsigned short* __restrict__ Vt, unsigned* __restrict__ kmaxn) {
  __shared__ __align__(16) unsigned char Al[128 * 128];
  __shared__ __align__(16) unsigned char Bl[64 * 128];
  const int tid = threadIdx.x;
  const int lane = tid & 63;
  const int w = tid >> 6;
  const int l15 = lane & 15, g = lane >> 4;
  const int wr = w >> 1, wc = w & 1;
  int bid = blockIdx.x;                    // 768 blocks, bijective XCD swizzle
  int lid = (bid & 7) * 96 + (bid >> 3);
  int by = lid / 24, bx = lid - by * 24;   // by 0..31, bx 0..23
  const int m0 = by * 128;

  f32x4 acc[4][2] = {};
  const int srow = tid >> 3, scg = tid & 7;
  const int rsw = (l15 & 7) << 4;

  for (int k0 = 0; k0 < DIMM; k0 += 64) {
    __syncthreads();
#pragma unroll
    for (int it = 0; it < 4; ++it) {
      int row = srow + it * 32;
      int sw = (row & 7) << 4;
      *(int4*)(Al + row * 128 + ((scg * 16) ^ sw)) =
          *(const int4*)(Xbf + (size_t)(m0 + row) * DIMM + k0 + scg * 8);
      if (it < 2) {
        *(int4*)(Bl + row * 128 + ((scg * 16) ^ sw)) =
            *(const int4*)(Wt + (size_t)(bx * 64 + row) * DIMM + k0 + scg * 8);
      }
    }
    __syncthreads();
#pragma unroll
    for (int ks = 0; ks < 2; ++ks) {
      bf16x8 af[4], bfr[2];
#pragma unroll
      for (int mi = 0; mi < 4; ++mi)
        af[mi] = *(const bf16x8*)(Al + (wr * 64 + mi * 16 + l15) * 128 +
                                  ((ks * 64 + g * 16) ^ rsw));
#pragma unroll
      for (int nj = 0; nj < 2; ++nj)
        bfr[nj] = *(const bf16x8*)(Bl + (wc * 32 + nj * 16 + l15) * 128 +
                                   ((ks * 64 + g * 16) ^ rsw));
#pragma unroll
      for (int mi = 0; mi < 4; ++mi)
#pragma unroll
        for (int nj = 0; nj < 2; ++nj)
          acc[mi][nj] = __builtin_amdgcn_mfma_f32_16x16x32_bf16(
              af[mi], bfr[nj], acc[mi][nj], 0, 0, 0);
    }
  }
  const int chunk = bx >> 3;               // 0=Q 1=K 2=V
  const int bb = m0 >> 11;
#pragma unroll
  for (int nj = 0; nj < 2; ++nj) {
    int col = (bx & 7) * 64 + wc * 32 + nj * 16 + l15;    // 0..511
    int hh = col >> 6, dd = col & 63;
#pragma unroll
    for (int mi = 0; mi < 4; ++mi) {
      int ii0 = (m0 & (SEQ - 1)) + wr * 64 + mi * 16 + g * 4;
      if (chunk == 2) {
        union { unsigned short u[4]; ushort4 v; } pk;
#pragma unroll
        for (int r = 0; r < 4; ++r) pk.u[r] = bfbits(acc[mi][nj][r]);
        *(ushort4*)(Vt + ((size_t)(bb * HEADS + hh) * DHEAD + dd) * SEQ + ii0) = pk.v;
      } else {
        unsigned short* dst = (chunk == 0) ? Qbf : Kbf;
        float sc = (chunk == 0) ? QSCALE_L2 : 1.f;
#pragma unroll
        for (int r = 0; r < 4; ++r)
          dst[((size_t)(bb * HEADS + hh) * SEQ + ii0 + r) * DHEAD + dd] =
              bfbits(acc[mi][nj][r] * sc);
      }
    }
  }
  if (chunk == 1) {                        // fused key-bound: max|k| per (b,h)
    float kab = 0.f;
#pragma unroll
    for (int nj = 0; nj < 2; ++nj)
#pragma unroll
      for (int mi = 0; mi < 4; ++mi)
#pragma unroll
        for (int r = 0; r < 4; ++r) kab = fmaxf(kab, fabsf(acc[mi][nj][r]));
#pragma unroll
    for (int d = 1; d < 64; d <<= 1) kab = fmaxf(kab, __shfl_xor(kab, d));
    if (lane == 0)                         // block covers exactly one head
      atomicMax(kmaxn + (bb * HEADS + (bx & 7)), __float_as_uint(kab * 1.005f));
  }
}

// ---------------- flash attention: split-KV x4, dbuf, in-reg P ---------------
// S^T = mfma(K,Q): lane (l15,g) holds P[q=l15][key=16j+4g+r]; exp2 with fixed
// bound B = ||q||*8*max|k|. V layout: half-swapped store so ds_read_b64
// fragments are bank-conflict-free (byte ^= (row&7)<<4 | (row>>3&1)<<3).
__global__ __launch_bounds__(256) void attn_split(const unsigned short* __restrict__ Qbf,
                                                  const unsigned short* __restrict__ Kbf,
                                                  const unsigned short* __restrict__ Vt,
                                                  const float* __restrict__ maskf,
                                                  const unsigned* __restrict__ kmaxn,
                                                  unsigned short* __restrict__ Po,
                                                  float* __restrict__ LSE) {
  __shared__ __align__(16) unsigned char Ks[16384];   // 2 x 8KB
  __shared__ __align__(16) unsigned char Vs[16384];

  const int tid = threadIdx.x;
  const int lane = tid & 63;
  const int w = tid >> 6;
  const int l15 = lane & 15, g = lane >> 4;

  int fid = blockIdx.x;
  int lid = (fid & 7) * 256 + (fid >> 3);  // bijective over 2048
  const int bh = lid >> 7;                 // 0..15
  const int rem = lid & 127;
  const int qb = rem >> 2;                 // 0..31
  const int quarter = rem & 3;
  const int bb = bh >> 3;

  const unsigned short* Qg = Qbf + ((size_t)bh * SEQ + qb * 64) * DHEAD;
  const unsigned short* Kg = Kbf + (size_t)bh * SEQ * DHEAD;
  const unsigned short* Vg = Vt  + (size_t)bh * DHEAD * SEQ;
  const float* mrow = maskf + bb * SEQ;

  bf16x8 qf0, qf1;
  {
    const unsigned char* qrow = (const unsigned char*)(Qg + (size_t)(w * 16 + l15) * DHEAD);
    qf0 = *(const bf16x8*)(qrow + g * 16);
    qf1 = *(const bf16x8*)(qrow + 64 + g * 16);
  }
  float Bx, Bnat;
  {
    float qn2 = 0.f;
#pragma unroll
    for (int i = 0; i < 8; ++i) {
      float a = (float)qf0[i]; qn2 += a * a;
      float b = (float)qf1[i]; qn2 += b * b;
    }
    qn2 += __shfl_xor(qn2, 16);
    qn2 += __shfl_xor(qn2, 32);
    const float kabs = __uint_as_float(kmaxn[bh]);
    Bx = sqrtf(qn2) * 8.f * kabs;          // log2-units (Q pre-scaled)
    Bnat = Bx * 0.69314718f;
  }

  f32x4 o[4] = {};
  float lsum = 0.f;

  const int sm = tid >> 2;
  const int sc = (tid & 3) * 32;
  const int ssw = (sm & 7) << 4;
  const int vswap = (sm >> 3) & 1;         // half-swap flag for V stores
  const int rsw = (l15 & 7) << 4;
  const int vsw = rsw | (((l15 >> 3) & 1) << 3);   // V-read swizzle (8B gran)
  const int kt0 = quarter * 8;

  int4 rk0, rk1, rv0, rv1;
  {
    const unsigned char* ksrc =
        (const unsigned char*)(Kg + (size_t)kt0 * 64 * DHEAD) + sm * 128 + sc;
    const unsigned char* vsrc =
        (const unsigned char*)(Vg + (size_t)sm * SEQ + kt0 * 64) + sc;
    rk0 = *(const int4*)(ksrc); rk1 = *(const int4*)(ksrc + 16);
    rv0 = *(const int4*)(vsrc); rv1 = *(const int4*)(vsrc + 16);
  }
  {
    *(int4*)(Ks + sm * 128 + ((sc)      ^ ssw)) = rk0;
    *(int4*)(Ks + sm * 128 + ((sc + 16) ^ ssw)) = rk1;
    int4 sv0 = vswap ? (int4){rv0.z, rv0.w, rv0.x, rv0.y} : rv0;
    int4 sv1 = vswap ? (int4){rv1.z, rv1.w, rv1.x, rv1.y} : rv1;
    *(int4*)(Vs + sm * 128 + ((sc)      ^ ssw)) = sv0;
    *(int4*)(Vs + sm * 128 + ((sc + 16) ^ ssw)) = sv1;
  }
  __syncthreads();

  for (int t = 0; t < 8; ++t) {
    const int kt = kt0 + t;
    const int co = (t & 1) << 13;          // current buffer byte offset
    const int no = co ^ 8192;              // next buffer
    float4 km[4];
#pragma unroll
    for (int j = 0; j < 4; ++j) km[j] = *(const float4*)(mrow + kt * 64 + 16 * j + 4 * g);
    if (t < 7) {                           // T14: issue next tile's loads now
      const unsigned char* ksrc =
          (const unsigned char*)(Kg + (size_t)(kt + 1) * 64 * DHEAD) + sm * 128 + sc;
      const unsigned char* vsrc =
          (const unsigned char*)(Vg + (size_t)sm * SEQ + (kt + 1) * 64) + sc;
      rk0 = *(const int4*)(ksrc); rk1 = *(const int4*)(ksrc + 16);
      rv0 = *(const int4*)(vsrc); rv1 = *(const int4*)(vsrc + 16);
    }

    // S^T = K · Q^T
    f32x4 s[4];
#pragma unroll
    for (int j = 0; j < 4; ++j) {
      const unsigned char* krow = Ks + co + (16 * j + l15) * 128;
      bf16x8 kf0 = *(const bf16x8*)(krow + ((g * 16)      ^ rsw));
      bf16x8 kf1 = *(const bf16x8*)(krow + ((64 + g * 16) ^ rsw));
      f32x4 z = (f32x4){0.f, 0.f, 0.f, 0.f};
      z = __builtin_amdgcn_mfma_f32_16x16x32_bf16(kf0, qf0, z, 0, 0, 0);
      z = __builtin_amdgcn_mfma_f32_16x16x32_bf16(kf1, qf1, z, 0, 0, 0);
      s[j] = z;
    }

    // p = exp2(s - Bx) * km ; pack to bf16x4 A-fragments in-register
    s16x4 pa[4];
#pragma unroll
    for (int j = 0; j < 4; ++j) {
      float p0 = EXP2F(s[j][0] - Bx) * km[j].x;
      float p1 = EXP2F(s[j][1] - Bx) * km[j].y;
      float p2 = EXP2F(s[j][2] - Bx) * km[j].z;
      float p3 = EXP2F(s[j][3] - Bx) * km[j].w;
      lsum += (p0 + p1) + (p2 + p3);
      union { uint2 u; s16x4 v; } pk;
      pk.u.x = cvtpk(p0, p1);
      pk.u.y = cvtpk(p2, p3);
      pa[j] = pk.v;
    }

    // O += P @ V via 16x16x16 (conflict-free b64 reads)
#pragma unroll
    for (int dj = 0; dj < 4; ++dj) {
      const unsigned char* vrow = Vs + co + (16 * dj + l15) * 128;
#pragma unroll
      for (int j = 0; j < 4; ++j) {
        s16x4 vb = *(const s16x4*)(vrow + ((32 * j + 8 * g) ^ vsw));
        o[dj] = mfma16(pa[j], vb, o[dj]);
      }
    }

    if (t < 7) {                           // stage next tile into other buffer
      *(int4*)(Ks + no + sm * 128 + ((sc)      ^ ssw)) = rk0;
      *(int4*)(Ks + no + sm * 128 + ((sc + 16) ^ ssw)) = rk1;
      int4 sv0 = vswap ? (int4){rv0.z, rv0.w, rv0.x, rv0.y} : rv0;
      int4 sv1 = vswap ? (int4){rv1.z, rv1.w, rv1.x, rv1.y} : rv1;
      *(int4*)(Vs + no + sm * 128 + ((sc)      ^ ssw)) = sv0;
      *(int4*)(Vs + no + sm * 128 + ((sc + 16) ^ ssw)) = sv1;
      __syncthreads();                     // single barrier per tile
    }
  }

  // epilogue: row sums across g-lanes, redistribute, write partial O + LSE
  lsum += __shfl_xor(lsum, 16);
  lsum += __shfl_xor(lsum, 32);
#pragma unroll
  for (int r = 0; r < 4; ++r) {
    float lr = __shfl(lsum, 4 * g + r);    // sum for q-row 4g+r
    float inv = (lr > 0.f) ? 1.f / lr : 0.f;
    int row = qb * 64 + w * 16 + 4 * g + r;
    size_t base = (size_t)quarter * QKV_ELEMS + ((size_t)bh * SEQ + row) * DHEAD + l15;
    Po[base]      = bfbits(o[0][r] * inv);
    Po[base + 16] = bfbits(o[1][r] * inv);
    Po[base + 32] = bfbits(o[2][r] * inv);
    Po[base + 48] = bfbits(o[3][r] * inv);
  }
  if (g == 0) {
    int row = qb * 64 + w * 16 + l15;
    LSE[quarter * BHS + bh * SEQ + row] =
        (lsum > 0.f) ? Bnat + __logf(lsum) : -3.0e38f;
  }
}

// ---------------- combine 4 partials + depthwise conv residual -> Obf bf16 ---
__global__ __launch_bounds__(256) void combine_conv(
    const unsigned short* __restrict__ Po, const float* __restrict__ LSE,
    const unsigned short* __restrict__ Vt, const float* __restrict__ cw,
    unsigned short* __restrict__ Obf) {
  __shared__ float T[96][68];
  __shared__ float cwl[33];
  const int tid = threadIdx.x;
  const int bid = blockIdx.x;              // 512 = 16 bh x 32 n-chunks
  const int bh = bid >> 5;
  const int n0 = (bid & 31) * 64;
  const int hh = bh & 7;
  if (tid < 33) cwl[tid] = cw[hh * 33 + tid];
  for (int idx = tid; idx < 64 * 24; idx += 256) {
    int d = idx / 24, c4 = idx - (idx / 24) * 24;
    int nbase = n0 - 16 + c4 * 4;
    const unsigned short* src = Vt + ((size_t)bh * DHEAD + d) * SEQ;
#pragma unroll
    for (int q = 0; q < 4; ++q) {
      int n = nbase + q;
      T[c4 * 4 + q][d] = (n >= 0 && n < SEQ) ? bf2f(src[n]) : 0.f;
    }
  }
  __syncthreads();
#pragma unroll
  for (int p = 0; p < 4; ++p) {
    int n = (tid >> 4) + p * 16;           // 0..63
    int d4 = tid & 15;
    int row = bh * SEQ + n0 + n;
    float ls[NSPLIT], m = -3.0e38f;
#pragma unroll
    for (int q = 0; q < NSPLIT; ++q) { ls[q] = LSE[q * BHS + row]; m = fmaxf(m, ls[q]); }
    float wq[NSPLIT], tot = 0.f;
#pragma unroll
    for (int q = 0; q < NSPLIT; ++q) { wq[q] = __expf(ls[q] - m); tot += wq[q]; }
    float inv = 1.f / tot;
    float o0 = 0.f, o1 = 0.f, o2 = 0.f, o3 = 0.f;
#pragma unroll
    for (int q = 0; q < NSPLIT; ++q) {
      float wk = wq[q] * inv;
      ushort4 a = *(const ushort4*)(Po + (size_t)q * QKV_ELEMS + (size_t)row * DHEAD + d4 * 4);
      o0 += wk * bf2f(a.x); o1 += wk * bf2f(a.y);
      o2 += wk * bf2f(a.z); o3 += wk * bf2f(a.w);
    }
#pragma unroll
    for (int t = 0; t < 33; ++t) {
      float wv = cwl[t];
      float4 tv = *(const float4*)&T[n + t][d4 * 4];
      o0 += wv * tv.x; o1 += wv * tv.y; o2 += wv * tv.z; o3 += wv * tv.w;
    }
    union { unsigned short u[4]; ushort4 v; } pk;
    pk.u[0] = bfbits(o0); pk.u[1] = bfbits(o1);
    pk.u[2] = bfbits(o2); pk.u[3] = bfbits(o3);
    *(ushort4*)(Obf + (size_t)row * DHEAD + d4 * 4) = pk.v;
  }
}

// ---------------- out GEMM (MFMA): Obf bf16 gather-A, 64x64 tiles ------------
__global__ __launch_bounds__(256) void gemm_out_mfma(
    const unsigned short* __restrict__ Obf, const unsigned short* __restrict__ Wt,
    const float* __restrict__ bias, const float* __restrict__ maskf,
    float* __restrict__ out) {
  __shared__ __align__(16) unsigned char Al[64 * 128];
  __shared__ __align__(16) unsigned char Bl[64 * 128];
  const int tid = threadIdx.x;
  const int lane = tid & 63;
  const int w = tid >> 6;
  const int l15 = lane & 15, g = lane >> 4;
  const int wr = w >> 1, wc = w & 1;
  int bid = blockIdx.x;                    // 512 blocks
  int lid = (bid & 7) * 64 + (bid >> 3);
  int by = lid >> 3, bx = lid & 7;         // by 0..63, bx 0..7
  const int m0 = by * 64, n0 = bx * 64;
  const int bb = m0 >> 11;
  const int ii0 = m0 & (SEQ - 1);

  f32x4 acc[2][2] = {};
  const int srow = tid >> 3, scg = tid & 7;
  const int rsw = (l15 & 7) << 4;

  for (int k0 = 0; k0 < DIMM; k0 += 64) {
    const int hh = k0 >> 6;
    __syncthreads();
#pragma unroll
    for (int it = 0; it < 2; ++it) {
      int row = srow + it * 32;
      int sw = (row & 7) << 4;
      *(int4*)(Al + row * 128 + ((scg * 16) ^ sw)) =
          *(const int4*)(Obf + ((size_t)(bb * HEADS + hh) * SEQ + ii0 + row) * DHEAD + scg * 8);
      *(int4*)(Bl + row * 128 + ((scg * 16) ^ sw)) =
          *(const int4*)(Wt + (size_t)(n0 + row) * DIMM + k0 + scg * 8);
    }
    __syncthreads();
#pragma unroll
    for (int ks = 0; ks < 2; ++ks) {
      bf16x8 af[2], bfr[2];
#pragma unroll
      for (int mi = 0; mi < 2; ++mi)
        af[mi] = *(const bf16x8*)(Al + (wr * 32 + mi * 16 + l15) * 128 +
                                  ((ks * 64 + g * 16) ^ rsw));
#pragma unroll
      for (int nj = 0; nj < 2; ++nj)
        bfr[nj] = *(const bf16x8*)(Bl + (wc * 32 + nj * 16 + l15) * 128 +
                                   ((ks * 64 + g * 16) ^ rsw));
#pragma unroll
      for (int mi = 0; mi < 2; ++mi)
#pragma unroll
        for (int nj = 0; nj < 2; ++nj)
          acc[mi][nj] = __builtin_amdgcn_mfma_f32_16x16x32_bf16(
              af[mi], bfr[nj], acc[mi][nj], 0, 0, 0);
    }
  }
#pragma unroll
  for (int nj = 0; nj < 2; ++nj) {
    int col = n0 + wc * 32 + nj * 16 + l15;
    float bcol = bias[col];
#pragma unroll
    for (int mi = 0; mi < 2; ++mi) {
#pragma unroll
      for (int r = 0; r < 4; ++r) {
        int m = m0 + wr * 32 + mi * 16 + g * 4 + r;
        out[(size_t)m * DIMM + col] = (acc[mi][nj][r] + bcol) * maskf[m];
      }
    }
  }
}

extern "C" void kernel_launch(void* const* d_in, const int* in_sizes, int n_in,
                              void* d_out, int out_size, void* d_ws, size_t ws_size,
                              hipStream_t stream) {
  const float* x     = (const float*)d_in[0];
  const void*  mask  = d_in[1];
  const float* Wqkv  = (const float*)d_in[2];
  const float* Wout  = (const float*)d_in[3];
  const float* bout  = (const float*)d_in[4];
  const float* convw = (const float*)d_in[5];
  float* out = (float*)d_out;

  float* maskf = (float*)d_ws;
  unsigned* kmaxn = (unsigned*)(maskf + 4096);           // 16 used, pad 64
  unsigned short* Qbf = (unsigned short*)(kmaxn + 64);
  unsigned short* Kbf = Qbf + QKV_ELEMS;
  unsigned short* Vt  = Kbf + QKV_ELEMS;
  unsigned short* Po  = Vt + QKV_ELEMS;                  // NSPLIT partials
  float* LSE          = (float*)(Po + NSPLIT * QKV_ELEMS);
  unsigned short* Obf = (unsigned short*)(LSE + NSPLIT * BHS);
  unsigned short* Wtq = Obf + QKV_ELEMS;                 // 1536*512
  unsigned short* Wto = Wtq + (size_t)NQKV * DIMM;       // 512*512
  unsigned short* Xbf = Wto + (size_t)DIMM * DIMM;       // 4096*512

  prep_all<<<1281, 256, 0, stream>>>(x, mask, Wqkv, Wout, Xbf, maskf, Wtq, Wto, kmaxn);
  gemm_qkv_mfma<<<768, 256, 0, stream>>>(Xbf, Wtq, Qbf, Kbf, Vt, kmaxn);
  attn_split<<<2048, 256, 0, stream>>>(Qbf, Kbf, Vt, maskf, kmaxn, Po, LSE);
  combine_conv<<<512, 256, 0, stream>>>(Po, LSE, Vt, convw, Obf);
  gemm_out_mfma<<<512, 256, 0, stream>>>(Obf, Wto, bout, maskf, out);
}

// Round 9
// 99.003 us; speedup vs baseline: 7.5322x; 1.0055x over previous
//
#include <hip/hip_runtime.h>
#include <float.h>

#define BATCH 2
#define SEQ   2048
#define HEADS 8
#define DHEAD 64
#define DIMM  512
#define NQKV  1536
#define QSCALE_L2 (0.125f * 1.44269504f)   // fold log2(e)*scale into Q (exp2 softmax)

#define QKV_ELEMS ((size_t)BATCH * HEADS * SEQ * DHEAD)   // 2097152
#define BHS (BATCH * HEADS * SEQ)                          // 32768
#define NSPLIT 4

typedef __bf16 bf16x8 __attribute__((ext_vector_type(8)));
typedef short  s16x4  __attribute__((ext_vector_type(4)));
typedef float  f32x4  __attribute__((ext_vector_type(4)));

#if __has_builtin(__builtin_amdgcn_exp2f)
#define EXP2F __builtin_amdgcn_exp2f
#else
#define EXP2F exp2f
#endif

__device__ __forceinline__ unsigned short bfbits(float f) {
  __bf16 h = (__bf16)f;
  return *(unsigned short*)&h;
}
__device__ __forceinline__ float bf2f(unsigned short u) {
  return __uint_as_float((unsigned)u << 16);
}
__device__ __forceinline__ unsigned cvtpk(float a, float b) {
  unsigned r;
  asm("v_cvt_pk_bf16_f32 %0, %1, %2" : "=v"(r) : "v"(a), "v"(b));
  return r;
}
__device__ __forceinline__ f32x4 mfma16(s16x4 a, s16x4 b, f32x4 c) {
#if __has_builtin(__builtin_amdgcn_mfma_f32_16x16x16bf16_1k)
  return __builtin_amdgcn_mfma_f32_16x16x16bf16_1k(a, b, c, 0, 0, 0);
#else
  f32x4 d;
  asm("v_mfma_f32_16x16x16_bf16 %0, %1, %2, %3" : "=v"(d) : "v"(a), "v"(b), "v"(c));
  return d;
#endif
}

// ---------------- fused prep: X->bf16 | W transposes | mask sniff ------------
__device__ __forceinline__ void transpose_tile_dev(
    const float* __restrict__ W, unsigned short* __restrict__ Wt,
    int K, int N, int n0, int k0, int t, float T[64][65]) {
  {
    int r0 = t >> 4, c4 = t & 15;
#pragma unroll
    for (int rr = 0; rr < 4; ++rr) {
      int r = r0 + rr * 16;
      float4 v = *(const float4*)(W + (size_t)(k0 + r) * N + n0 + c4 * 4);
      T[r][c4 * 4 + 0] = v.x; T[r][c4 * 4 + 1] = v.y;
      T[r][c4 * 4 + 2] = v.z; T[r][c4 * 4 + 3] = v.w;
    }
  }
  __syncthreads();
  {
    int n = t >> 2, kc = t & 3;
    union { unsigned short u[16]; int4 v[2]; } p;
#pragma unroll
    for (int i = 0; i < 16; ++i) p.u[i] = bfbits(T[kc * 16 + i][n]);
    int4* dst = (int4*)(Wt + (size_t)(n0 + n) * K + k0 + kc * 16);
    dst[0] = p.v[0]; dst[1] = p.v[1];
  }
}

__global__ __launch_bounds__(256) void prep_all(
    const float* __restrict__ X, const void* __restrict__ mraw,
    const float* __restrict__ Wqkv, const float* __restrict__ Wout,
    unsigned short* __restrict__ Xbf, float* __restrict__ maskf,
    unsigned short* __restrict__ Wtq, unsigned short* __restrict__ Wto,
    unsigned* __restrict__ kmaxn) {
  __shared__ float T[64][65];
  __shared__ int f_bf16, f_f32, f_gt1, f_oddnz;
  const int b = blockIdx.x;
  const int t = threadIdx.x;
  if (b < 1024) {                      // X fp32 -> bf16 (2M elems)
    size_t i = ((size_t)b * 256 + t) * 8;
    float4 a0 = *(const float4*)(X + i);
    float4 a1 = *(const float4*)(X + i + 4);
    union { unsigned short u[8]; int4 v; } pk;
    pk.u[0] = bfbits(a0.x); pk.u[1] = bfbits(a0.y);
    pk.u[2] = bfbits(a0.z); pk.u[3] = bfbits(a0.w);
    pk.u[4] = bfbits(a1.x); pk.u[5] = bfbits(a1.y);
    pk.u[6] = bfbits(a1.z); pk.u[7] = bfbits(a1.w);
    *(int4*)(Xbf + i) = pk.v;
  } else if (b < 1216) {               // Wqkv transpose: 24 n-tiles x 8 k-tiles
    int bb2 = b - 1024;
    transpose_tile_dev(Wqkv, Wtq, DIMM, NQKV, (bb2 % 24) * 64, (bb2 / 24) * 64, t, T);
  } else if (b < 1280) {               // Wout transpose: 8 x 8
    int bb2 = b - 1216;
    transpose_tile_dev(Wout, Wto, DIMM, DIMM, (bb2 & 7) * 64, (bb2 >> 3) * 64, t, T);
  } else {                             // mask sniff + normalize + kmaxn init
    if (t < 16) kmaxn[t] = 0u;
    if (t == 0) { f_bf16 = 0; f_f32 = 0; f_gt1 = 0; f_oddnz = 0; }
    __syncthreads();
    const unsigned int* w = (const unsigned int*)mraw;
    unsigned int v = w[t];             // first 1KB: safe for every candidate dtype
    if (v == 0x3f803f80u) f_bf16 = 1;
    if (v == 0x3f800000u) f_f32 = 1;
    if (v > 1u)           f_gt1 = 1;
    if ((t & 1) && v != 0u) f_oddnz = 1;
    __syncthreads();
    int mode;                          // 0=i32 1=u8 2=i64 3=f32 4=bf16
    if (f_bf16)       mode = 4;
    else if (f_f32)   mode = 3;
    else if (f_gt1)   mode = 1;
    else if (!f_oddnz) mode = 2;
    else              mode = 0;
    for (int i = t; i < BATCH * SEQ; i += 256) {
      bool keep;
      if (mode == 4)      keep = ((const unsigned short*)mraw)[i] != 0;
      else if (mode == 3) keep = ((const float*)mraw)[i] != 0.f;
      else if (mode == 1) keep = ((const unsigned char*)mraw)[i] != 0;
      else if (mode == 2) keep = w[2 * i] != 0u;
      else                keep = w[i] != 0u;
      maskf[i] = keep ? 1.f : 0.f;
    }
  }
}

// ---------------- qkv GEMM (MFMA) + fused per-(b,h) max|k| -------------------
// Q/K epilogue: repack through LDS -> coalesced dwordx4 stores.
__global__ __launch_bounds__(256) void gemm_qkv_mfma(
    const unsigned short* __restrict__ Xbf, const unsigned short* __restrict__ Wt,
    unsigned short* __restrict__ Qbf, unsigned short* __restrict__ Kbf,
    unsigned short* __restrict__ Vt, unsigned* __restrict__ kmaxn) {
  __shared__ __align__(16) unsigned char Al[128 * 128];
  __shared__ __align__(16) unsigned char Bl[64 * 128];
  const int tid = threadIdx.x;
  const int lane = tid & 63;
  const int w = tid >> 6;
  const int l15 = lane & 15, g = lane >> 4;
  const int wr = w >> 1, wc = w & 1;
  int bid = blockIdx.x;                    // 768 blocks, bijective XCD swizzle
  int lid = (bid & 7) * 96 + (bid >> 3);
  int by = lid / 24, bx = lid - by * 24;   // by 0..31, bx 0..23
  const int m0 = by * 128;

  f32x4 acc[4][2] = {};
  const int srow = tid >> 3, scg = tid & 7;
  const int rsw = (l15 & 7) << 4;

  for (int k0 = 0; k0 < DIMM; k0 += 64) {
    __syncthreads();
#pragma unroll
    for (int it = 0; it < 4; ++it) {
      int row = srow + it * 32;
      int sw = (row & 7) << 4;
      *(int4*)(Al + row * 128 + ((scg * 16) ^ sw)) =
          *(const int4*)(Xbf + (size_t)(m0 + row) * DIMM + k0 + scg * 8);
      if (it < 2) {
        *(int4*)(Bl + row * 128 + ((scg * 16) ^ sw)) =
            *(const int4*)(Wt + (size_t)(bx * 64 + row) * DIMM + k0 + scg * 8);
      }
    }
    __syncthreads();
#pragma unroll
    for (int ks = 0; ks < 2; ++ks) {
      bf16x8 af[4], bfr[2];
#pragma unroll
      for (int mi = 0; mi < 4; ++mi)
        af[mi] = *(const bf16x8*)(Al + (wr * 64 + mi * 16 + l15) * 128 +
                                  ((ks * 64 + g * 16) ^ rsw));
#pragma unroll
      for (int nj = 0; nj < 2; ++nj)
        bfr[nj] = *(const bf16x8*)(Bl + (wc * 32 + nj * 16 + l15) * 128 +
                                   ((ks * 64 + g * 16) ^ rsw));
#pragma unroll
      for (int mi = 0; mi < 4; ++mi)
#pragma unroll
        for (int nj = 0; nj < 2; ++nj)
          acc[mi][nj] = __builtin_amdgcn_mfma_f32_16x16x32_bf16(
              af[mi], bfr[nj], acc[mi][nj], 0, 0, 0);
    }
  }
  const int chunk = bx >> 3;               // 0=Q 1=K 2=V
  const int bb = m0 >> 11;
  const int hh = bx & 7;                   // head (block covers exactly one)
  if (chunk == 2) {
#pragma unroll
    for (int nj = 0; nj < 2; ++nj) {
      int dd = wc * 32 + nj * 16 + l15;
#pragma unroll
      for (int mi = 0; mi < 4; ++mi) {
        int ii0 = (m0 & (SEQ - 1)) + wr * 64 + mi * 16 + g * 4;
        union { unsigned short u[4]; ushort4 v; } pk;
#pragma unroll
        for (int r = 0; r < 4; ++r) pk.u[r] = bfbits(acc[mi][nj][r]);
        *(ushort4*)(Vt + ((size_t)(bb * HEADS + hh) * DHEAD + dd) * SEQ + ii0) = pk.v;
      }
    }
  } else {
    // fused key-bound: max|k| per (b,h)
    if (chunk == 1) {
      float kab = 0.f;
#pragma unroll
      for (int nj = 0; nj < 2; ++nj)
#pragma unroll
        for (int mi = 0; mi < 4; ++mi)
#pragma unroll
          for (int r = 0; r < 4; ++r) kab = fmaxf(kab, fabsf(acc[mi][nj][r]));
#pragma unroll
      for (int d = 1; d < 64; d <<= 1) kab = fmaxf(kab, __shfl_xor(kab, d));
      if (lane == 0)
        atomicMax(kmaxn + (bb * HEADS + hh), __float_as_uint(kab * 1.005f));
    }
    // repack 128x64 bf16 tile through LDS -> coalesced stores
    unsigned short* dst = (chunk == 0) ? Qbf : Kbf;
    const float sc = (chunk == 0) ? QSCALE_L2 : 1.f;
    __syncthreads();                       // Al reuse
#pragma unroll
    for (int nj = 0; nj < 2; ++nj) {
      int dd = wc * 32 + nj * 16 + l15;
#pragma unroll
      for (int mi = 0; mi < 4; ++mi) {
#pragma unroll
        for (int r = 0; r < 4; ++r) {
          int rowl = wr * 64 + mi * 16 + g * 4 + r;
          *(unsigned short*)(Al + rowl * 128 + ((dd * 2) ^ ((rowl & 7) << 4))) =
              bfbits(acc[mi][nj][r] * sc);
        }
      }
    }
    __syncthreads();
    const int rr = tid >> 1, hf = tid & 1;
    const int ii0 = (m0 & (SEQ - 1));
    unsigned short* gout =
        dst + ((size_t)(bb * HEADS + hh) * SEQ + ii0 + rr) * DHEAD + hf * 32;
    const int sw2 = (rr & 7) << 4;
#pragma unroll
    for (int q = 0; q < 4; ++q)
      *(int4*)(gout + q * 8) =
          *(const int4*)(Al + rr * 128 + ((hf * 64 + q * 16) ^ sw2));
  }
}

// ---------------- flash attention: split-KV x4, shared-B, in-reg P -----------
// S^T = mfma(K,Q): lane (l15,g) holds P[q=l15][key=16j+4g+r]; exp2 with fixed
// bound B = ||q||*8*max|k| shared across splits -> partials directly summable.
__global__ __launch_bounds__(256) void attn_split(const unsigned short* __restrict__ Qbf,
                                                  const unsigned short* __restrict__ Kbf,
                                                  const unsigned short* __restrict__ Vt,
                                                  const float* __restrict__ maskf,
                                                  const unsigned* __restrict__ kmaxn,
                                                  unsigned short* __restrict__ Po,
                                                  float* __restrict__ LSUM) {
  __shared__ __align__(16) unsigned char Ks[16384];   // 2 x 8KB
  __shared__ __align__(16) unsigned char Vs[16384];

  const int tid = threadIdx.x;
  const int lane = tid & 63;
  const int w = tid >> 6;
  const int l15 = lane & 15, g = lane >> 4;

  int fid = blockIdx.x;
  int lid = (fid & 7) * 256 + (fid >> 3);  // bijective over 2048
  const int bh = lid >> 7;                 // 0..15
  const int rem = lid & 127;
  const int qb = rem >> 2;                 // 0..31
  const int quarter = rem & 3;
  const int bb = bh >> 3;

  const unsigned short* Qg = Qbf + ((size_t)bh * SEQ + qb * 64) * DHEAD;
  const unsigned short* Kg = Kbf + (size_t)bh * SEQ * DHEAD;
  const unsigned short* Vg = Vt  + (size_t)bh * DHEAD * SEQ;
  const float* mrow = maskf + bb * SEQ;

  bf16x8 qf0, qf1;
  {
    const unsigned char* qrow = (const unsigned char*)(Qg + (size_t)(w * 16 + l15) * DHEAD);
    qf0 = *(const bf16x8*)(qrow + g * 16);
    qf1 = *(const bf16x8*)(qrow + 64 + g * 16);
  }
  float Bx;
  {
    float qn2 = 0.f;
#pragma unroll
    for (int i = 0; i < 8; ++i) {
      float a = (float)qf0[i]; qn2 += a * a;
      float b = (float)qf1[i]; qn2 += b * b;
    }
    qn2 += __shfl_xor(qn2, 16);
    qn2 += __shfl_xor(qn2, 32);
    const float kabs = __uint_as_float(kmaxn[bh]);
    Bx = sqrtf(qn2) * 8.f * kabs;          // log2-units (Q pre-scaled)
  }

  f32x4 o[4] = {};
  float lsum = 0.f;

  const int sm = tid >> 2;
  const int sc = (tid & 3) * 32;
  const int ssw = (sm & 7) << 4;
  const int vswap = (sm >> 3) & 1;         // half-swap flag for V stores
  const int rsw = (l15 & 7) << 4;
  const int vsw = rsw | (((l15 >> 3) & 1) << 3);   // V-read swizzle (8B gran)
  const int kt0 = quarter * 8;

  int4 rk0, rk1, rv0, rv1;
  {
    const unsigned char* ksrc =
        (const unsigned char*)(Kg + (size_t)kt0 * 64 * DHEAD) + sm * 128 + sc;
    const unsigned char* vsrc =
        (const unsigned char*)(Vg + (size_t)sm * SEQ + kt0 * 64) + sc;
    rk0 = *(const int4*)(ksrc); rk1 = *(const int4*)(ksrc + 16);
    rv0 = *(const int4*)(vsrc); rv1 = *(const int4*)(vsrc + 16);
  }
  {
    *(int4*)(Ks + sm * 128 + ((sc)      ^ ssw)) = rk0;
    *(int4*)(Ks + sm * 128 + ((sc + 16) ^ ssw)) = rk1;
    int4 sv0 = vswap ? (int4){rv0.z, rv0.w, rv0.x, rv0.y} : rv0;
    int4 sv1 = vswap ? (int4){rv1.z, rv1.w, rv1.x, rv1.y} : rv1;
    *(int4*)(Vs + sm * 128 + ((sc)      ^ ssw)) = sv0;
    *(int4*)(Vs + sm * 128 + ((sc + 16) ^ ssw)) = sv1;
  }
  __syncthreads();

  for (int t = 0; t < 8; ++t) {
    const int kt = kt0 + t;
    const int co = (t & 1) << 13;          // current buffer byte offset
    const int no = co ^ 8192;              // next buffer
    float4 km[4];
#pragma unroll
    for (int j = 0; j < 4; ++j) km[j] = *(const float4*)(mrow + kt * 64 + 16 * j + 4 * g);
    if (t < 7) {                           // T14: issue next tile's loads now
      const unsigned char* ksrc =
          (const unsigned char*)(Kg + (size_t)(kt + 1) * 64 * DHEAD) + sm * 128 + sc;
      const unsigned char* vsrc =
          (const unsigned char*)(Vg + (size_t)sm * SEQ + (kt + 1) * 64) + sc;
      rk0 = *(const int4*)(ksrc); rk1 = *(const int4*)(ksrc + 16);
      rv0 = *(const int4*)(vsrc); rv1 = *(const int4*)(vsrc + 16);
    }

    // S^T = K · Q^T
    f32x4 s[4];
#pragma unroll
    for (int j = 0; j < 4; ++j) {
      const unsigned char* krow = Ks + co + (16 * j + l15) * 128;
      bf16x8 kf0 = *(const bf16x8*)(krow + ((g * 16)      ^ rsw));
      bf16x8 kf1 = *(const bf16x8*)(krow + ((64 + g * 16) ^ rsw));
      f32x4 z = (f32x4){0.f, 0.f, 0.f, 0.f};
      z = __builtin_amdgcn_mfma_f32_16x16x32_bf16(kf0, qf0, z, 0, 0, 0);
      z = __builtin_amdgcn_mfma_f32_16x16x32_bf16(kf1, qf1, z, 0, 0, 0);
      s[j] = z;
    }

    // p = exp2(s - Bx) * km ; pack to bf16x4 A-fragments in-register
    s16x4 pa[4];
#pragma unroll
    for (int j = 0; j < 4; ++j) {
      float p0 = EXP2F(s[j][0] - Bx) * km[j].x;
      float p1 = EXP2F(s[j][1] - Bx) * km[j].y;
      float p2 = EXP2F(s[j][2] - Bx) * km[j].z;
      float p3 = EXP2F(s[j][3] - Bx) * km[j].w;
      lsum += (p0 + p1) + (p2 + p3);
      union { uint2 u; s16x4 v; } pk;
      pk.u.x = cvtpk(p0, p1);
      pk.u.y = cvtpk(p2, p3);
      pa[j] = pk.v;
    }

    // O += P @ V via 16x16x16 (conflict-free b64 reads)
#pragma unroll
    for (int dj = 0; dj < 4; ++dj) {
      const unsigned char* vrow = Vs + co + (16 * dj + l15) * 128;
#pragma unroll
      for (int j = 0; j < 4; ++j) {
        s16x4 vb = *(const s16x4*)(vrow + ((32 * j + 8 * g) ^ vsw));
        o[dj] = mfma16(pa[j], vb, o[dj]);
      }
    }

    if (t < 7) {                           // stage next tile into other buffer
      *(int4*)(Ks + no + sm * 128 + ((sc)      ^ ssw)) = rk0;
      *(int4*)(Ks + no + sm * 128 + ((sc + 16) ^ ssw)) = rk1;
      int4 sv0 = vswap ? (int4){rv0.z, rv0.w, rv0.x, rv0.y} : rv0;
      int4 sv1 = vswap ? (int4){rv1.z, rv1.w, rv1.x, rv1.y} : rv1;
      *(int4*)(Vs + no + sm * 128 + ((sc)      ^ ssw)) = sv0;
      *(int4*)(Vs + no + sm * 128 + ((sc + 16) ^ ssw)) = sv1;
      __syncthreads();                     // single barrier per tile
    }
  }

  // epilogue: write unnormalized partial O + row-sum (shared B across splits)
#pragma unroll
  for (int r = 0; r < 4; ++r) {
    int row = qb * 64 + w * 16 + 4 * g + r;
    size_t base = (size_t)quarter * QKV_ELEMS + ((size_t)bh * SEQ + row) * DHEAD + l15;
    Po[base]      = bfbits(o[0][r]);
    Po[base + 16] = bfbits(o[1][r]);
    Po[base + 32] = bfbits(o[2][r]);
    Po[base + 48] = bfbits(o[3][r]);
  }
  lsum += __shfl_xor(lsum, 16);
  lsum += __shfl_xor(lsum, 32);
  if (g == 0) {
    int row = qb * 64 + w * 16 + l15;
    LSUM[quarter * BHS + bh * SEQ + row] = lsum;
  }
}

// ---------------- combine 4 partials (plain sum) + conv residual -> Obf ------
__global__ __launch_bounds__(256) void combine_conv(
    const unsigned short* __restrict__ Po, const float* __restrict__ LSUM,
    const unsigned short* __restrict__ Vt, const float* __restrict__ cw,
    unsigned short* __restrict__ Obf) {
  __shared__ float T[96][68];
  __shared__ float cwl[33];
  const int tid = threadIdx.x;
  const int bid = blockIdx.x;              // 512 = 16 bh x 32 n-chunks
  const int bh = bid >> 5;
  const int n0 = (bid & 31) * 64;
  const int hh = bh & 7;
  if (tid < 33) cwl[tid] = cw[hh * 33 + tid];
  for (int idx = tid; idx < 64 * 24; idx += 256) {
    int d = idx / 24, c4 = idx - (idx / 24) * 24;
    int nbase = n0 - 16 + c4 * 4;
    const unsigned short* src = Vt + ((size_t)bh * DHEAD + d) * SEQ;
#pragma unroll
    for (int q = 0; q < 4; ++q) {
      int n = nbase + q;
      T[c4 * 4 + q][d] = (n >= 0 && n < SEQ) ? bf2f(src[n]) : 0.f;
    }
  }
  __syncthreads();
#pragma unroll
  for (int p = 0; p < 4; ++p) {
    int n = (tid >> 4) + p * 16;           // 0..63
    int d4 = tid & 15;
    int row = bh * SEQ + n0 + n;
    float tot = 0.f;
#pragma unroll
    for (int q = 0; q < NSPLIT; ++q) tot += LSUM[q * BHS + row];
    float inv = (tot > 0.f) ? 1.f / tot : 0.f;
    float o0 = 0.f, o1 = 0.f, o2 = 0.f, o3 = 0.f;
#pragma unroll
    for (int q = 0; q < NSPLIT; ++q) {
      ushort4 a = *(const ushort4*)(Po + (size_t)q * QKV_ELEMS + (size_t)row * DHEAD + d4 * 4);
      o0 += bf2f(a.x); o1 += bf2f(a.y);
      o2 += bf2f(a.z); o3 += bf2f(a.w);
    }
    o0 *= inv; o1 *= inv; o2 *= inv; o3 *= inv;
#pragma unroll
    for (int t = 0; t < 33; ++t) {
      float wv = cwl[t];
      float4 tv = *(const float4*)&T[n + t][d4 * 4];
      o0 += wv * tv.x; o1 += wv * tv.y; o2 += wv * tv.z; o3 += wv * tv.w;
    }
    union { unsigned short u[4]; ushort4 v; } pk;
    pk.u[0] = bfbits(o0); pk.u[1] = bfbits(o1);
    pk.u[2] = bfbits(o2); pk.u[3] = bfbits(o3);
    *(ushort4*)(Obf + (size_t)row * DHEAD + d4 * 4) = pk.v;
  }
}

// ---------------- out GEMM (MFMA): Obf bf16 gather-A, 64x64 tiles ------------
__global__ __launch_bounds__(256) void gemm_out_mfma(
    const unsigned short* __restrict__ Obf, const unsigned short* __restrict__ Wt,
    const float* __restrict__ bias, const float* __restrict__ maskf,
    float* __restrict__ out) {
  __shared__ __align__(16) unsigned char Al[64 * 128];
  __shared__ __align__(16) unsigned char Bl[64 * 128];
  const int tid = threadIdx.x;
  const int lane = tid & 63;
  const int w = tid >> 6;
  const int l15 = lane & 15, g = lane >> 4;
  const int wr = w >> 1, wc = w & 1;
  int bid = blockIdx.x;                    // 512 blocks
  int lid = (bid & 7) * 64 + (bid >> 3);
  int by = lid >> 3, bx = lid & 7;         // by 0..63, bx 0..7
  const int m0 = by * 64, n0 = bx * 64;
  const int bb = m0 >> 11;
  const int ii0 = m0 & (SEQ - 1);

  f32x4 acc[2][2] = {};
  const int srow = tid >> 3, scg = tid & 7;
  const int rsw = (l15 & 7) << 4;

  for (int k0 = 0; k0 < DIMM; k0 += 64) {
    const int hh = k0 >> 6;
    __syncthreads();
#pragma unroll
    for (int it = 0; it < 2; ++it) {
      int row = srow + it * 32;
      int sw = (row & 7) << 4;
      *(int4*)(Al + row * 128 + ((scg * 16) ^ sw)) =
          *(const int4*)(Obf + ((size_t)(bb * HEADS + hh) * SEQ + ii0 + row) * DHEAD + scg * 8);
      *(int4*)(Bl + row * 128 + ((scg * 16) ^ sw)) =
          *(const int4*)(Wt + (size_t)(n0 + row) * DIMM + k0 + scg * 8);
    }
    __syncthreads();
#pragma unroll
    for (int ks = 0; ks < 2; ++ks) {
      bf16x8 af[2], bfr[2];
#pragma unroll
      for (int mi = 0; mi < 2; ++mi)
        af[mi] = *(const bf16x8*)(Al + (wr * 32 + mi * 16 + l15) * 128 +
                                  ((ks * 64 + g * 16) ^ rsw));
#pragma unroll
      for (int nj = 0; nj < 2; ++nj)
        bfr[nj] = *(const bf16x8*)(Bl + (wc * 32 + nj * 16 + l15) * 128 +
                                   ((ks * 64 + g * 16) ^ rsw));
#pragma unroll
      for (int mi = 0; mi < 2; ++mi)
#pragma unroll
        for (int nj = 0; nj < 2; ++nj)
          acc[mi][nj] = __builtin_amdgcn_mfma_f32_16x16x32_bf16(
              af[mi], bfr[nj], acc[mi][nj], 0, 0, 0);
    }
  }
#pragma unroll
  for (int nj = 0; nj < 2; ++nj) {
    int col = n0 + wc * 32 + nj * 16 + l15;
    float bcol = bias[col];
#pragma unroll
    for (int mi = 0; mi < 2; ++mi) {
#pragma unroll
      for (int r = 0; r < 4; ++r) {
        int m = m0 + wr * 32 + mi * 16 + g * 4 + r;
        out[(size_t)m * DIMM + col] = (acc[mi][nj][r] + bcol) * maskf[m];
      }
    }
  }
}

extern "C" void kernel_launch(void* const* d_in, const int* in_sizes, int n_in,
                              void* d_out, int out_size, void* d_ws, size_t ws_size,
                              hipStream_t stream) {
  const float* x     = (const float*)d_in[0];
  const void*  mask  = d_in[1];
  const float* Wqkv  = (const float*)d_in[2];
  const float* Wout  = (const float*)d_in[3];
  const float* bout  = (const float*)d_in[4];
  const float* convw = (const float*)d_in[5];
  float* out = (float*)d_out;

  float* maskf = (float*)d_ws;
  unsigned* kmaxn = (unsigned*)(maskf + 4096);           // 16 used, pad 64
  unsigned short* Qbf = (unsigned short*)(kmaxn + 64);
  unsigned short* Kbf = Qbf + QKV_ELEMS;
  unsigned short* Vt  = Kbf + QKV_ELEMS;
  unsigned short* Po  = Vt + QKV_ELEMS;                  // NSPLIT partials
  float* LSUM         = (float*)(Po + NSPLIT * QKV_ELEMS);
  unsigned short* Obf = (unsigned short*)(LSUM + NSPLIT * BHS);
  unsigned short* Wtq = Obf + QKV_ELEMS;                 // 1536*512
  unsigned short* Wto = Wtq + (size_t)NQKV * DIMM;       // 512*512
  unsigned short* Xbf = Wto + (size_t)DIMM * DIMM;       // 4096*512

  prep_all<<<1281, 256, 0, stream>>>(x, mask, Wqkv, Wout, Xbf, maskf, Wtq, Wto, kmaxn);
  gemm_qkv_mfma<<<768, 256, 0, stream>>>(Xbf, Wtq, Qbf, Kbf, Vt, kmaxn);
  attn_split<<<2048, 256, 0, stream>>>(Qbf, Kbf, Vt, maskf, kmaxn, Po, LSUM);
  combine_conv<<<512, 256, 0, stream>>>(Po, LSUM, Vt, convw, Obf);
  gemm_out_mfma<<<512, 256, 0, stream>>>(Obf, Wto, bout, maskf, out);
}